// Round 1
// 178.607 us; speedup vs baseline: 1.0253x; 1.0253x over previous
//
#include <hip/hip_runtime.h>
#include <hip/hip_bf16.h>

// ---------------------------------------------------------------------------
// SelfAttention2d, fully-MFMA pipeline, fragment-major memory layouts.
// MFMA 16x16x32 bf16: A[m=il][k=q*8+j], B[col=il][k=q*8+j], C[row=q*4+r][col=il]
//
// R1: conv/kqv/attn_out GEMM kernels restructured from 1-wave blocks (0.75
// waves/SIMD, MfmaUtil 11%) to 4-wave blocks; each wave owns a 2x2 quadrant
// of the 4x4 fragment tile (32 pos x 32 cout). Load:MFMA ratio unchanged,
// waves/SIMD 0.75 -> 3 for latency hiding.
//
// Attention computes S TRANSPOSED (A=K, B=Q) so each lane holds
// S[m=m0+il][n=nb+q*4+r]:  pw lookups become ny-invariant registers, ph is one
// read/ny, and P needs only an 8B LDS write + b128 read to become the PV
// A-operand (full K=32).
//
// Layouts:
//   XC   [b][kc 0..7][y 0..33][x 0..33][ci 32]  zero-padded image, bf16
//   WB2  [t9][coG6][nt4][kc8][lane64][8]        w_out frag-major
//   WK2  [coG6][nt4][kc8][lane64][8]            w_kqv frag-major
//   WA2  [coG2][nt4][kc4][lane64][8]            w_attn frag-major
//   VT   [bh][ny32][d16][ci 32]                 V^T frag-major
//   artX [b][kc4][pp1024][ci32]                 attn out, frag-major
//
// ws (ushort units, 7,262,208 B <= proven-safe 8,192,000):
//   WB2 0 / WK2 884736 / WA2 983040 / KRWB 999424 / KRHB 1000448 /
//   XC 1001472 (2,367,488) / ART2 3368960 (b=6,7 slots)
// d_out scratch (ushort): KS 0 / QS 1048576 / VT 2097152 / ART1 7340032 (b0..5)
// Order: prep -> zero_xc -> xt -> kqv -> attn -> attn_out -> conv
// ---------------------------------------------------------------------------

typedef short v8s __attribute__((ext_vector_type(8)));
typedef float v4f __attribute__((ext_vector_type(4)));

#define WB2_US   0u
#define WK2_US   884736u
#define WA2_US   983040u
#define KRWB_US  999424u
#define KRHB_US  1000448u
#define XC_US    1001472u
#define ART2_US  3368960u

#define KS_US    0u
#define QS_US    1048576u
#define VTS_US   2097152u
#define ART1_US  7340032u

#define QSCALE 0.360673760f   // 0.25 * log2(e)
#define SHIFT2 17.3123405f    // 12 * log2(e)

__device__ __forceinline__ unsigned short f2bs(float f) {
  __hip_bfloat16 h = __float2bfloat16(f);
  return *reinterpret_cast<unsigned short*>(&h);
}

// ---------------------------------------------------------------------------
__global__ __launch_bounds__(256) void prep_kernel(
    const float* __restrict__ w_out, const float* __restrict__ w_kqv,
    const float* __restrict__ w_attn, const float* __restrict__ krw,
    const float* __restrict__ krh, unsigned short* __restrict__ ws) {
  int i = blockIdx.x * 256 + threadIdx.x;
  if (i < 884736) {              // WB2[t][coG][nt][kc][lane][8]
    int j = i & 7, l = (i >> 3) & 63, kc = (i >> 9) & 7, nt = (i >> 12) & 3;
    int r = i >> 14; int coG = r % 6, t = r / 6;
    int co = coG * 64 + nt * 16 + (l & 15);
    int ci = kc * 32 + (l >> 4) * 8 + j;
    ws[WB2_US + i] = f2bs(w_out[(size_t)co * 2304 + ci * 9 + t]);
  } else if (i < 983040) {       // WK2[coG][nt][kc][lane][8]
    int o = i - 884736;
    int j = o & 7, l = (o >> 3) & 63, kc = (o >> 9) & 7, nt = (o >> 12) & 3;
    int coG = o >> 14;
    int co = coG * 64 + nt * 16 + (l & 15);
    int ci = kc * 32 + (l >> 4) * 8 + j;
    ws[WK2_US + o] = f2bs(w_kqv[co * 256 + ci]);
  } else if (i < 999424) {       // WA2[coG][nt][kc][lane][8]
    int o = i - 983040;
    int j = o & 7, l = (o >> 3) & 63, kc = (o >> 9) & 3, nt = (o >> 11) & 3;
    int coG = o >> 13;
    int co = coG * 64 + nt * 16 + (l & 15);
    int ci = kc * 32 + (l >> 4) * 8 + j;
    ws[WA2_US + o] = f2bs(w_attn[co * 128 + ci]);
  } else if (i < 1000448) {      // krw bf16 [64][16], row 63 zero
    int j = i - 999424; int c = j >> 4, d = j & 15;
    ws[KRWB_US + j] = (c < 63) ? f2bs(krw[c * 16 + d]) : (unsigned short)0;
  } else if (i < 1001472) {
    int j = i - 1000448; int c = j >> 4, d = j & 15;
    ws[KRHB_US + j] = (c < 63) ? f2bs(krh[c * 16 + d]) : (unsigned short)0;
  }
}

// ---------------------------------------------------------------------------
__global__ __launch_bounds__(256) void zero_xc_kernel(unsigned short* __restrict__ xc) {
  int i = blockIdx.x * 256 + threadIdx.x;   // 295,936 uint4 = 2,367,488 us
  uint4 z = {0u, 0u, 0u, 0u};
  ((uint4*)xc)[i] = z;
}

// ---------------------------------------------------------------------------
// x [b][ci][pos] fp32 -> XC[b][ci>>5][y+1][x+1][ci&31] bf16 via LDS tile.
__global__ __launch_bounds__(256) void xt_kernel(
    const float* __restrict__ x, unsigned short* __restrict__ xc) {
  __shared__ float t[64][65];
  int tid = threadIdx.x; int pl = tid & 63, cg = tid >> 6;
  int pos0 = blockIdx.x * 64, ci0 = blockIdx.y * 64, b = blockIdx.z;
  const float* xb = x + ((size_t)(b * 256 + ci0)) * 1024 + pos0;
#pragma unroll
  for (int i = 0; i < 16; ++i) {
    int ci_l = cg * 16 + i;
    t[ci_l][pl] = xb[(size_t)ci_l * 1024 + pl];
  }
  __syncthreads();
#pragma unroll
  for (int i = 0; i < 16; ++i) {
    int pos_l = cg * 16 + i;
    int pos = pos0 + pos_l;
    int y = (pos >> 5) + 1, xx = (pos & 31) + 1;
    int ci = ci0 + pl;
    xc[((size_t)((b * 8 + (ci >> 5)) * 34 + y) * 34 + xx) * 32 + (ci & 31)] =
        f2bs(t[pl][pos_l]);
  }
}

// ---------------------------------------------------------------------------
// kqv GEMM: A-frags from XC (tap 1,1; contiguous 1KB loads), B from WK2.
// 4 waves/block; wave (mh,nh) owns the 2x2 quadrant (mt=mh*2+mi, nt=nh*2+ni).
__global__ __launch_bounds__(256) void kqv_mfma(
    const unsigned short* __restrict__ xc, const unsigned short* __restrict__ wk2,
    const float* __restrict__ bkqv, unsigned short* __restrict__ dq) {
  int tid = threadIdx.x;
  int lane = tid & 63; int il = lane & 15, q = lane >> 4;
  int wv = tid >> 6; int mh = wv >> 1, nh = wv & 1;
  int m0 = blockIdx.x * 64, coG = blockIdx.y;
  int b = m0 >> 10, pos0 = m0 & 1023;
  int row0 = pos0 >> 5;
  v4f acc[2][2];
#pragma unroll
  for (int mi = 0; mi < 2; ++mi)
#pragma unroll
    for (int ni = 0; ni < 2; ++ni) acc[mi][ni] = (v4f){0.f, 0.f, 0.f, 0.f};

  int pix[2];
#pragma unroll
  for (int mi = 0; mi < 2; ++mi)
    pix[mi] = (row0 + mh + 1) * 34 + (mi * 16 + il + 1);
  const unsigned short* bt = wk2 + (size_t)coG * 16384 + lane * 8;

#pragma unroll 4
  for (int kc = 0; kc < 8; ++kc) {
    v8s af[2], bf[2];
#pragma unroll
    for (int ni = 0; ni < 2; ++ni)
      bf[ni] = *(const v8s*)(bt + ((nh * 2 + ni) * 8 + kc) * 512);
#pragma unroll
    for (int mi = 0; mi < 2; ++mi)
      af[mi] = *(const v8s*)(xc + ((size_t)(b * 8 + kc) * 1156 + pix[mi]) * 32 + q * 8);
#pragma unroll
    for (int mi = 0; mi < 2; ++mi)
#pragma unroll
      for (int ni = 0; ni < 2; ++ni)
        acc[mi][ni] = __builtin_amdgcn_mfma_f32_16x16x32_bf16(
            af[mi], bf[ni], acc[mi][ni], 0, 0, 0);
  }
  int co0 = coG * 64;
#pragma unroll
  for (int ni = 0; ni < 2; ++ni) {
    int nt = nh * 2 + ni;
    int cob = co0 + nt * 16;
    int co = cob + il;
    float bias = bkqv[co];
    int cls = cob >> 7;                  // 0:k 1:q 2:v (uniform per nt)
    int h = (cob >> 4) & 7;
    size_t bh = (size_t)(b * 8 + h);
#pragma unroll
    for (int mi = 0; mi < 2; ++mi) {
      int mt = mh * 2 + mi;
      int pos = pos0 + mt * 16 + q * 4;
      v4f a = acc[mi][ni];
#pragma unroll
      for (int r = 0; r < 4; ++r) {
        float v = a[r] + bias;
        int p = pos + r;
        if (cls == 0)      dq[KS_US + bh * 16384 + p * 16 + il] = f2bs(v);
        else if (cls == 1) dq[QS_US + bh * 16384 + p * 16 + il] = f2bs(v * QSCALE);
        else               dq[VTS_US + bh * 16384 + ((p >> 5) * 16 + il) * 32 + (p & 31)] = f2bs(v);
      }
    }
  }
}

// ---------------------------------------------------------------------------
// MFMA attention, S-transposed formulation. Block 256 = 4 waves; wave owns a
// 16-row m-tile. Lane (q,il) reg r holds S[m0+il][nb+q*4+r].
__global__ __launch_bounds__(256) void attn_mfma(
    unsigned short* __restrict__ dq, const unsigned short* __restrict__ krwb,
    const unsigned short* __restrict__ krhb, unsigned short* __restrict__ wsart) {
  __shared__ float lds[4][2448];
  int tid = threadIdx.x; int w = tid >> 6, lane = tid & 63;
  int il = lane & 15, q = lane >> 4;
  int bh = blockIdx.y; int b = bh >> 3, h = bh & 7;
  int m0 = blockIdx.x * 64 + w * 16;
  int my = m0 >> 5, mxb = m0 & 31;
  float* pw = lds[w];                       // [16 rows][stride 64]
  float* ph = pw + 1024;                    // [16 rows][stride 68], - SHIFT2
  unsigned short* pl = (unsigned short*)(ph + 1088);  // [16 rows][stride 40] bf16

  const v8s z8 = {0, 0, 0, 0, 0, 0, 0, 0};
  const v4f z4 = {0.f, 0.f, 0.f, 0.f};

  // Q frag: A-layout for table build == B-layout for S^T (same registers).
  const unsigned short* qrow = dq + QS_US + (size_t)bh * 16384 + (m0 + il) * 16;
  v8s qa = *(const v8s*)(qrow + (q & 1) * 8);
  qa = (q < 2) ? qa : z8;

  // PW / PH tables via MFMA (C row = m-row in tile, col = table col)
#pragma unroll
  for (int nt = 0; nt < 4; ++nt) {
    int c = nt * 16 + il;
    v8s bw = *(const v8s*)(krwb + c * 16 + (q & 1) * 8);
    v8s bhh = *(const v8s*)(krhb + c * 16 + (q & 1) * 8);
    bw = (q < 2) ? bw : z8;
    bhh = (q < 2) ? bhh : z8;
    v4f pwc = __builtin_amdgcn_mfma_f32_16x16x32_bf16(qa, bw, z4, 0, 0, 0);
    v4f phc = __builtin_amdgcn_mfma_f32_16x16x32_bf16(qa, bhh, z4, 0, 0, 0);
#pragma unroll
    for (int r = 0; r < 4; ++r) {
      pw[(q * 4 + r) * 64 + c] = pwc[r];
      ph[(q * 4 + r) * 68 + c] = phc[r] - SHIFT2;
    }
  }
  __builtin_amdgcn_wave_barrier();

  // pw lookups are ny-invariant per lane in the transposed scheme: hoist.
  float pwv[2][4];
#pragma unroll
  for (int nt2 = 0; nt2 < 2; ++nt2)
#pragma unroll
    for (int r = 0; r < 4; ++r)
      pwv[nt2][r] = pw[il * 64 + (nt2 * 16 + q * 4 + r) - mxb - il + 31];

  v4f oacc = z4;
  float sacc = 0.f;
  const unsigned short* kbase = dq + KS_US + (size_t)bh * 16384;
  const unsigned short* vbase = dq + VTS_US + (size_t)bh * 16384;

  for (int ny = 0; ny < 32; ++ny) {
    float phv = ph[il * 68 + (ny - my + 31)];
    v4f s[2];
#pragma unroll
    for (int nt2 = 0; nt2 < 2; ++nt2) {
      v8s kb = *(const v8s*)(kbase + (ny * 32 + nt2 * 16 + il) * 16 + (q & 1) * 8);
      kb = (q < 2) ? kb : z8;
      s[nt2] = __builtin_amdgcn_mfma_f32_16x16x32_bf16(kb, qa, z4, 0, 0, 0);
    }
#pragma unroll
    for (int nt2 = 0; nt2 < 2; ++nt2) {
      float p[4];
#pragma unroll
      for (int r = 0; r < 4; ++r) {
        float t = s[nt2][r] + pwv[nt2][r] + phv;
        p[r] = exp2f(t);
        sacc += p[r];
      }
      uint2 pk;
      pk.x = (unsigned)f2bs(p[0]) | ((unsigned)f2bs(p[1]) << 16);
      pk.y = (unsigned)f2bs(p[2]) | ((unsigned)f2bs(p[3]) << 16);
      *(uint2*)(pl + il * 40 + nt2 * 16 + q * 4) = pk;
    }
    __builtin_amdgcn_wave_barrier();
    v8s pf = *(const v8s*)(pl + il * 40 + q * 8);
    v8s vb = *(const v8s*)(vbase + (ny * 16 + il) * 32 + q * 8);
    oacc = __builtin_amdgcn_mfma_f32_16x16x32_bf16(pf, vb, oacc, 0, 0, 0);
    __builtin_amdgcn_wave_barrier();
  }

  // row sums: lane holds partial for row il; combine quads, then fetch per-r.
  sacc += __shfl_xor(sacc, 16);
  sacc += __shfl_xor(sacc, 32);

  unsigned short* abase = (b < 6) ? (dq + ART1_US + (size_t)b * 131072)
                                  : (wsart + (size_t)(b - 6) * 131072);
#pragma unroll
  for (int r = 0; r < 4; ++r) {
    float sr = __shfl(sacc, q * 4 + r);       // full sum for row q*4+r
    int m = m0 + q * 4 + r;
    int c = h * 16 + (m >> 6);                // ci of art
    int pp = (m & 63) * 16 + il;              // pos' of art
    abase[((c >> 5) * 1024 + pp) * 32 + (c & 31)] = f2bs(oacc[r] / sr);
  }
}

// ---------------------------------------------------------------------------
// attn_out GEMM: A from artX (contiguous), B from WA2 (frag-major).
// 4 waves/block; wave (mh,nh) owns the 2x2 quadrant.
__global__ __launch_bounds__(256) void attn_out_mfma(
    const unsigned short* __restrict__ dq, const unsigned short* __restrict__ wsart,
    const unsigned short* __restrict__ wa2, const float* __restrict__ ba,
    float* __restrict__ out) {
  int tid = threadIdx.x;
  int lane = tid & 63; int il = lane & 15, q = lane >> 4;
  int wv = tid >> 6; int mh = wv >> 1, nh = wv & 1;
  int m0 = blockIdx.x * 64, coG = blockIdx.y;
  int b = m0 >> 10, pp0 = m0 & 1023;
  const unsigned short* ab = (b < 6) ? (dq + ART1_US + (size_t)b * 131072)
                                     : (wsart + (size_t)(b - 6) * 131072);
  const unsigned short* bt = wa2 + (size_t)coG * 8192 + lane * 8;
  v4f acc[2][2];
#pragma unroll
  for (int mi = 0; mi < 2; ++mi)
#pragma unroll
    for (int ni = 0; ni < 2; ++ni) acc[mi][ni] = (v4f){0.f, 0.f, 0.f, 0.f};
#pragma unroll
  for (int kc = 0; kc < 4; ++kc) {
    v8s af[2], bf[2];
#pragma unroll
    for (int ni = 0; ni < 2; ++ni)
      bf[ni] = *(const v8s*)(bt + ((nh * 2 + ni) * 4 + kc) * 512);
#pragma unroll
    for (int mi = 0; mi < 2; ++mi)
      af[mi] = *(const v8s*)(ab + (kc * 1024 + pp0 + (mh * 2 + mi) * 16 + il) * 32 + q * 8);
#pragma unroll
    for (int mi = 0; mi < 2; ++mi)
#pragma unroll
      for (int ni = 0; ni < 2; ++ni)
        acc[mi][ni] = __builtin_amdgcn_mfma_f32_16x16x32_bf16(
            af[mi], bf[ni], acc[mi][ni], 0, 0, 0);
  }
  int co0 = coG * 64;
#pragma unroll
  for (int ni = 0; ni < 2; ++ni) {
    int co = co0 + (nh * 2 + ni) * 16 + il;
    float bias = ba[co];
#pragma unroll
    for (int mi = 0; mi < 2; ++mi) {
      int mt = mh * 2 + mi;
      v4f a = acc[mi][ni];
      float4 v; v.x = a[0] + bias; v.y = a[1] + bias;
      v.z = a[2] + bias; v.w = a[3] + bias;
      *(float4*)(out + ((size_t)(b * 512 + 384 + co)) * 1024 + pp0 + mt * 16 + q * 4) = v;
    }
  }
}

// ---------------------------------------------------------------------------
// conv3x3 via MFMA on XC: every A/B frag load is contiguous 1KB.
// 4 waves/block; wave (mh,nh) owns the 2x2 quadrant of the 4x4 tile.
__global__ __launch_bounds__(256) void conv_mfma(
    const unsigned short* __restrict__ xc, const unsigned short* __restrict__ wb2,
    const float* __restrict__ bo, float* __restrict__ out) {
  int tid = threadIdx.x;
  int lane = tid & 63; int il = lane & 15, q = lane >> 4;
  int wv = tid >> 6; int mh = wv >> 1, nh = wv & 1;
  int pt = blockIdx.x, coG = blockIdx.y, b = blockIdx.z;
  int pos0 = pt * 64;
  int row0 = pos0 >> 5;
  v4f acc[2][2];
#pragma unroll
  for (int mi = 0; mi < 2; ++mi)
#pragma unroll
    for (int ni = 0; ni < 2; ++ni) acc[mi][ni] = (v4f){0.f, 0.f, 0.f, 0.f};

#pragma unroll
  for (int ky = 0; ky < 3; ++ky) {
#pragma unroll
    for (int kx = 0; kx < 3; ++kx) {
      const unsigned short* bt =
          wb2 + (size_t)((ky * 3 + kx) * 6 + coG) * 16384 + lane * 8;
      int pix[2];
#pragma unroll
      for (int mi = 0; mi < 2; ++mi)
        pix[mi] = (row0 + mh + ky) * 34 + (mi * 16 + il + kx);
#pragma unroll 4
      for (int kc = 0; kc < 8; ++kc) {
        v8s bf[2], af[2];
#pragma unroll
        for (int ni = 0; ni < 2; ++ni)
          bf[ni] = *(const v8s*)(bt + ((nh * 2 + ni) * 8 + kc) * 512);
#pragma unroll
        for (int mi = 0; mi < 2; ++mi)
          af[mi] = *(const v8s*)(xc + ((size_t)(b * 8 + kc) * 1156 + pix[mi]) * 32 + q * 8);
#pragma unroll
        for (int mi = 0; mi < 2; ++mi)
#pragma unroll
          for (int ni = 0; ni < 2; ++ni)
            acc[mi][ni] = __builtin_amdgcn_mfma_f32_16x16x32_bf16(
                af[mi], bf[ni], acc[mi][ni], 0, 0, 0);
      }
    }
  }
  int co0 = coG * 64;
#pragma unroll
  for (int ni = 0; ni < 2; ++ni) {
    int co = co0 + (nh * 2 + ni) * 16 + il;
    float bias = bo[co];
#pragma unroll
    for (int mi = 0; mi < 2; ++mi) {
      int mt = mh * 2 + mi;
      v4f a = acc[mi][ni];
      float4 v; v.x = a[0] + bias; v.y = a[1] + bias;
      v.z = a[2] + bias; v.w = a[3] + bias;
      *(float4*)(out + ((size_t)(b * 512 + co)) * 1024 + pos0 + mt * 16 + q * 4) = v;
    }
  }
}

// ---------------------------------------------------------------------------
extern "C" void kernel_launch(void* const* d_in, const int* in_sizes, int n_in,
                              void* d_out, int out_size, void* d_ws, size_t ws_size,
                              hipStream_t stream) {
  const float* x      = (const float*)d_in[0];
  const float* b_out  = (const float*)d_in[2];
  const float* b_kqv  = (const float*)d_in[4];
  const float* b_attn = (const float*)d_in[6];
  const float* krw    = (const float*)d_in[7];
  const float* krh    = (const float*)d_in[8];
  unsigned short* ws = (unsigned short*)d_ws;
  float* out = (float*)d_out;
  unsigned short* dq = (unsigned short*)d_out;

  prep_kernel<<<3912, 256, 0, stream>>>(
      (const float*)d_in[1], (const float*)d_in[3], (const float*)d_in[5],
      krw, krh, ws);
  zero_xc_kernel<<<1156, 256, 0, stream>>>(ws + XC_US);
  xt_kernel<<<dim3(16, 4, 8), 256, 0, stream>>>(x, ws + XC_US);
  kqv_mfma<<<dim3(128, 6), 256, 0, stream>>>(
      ws + XC_US, ws + WK2_US, b_kqv, dq);
  attn_mfma<<<dim3(16, 64), 256, 0, stream>>>(
      dq, ws + KRWB_US, ws + KRHB_US, ws + ART2_US);
  attn_out_mfma<<<dim3(128, 2), 256, 0, stream>>>(
      dq, ws + ART2_US, ws + WA2_US, b_attn, out);
  conv_mfma<<<dim3(16, 6, 8), 256, 0, stream>>>(
      ws + XC_US, ws + WB2_US, b_out, out);
}

// Round 2
// 173.144 us; speedup vs baseline: 1.0577x; 1.0316x over previous
//
#include <hip/hip_runtime.h>
#include <hip/hip_bf16.h>

// ---------------------------------------------------------------------------
// SelfAttention2d, fully-MFMA pipeline, fragment-major memory layouts.
// MFMA 16x16x32 bf16: A[m=il][k=q*8+j], B[col=il][k=q*8+j], C[row=q*4+r][col=il]
//
// R2: conv_mfma rebuilt as LDS-staged double-buffered pipeline. R1 evidence:
// occupancy 7->28% with dur unchanged (44.9us) => latency-bound at 1
// outstanding iteration/wave, not TLP-starved. New conv: block = 64 pos x
// 96 cout, 4 waves; XC tile (4 rows, 8.7KB) staged once per kc (reused by all
// 9 taps), weight tile (6KB) staged per (tap,kc); both dbuf, reg-staged
// (issue loads -> compute -> ds_write -> 1 barrier). b-pinned XCD swizzle
// (b = blockIdx.x & 7) keeps per-XCD L2 set at 2.35MB (resident).
//
// Attention computes S TRANSPOSED (A=K, B=Q) so each lane holds
// S[m=m0+il][n=nb+q*4+r]:  pw lookups become ny-invariant registers, ph is one
// read/ny, and P needs only an 8B LDS write + b128 read to become the PV
// A-operand (full K=32).
//
// Layouts:
//   XC   [b][kc 0..7][y 0..33][x 0..33][ci 32]  zero-padded image, bf16
//   WB2  [t9][coG6][nt4][kc8][lane64][8]        w_out frag-major
//   WK2  [coG6][nt4][kc8][lane64][8]            w_kqv frag-major
//   WA2  [coG2][nt4][kc4][lane64][8]            w_attn frag-major
//   VT   [bh][ny32][d16][ci 32]                 V^T frag-major
//   artX [b][kc4][pp1024][ci32]                 attn out, frag-major
//
// ws (ushort units, 7,262,208 B <= proven-safe 8,192,000):
//   WB2 0 / WK2 884736 / WA2 983040 / KRWB 999424 / KRHB 1000448 /
//   XC 1001472 (2,367,488) / ART2 3368960 (b=6,7 slots)
// d_out scratch (ushort): KS 0 / QS 1048576 / VT 2097152 / ART1 7340032 (b0..5)
// Order: prep -> zero_xc -> xt -> kqv -> attn -> attn_out -> conv
// ---------------------------------------------------------------------------

typedef short v8s __attribute__((ext_vector_type(8)));
typedef float v4f __attribute__((ext_vector_type(4)));

#define WB2_US   0u
#define WK2_US   884736u
#define WA2_US   983040u
#define KRWB_US  999424u
#define KRHB_US  1000448u
#define XC_US    1001472u
#define ART2_US  3368960u

#define KS_US    0u
#define QS_US    1048576u
#define VTS_US   2097152u
#define ART1_US  7340032u

#define QSCALE 0.360673760f   // 0.25 * log2(e)
#define SHIFT2 17.3123405f    // 12 * log2(e)

__device__ __forceinline__ unsigned short f2bs(float f) {
  __hip_bfloat16 h = __float2bfloat16(f);
  return *reinterpret_cast<unsigned short*>(&h);
}

// ---------------------------------------------------------------------------
__global__ __launch_bounds__(256) void prep_kernel(
    const float* __restrict__ w_out, const float* __restrict__ w_kqv,
    const float* __restrict__ w_attn, const float* __restrict__ krw,
    const float* __restrict__ krh, unsigned short* __restrict__ ws) {
  int i = blockIdx.x * 256 + threadIdx.x;
  if (i < 884736) {              // WB2[t][coG][nt][kc][lane][8]
    int j = i & 7, l = (i >> 3) & 63, kc = (i >> 9) & 7, nt = (i >> 12) & 3;
    int r = i >> 14; int coG = r % 6, t = r / 6;
    int co = coG * 64 + nt * 16 + (l & 15);
    int ci = kc * 32 + (l >> 4) * 8 + j;
    ws[WB2_US + i] = f2bs(w_out[(size_t)co * 2304 + ci * 9 + t]);
  } else if (i < 983040) {       // WK2[coG][nt][kc][lane][8]
    int o = i - 884736;
    int j = o & 7, l = (o >> 3) & 63, kc = (o >> 9) & 7, nt = (o >> 12) & 3;
    int coG = o >> 14;
    int co = coG * 64 + nt * 16 + (l & 15);
    int ci = kc * 32 + (l >> 4) * 8 + j;
    ws[WK2_US + o] = f2bs(w_kqv[co * 256 + ci]);
  } else if (i < 999424) {       // WA2[coG][nt][kc][lane][8]
    int o = i - 983040;
    int j = o & 7, l = (o >> 3) & 63, kc = (o >> 9) & 3, nt = (o >> 11) & 3;
    int coG = o >> 13;
    int co = coG * 64 + nt * 16 + (l & 15);
    int ci = kc * 32 + (l >> 4) * 8 + j;
    ws[WA2_US + o] = f2bs(w_attn[co * 128 + ci]);
  } else if (i < 1000448) {      // krw bf16 [64][16], row 63 zero
    int j = i - 999424; int c = j >> 4, d = j & 15;
    ws[KRWB_US + j] = (c < 63) ? f2bs(krw[c * 16 + d]) : (unsigned short)0;
  } else if (i < 1001472) {
    int j = i - 1000448; int c = j >> 4, d = j & 15;
    ws[KRHB_US + j] = (c < 63) ? f2bs(krh[c * 16 + d]) : (unsigned short)0;
  }
}

// ---------------------------------------------------------------------------
__global__ __launch_bounds__(256) void zero_xc_kernel(unsigned short* __restrict__ xc) {
  int i = blockIdx.x * 256 + threadIdx.x;   // 295,936 uint4 = 2,367,488 us
  uint4 z = {0u, 0u, 0u, 0u};
  ((uint4*)xc)[i] = z;
}

// ---------------------------------------------------------------------------
// x [b][ci][pos] fp32 -> XC[b][ci>>5][y+1][x+1][ci&31] bf16 via LDS tile.
__global__ __launch_bounds__(256) void xt_kernel(
    const float* __restrict__ x, unsigned short* __restrict__ xc) {
  __shared__ float t[64][65];
  int tid = threadIdx.x; int pl = tid & 63, cg = tid >> 6;
  int pos0 = blockIdx.x * 64, ci0 = blockIdx.y * 64, b = blockIdx.z;
  const float* xb = x + ((size_t)(b * 256 + ci0)) * 1024 + pos0;
#pragma unroll
  for (int i = 0; i < 16; ++i) {
    int ci_l = cg * 16 + i;
    t[ci_l][pl] = xb[(size_t)ci_l * 1024 + pl];
  }
  __syncthreads();
#pragma unroll
  for (int i = 0; i < 16; ++i) {
    int pos_l = cg * 16 + i;
    int pos = pos0 + pos_l;
    int y = (pos >> 5) + 1, xx = (pos & 31) + 1;
    int ci = ci0 + pl;
    xc[((size_t)((b * 8 + (ci >> 5)) * 34 + y) * 34 + xx) * 32 + (ci & 31)] =
        f2bs(t[pl][pos_l]);
  }
}

// ---------------------------------------------------------------------------
// kqv GEMM: A-frags from XC (tap 1,1; contiguous 1KB loads), B from WK2.
// 4 waves/block; wave (mh,nh) owns the 2x2 quadrant (mt=mh*2+mi, nt=nh*2+ni).
__global__ __launch_bounds__(256) void kqv_mfma(
    const unsigned short* __restrict__ xc, const unsigned short* __restrict__ wk2,
    const float* __restrict__ bkqv, unsigned short* __restrict__ dq) {
  int tid = threadIdx.x;
  int lane = tid & 63; int il = lane & 15, q = lane >> 4;
  int wv = tid >> 6; int mh = wv >> 1, nh = wv & 1;
  int m0 = blockIdx.x * 64, coG = blockIdx.y;
  int b = m0 >> 10, pos0 = m0 & 1023;
  int row0 = pos0 >> 5;
  v4f acc[2][2];
#pragma unroll
  for (int mi = 0; mi < 2; ++mi)
#pragma unroll
    for (int ni = 0; ni < 2; ++ni) acc[mi][ni] = (v4f){0.f, 0.f, 0.f, 0.f};

  int pix[2];
#pragma unroll
  for (int mi = 0; mi < 2; ++mi)
    pix[mi] = (row0 + mh + 1) * 34 + (mi * 16 + il + 1);
  const unsigned short* bt = wk2 + (size_t)coG * 16384 + lane * 8;

#pragma unroll 4
  for (int kc = 0; kc < 8; ++kc) {
    v8s af[2], bf[2];
#pragma unroll
    for (int ni = 0; ni < 2; ++ni)
      bf[ni] = *(const v8s*)(bt + ((nh * 2 + ni) * 8 + kc) * 512);
#pragma unroll
    for (int mi = 0; mi < 2; ++mi)
      af[mi] = *(const v8s*)(xc + ((size_t)(b * 8 + kc) * 1156 + pix[mi]) * 32 + q * 8);
#pragma unroll
    for (int mi = 0; mi < 2; ++mi)
#pragma unroll
      for (int ni = 0; ni < 2; ++ni)
        acc[mi][ni] = __builtin_amdgcn_mfma_f32_16x16x32_bf16(
            af[mi], bf[ni], acc[mi][ni], 0, 0, 0);
  }
  int co0 = coG * 64;
#pragma unroll
  for (int ni = 0; ni < 2; ++ni) {
    int nt = nh * 2 + ni;
    int cob = co0 + nt * 16;
    int co = cob + il;
    float bias = bkqv[co];
    int cls = cob >> 7;                  // 0:k 1:q 2:v (uniform per nt)
    int h = (cob >> 4) & 7;
    size_t bh = (size_t)(b * 8 + h);
#pragma unroll
    for (int mi = 0; mi < 2; ++mi) {
      int mt = mh * 2 + mi;
      int pos = pos0 + mt * 16 + q * 4;
      v4f a = acc[mi][ni];
#pragma unroll
      for (int r = 0; r < 4; ++r) {
        float v = a[r] + bias;
        int p = pos + r;
        if (cls == 0)      dq[KS_US + bh * 16384 + p * 16 + il] = f2bs(v);
        else if (cls == 1) dq[QS_US + bh * 16384 + p * 16 + il] = f2bs(v * QSCALE);
        else               dq[VTS_US + bh * 16384 + ((p >> 5) * 16 + il) * 32 + (p & 31)] = f2bs(v);
      }
    }
  }
}

// ---------------------------------------------------------------------------
// MFMA attention, S-transposed formulation. Block 256 = 4 waves; wave owns a
// 16-row m-tile. Lane (q,il) reg r holds S[m0+il][nb+q*4+r].
__global__ __launch_bounds__(256) void attn_mfma(
    unsigned short* __restrict__ dq, const unsigned short* __restrict__ krwb,
    const unsigned short* __restrict__ krhb, unsigned short* __restrict__ wsart) {
  __shared__ float lds[4][2448];
  int tid = threadIdx.x; int w = tid >> 6, lane = tid & 63;
  int il = lane & 15, q = lane >> 4;
  int bh = blockIdx.y; int b = bh >> 3, h = bh & 7;
  int m0 = blockIdx.x * 64 + w * 16;
  int my = m0 >> 5, mxb = m0 & 31;
  float* pw = lds[w];                       // [16 rows][stride 64]
  float* ph = pw + 1024;                    // [16 rows][stride 68], - SHIFT2
  unsigned short* pl = (unsigned short*)(ph + 1088);  // [16 rows][stride 40] bf16

  const v8s z8 = {0, 0, 0, 0, 0, 0, 0, 0};
  const v4f z4 = {0.f, 0.f, 0.f, 0.f};

  // Q frag: A-layout for table build == B-layout for S^T (same registers).
  const unsigned short* qrow = dq + QS_US + (size_t)bh * 16384 + (m0 + il) * 16;
  v8s qa = *(const v8s*)(qrow + (q & 1) * 8);
  qa = (q < 2) ? qa : z8;

  // PW / PH tables via MFMA (C row = m-row in tile, col = table col)
#pragma unroll
  for (int nt = 0; nt < 4; ++nt) {
    int c = nt * 16 + il;
    v8s bw = *(const v8s*)(krwb + c * 16 + (q & 1) * 8);
    v8s bhh = *(const v8s*)(krhb + c * 16 + (q & 1) * 8);
    bw = (q < 2) ? bw : z8;
    bhh = (q < 2) ? bhh : z8;
    v4f pwc = __builtin_amdgcn_mfma_f32_16x16x32_bf16(qa, bw, z4, 0, 0, 0);
    v4f phc = __builtin_amdgcn_mfma_f32_16x16x32_bf16(qa, bhh, z4, 0, 0, 0);
#pragma unroll
    for (int r = 0; r < 4; ++r) {
      pw[(q * 4 + r) * 64 + c] = pwc[r];
      ph[(q * 4 + r) * 68 + c] = phc[r] - SHIFT2;
    }
  }
  __builtin_amdgcn_wave_barrier();

  // pw lookups are ny-invariant per lane in the transposed scheme: hoist.
  float pwv[2][4];
#pragma unroll
  for (int nt2 = 0; nt2 < 2; ++nt2)
#pragma unroll
    for (int r = 0; r < 4; ++r)
      pwv[nt2][r] = pw[il * 64 + (nt2 * 16 + q * 4 + r) - mxb - il + 31];

  v4f oacc = z4;
  float sacc = 0.f;
  const unsigned short* kbase = dq + KS_US + (size_t)bh * 16384;
  const unsigned short* vbase = dq + VTS_US + (size_t)bh * 16384;

  for (int ny = 0; ny < 32; ++ny) {
    float phv = ph[il * 68 + (ny - my + 31)];
    v4f s[2];
#pragma unroll
    for (int nt2 = 0; nt2 < 2; ++nt2) {
      v8s kb = *(const v8s*)(kbase + (ny * 32 + nt2 * 16 + il) * 16 + (q & 1) * 8);
      kb = (q < 2) ? kb : z8;
      s[nt2] = __builtin_amdgcn_mfma_f32_16x16x32_bf16(kb, qa, z4, 0, 0, 0);
    }
#pragma unroll
    for (int nt2 = 0; nt2 < 2; ++nt2) {
      float p[4];
#pragma unroll
      for (int r = 0; r < 4; ++r) {
        float t = s[nt2][r] + pwv[nt2][r] + phv;
        p[r] = exp2f(t);
        sacc += p[r];
      }
      uint2 pk;
      pk.x = (unsigned)f2bs(p[0]) | ((unsigned)f2bs(p[1]) << 16);
      pk.y = (unsigned)f2bs(p[2]) | ((unsigned)f2bs(p[3]) << 16);
      *(uint2*)(pl + il * 40 + nt2 * 16 + q * 4) = pk;
    }
    __builtin_amdgcn_wave_barrier();
    v8s pf = *(const v8s*)(pl + il * 40 + q * 8);
    v8s vb = *(const v8s*)(vbase + (ny * 16 + il) * 32 + q * 8);
    oacc = __builtin_amdgcn_mfma_f32_16x16x32_bf16(pf, vb, oacc, 0, 0, 0);
    __builtin_amdgcn_wave_barrier();
  }

  // row sums: lane holds partial for row il; combine quads, then fetch per-r.
  sacc += __shfl_xor(sacc, 16);
  sacc += __shfl_xor(sacc, 32);

  unsigned short* abase = (b < 6) ? (dq + ART1_US + (size_t)b * 131072)
                                  : (wsart + (size_t)(b - 6) * 131072);
#pragma unroll
  for (int r = 0; r < 4; ++r) {
    float sr = __shfl(sacc, q * 4 + r);       // full sum for row q*4+r
    int m = m0 + q * 4 + r;
    int c = h * 16 + (m >> 6);                // ci of art
    int pp = (m & 63) * 16 + il;              // pos' of art
    abase[((c >> 5) * 1024 + pp) * 32 + (c & 31)] = f2bs(oacc[r] / sr);
  }
}

// ---------------------------------------------------------------------------
// attn_out GEMM: A from artX (contiguous), B from WA2 (frag-major).
// 4 waves/block; wave (mh,nh) owns the 2x2 quadrant.
__global__ __launch_bounds__(256) void attn_out_mfma(
    const unsigned short* __restrict__ dq, const unsigned short* __restrict__ wsart,
    const unsigned short* __restrict__ wa2, const float* __restrict__ ba,
    float* __restrict__ out) {
  int tid = threadIdx.x;
  int lane = tid & 63; int il = lane & 15, q = lane >> 4;
  int wv = tid >> 6; int mh = wv >> 1, nh = wv & 1;
  int m0 = blockIdx.x * 64, coG = blockIdx.y;
  int b = m0 >> 10, pp0 = m0 & 1023;
  const unsigned short* ab = (b < 6) ? (dq + ART1_US + (size_t)b * 131072)
                                     : (wsart + (size_t)(b - 6) * 131072);
  const unsigned short* bt = wa2 + (size_t)coG * 8192 + lane * 8;
  v4f acc[2][2];
#pragma unroll
  for (int mi = 0; mi < 2; ++mi)
#pragma unroll
    for (int ni = 0; ni < 2; ++ni) acc[mi][ni] = (v4f){0.f, 0.f, 0.f, 0.f};
#pragma unroll
  for (int kc = 0; kc < 4; ++kc) {
    v8s af[2], bf[2];
#pragma unroll
    for (int ni = 0; ni < 2; ++ni)
      bf[ni] = *(const v8s*)(bt + ((nh * 2 + ni) * 4 + kc) * 512);
#pragma unroll
    for (int mi = 0; mi < 2; ++mi)
      af[mi] = *(const v8s*)(ab + (kc * 1024 + pp0 + (mh * 2 + mi) * 16 + il) * 32 + q * 8);
#pragma unroll
    for (int mi = 0; mi < 2; ++mi)
#pragma unroll
      for (int ni = 0; ni < 2; ++ni)
        acc[mi][ni] = __builtin_amdgcn_mfma_f32_16x16x32_bf16(
            af[mi], bf[ni], acc[mi][ni], 0, 0, 0);
  }
  int co0 = coG * 64;
#pragma unroll
  for (int ni = 0; ni < 2; ++ni) {
    int co = co0 + (nh * 2 + ni) * 16 + il;
    float bias = ba[co];
#pragma unroll
    for (int mi = 0; mi < 2; ++mi) {
      int mt = mh * 2 + mi;
      v4f a = acc[mi][ni];
      float4 v; v.x = a[0] + bias; v.y = a[1] + bias;
      v.z = a[2] + bias; v.w = a[3] + bias;
      *(float4*)(out + ((size_t)(b * 512 + 384 + co)) * 1024 + pp0 + mt * 16 + q * 4) = v;
    }
  }
}

// ---------------------------------------------------------------------------
// conv3x3 via MFMA, LDS-staged double-buffered pipeline (R2).
// Block: 64 pos x 96 cout, 256 thr = 4 waves; wave (mh,nh) = 2 m-frags x
// 3 n-frags. XC tile [4 rows][34 x][32 ci] staged once per kc (reused across
// 9 taps); weight tile [6 nf][512] staged per (tap,kc). Both double-buffered,
// reg-staged: issue global loads -> compute from LDS -> ds_write -> barrier.
// Grid (128,4): b = blockIdx.x & 7 pins batch to XCD (L2-resident 2.35MB).
__global__ __launch_bounds__(256) void conv_mfma(
    const unsigned short* __restrict__ xc, const unsigned short* __restrict__ wb2,
    const float* __restrict__ bo, float* __restrict__ out) {
  __shared__ unsigned short xcs[2][4352];   // [4 rows][34][32]
  __shared__ unsigned short wts[2][3072];   // [6 nf][64 lane][8]
  int tid = threadIdx.x;
  int lane = tid & 63; int il = lane & 15, q = lane >> 4;
  int wv = tid >> 6; int mh = wv >> 1, nh = wv & 1;
  int bx = blockIdx.x, nset = blockIdx.y;
  int b = bx & 7, ptb = bx >> 3;            // b fastest => XCD-pinned
  int pos0 = ptb * 64, y0 = ptb * 2;
  const unsigned short* xsrc = xc + ((size_t)(b * 8) * 1156 + y0 * 34) * 32;

  v4f acc[2][3];
#pragma unroll
  for (int mi = 0; mi < 2; ++mi)
#pragma unroll
    for (int j = 0; j < 3; ++j) acc[mi][j] = (v4f){0.f, 0.f, 0.f, 0.f};

  // weight fragment fetch: uint4 u of tile (tap,kc): nf = u>>6, lane-off = u&63
  auto wld = [&](int tap, int kc, int u) -> uint4 {
    int nf = u >> 6, off = u & 63;
    int nfg = nset * 6 + nf;
    int coG = nfg >> 2, nt = nfg & 3;
    return *(const uint4*)(wb2 +
        ((size_t)(((tap * 6 + coG) * 4 + nt) * 8 + kc) * 512 + off * 8));
  };

  // ---- prologue: stage xc[kc=0] and wt[tap=0,kc=0] into buffer 0
  {
    const uint4* g = (const uint4*)xsrc;
    uint4 a0 = g[tid], a1 = g[tid + 256];
    uint4 a2; if (tid < 32) a2 = g[tid + 512];
    ((uint4*)xcs[0])[tid] = a0;
    ((uint4*)xcs[0])[tid + 256] = a1;
    if (tid < 32) ((uint4*)xcs[0])[tid + 512] = a2;
    uint4 w0 = wld(0, 0, tid);
    uint4 w1; if (tid < 128) w1 = wld(0, 0, tid + 256);
    ((uint4*)wts[0])[tid] = w0;
    if (tid < 128) ((uint4*)wts[0])[tid + 256] = w1;
    __syncthreads();
  }

  int it = 0;
  for (int kc = 0; kc < 8; ++kc) {
    int xcur = kc & 1;
#pragma unroll
    for (int tap = 0; tap < 9; ++tap, ++it) {
      int cur = it & 1;
      bool last = (kc == 7) && (tap == 8);
      int tap_n = (tap == 8) ? 0 : tap + 1;
      int kc_n  = (tap == 8) ? kc + 1 : kc;
      bool stage_x = (tap == 8) && !last;

      // issue next-tile global loads (latency hides under MFMAs below)
      uint4 w0, w1, x0_, x1_, x2_;
      if (!last) {
        w0 = wld(tap_n, kc_n, tid);
        if (tid < 128) w1 = wld(tap_n, kc_n, tid + 256);
        if (stage_x) {
          const uint4* g = (const uint4*)(xsrc + (size_t)kc_n * 36992);
          x0_ = g[tid]; x1_ = g[tid + 256];
          if (tid < 32) x2_ = g[tid + 512];
        }
      }

      // compute current (tap,kc) from LDS
      int ky = tap / 3, kx = tap % 3;
      v8s af[2], bf[3];
#pragma unroll
      for (int mi = 0; mi < 2; ++mi)
        af[mi] = *(const v8s*)&xcs[xcur][((mh + ky) * 34 + mi * 16 + kx + il) * 32 + q * 8];
#pragma unroll
      for (int j = 0; j < 3; ++j)
        bf[j] = *(const v8s*)&wts[cur][(nh * 3 + j) * 512 + lane * 8];
#pragma unroll
      for (int mi = 0; mi < 2; ++mi)
#pragma unroll
        for (int j = 0; j < 3; ++j)
          acc[mi][j] = __builtin_amdgcn_mfma_f32_16x16x32_bf16(
              af[mi], bf[j], acc[mi][j], 0, 0, 0);

      // write next tiles into the other buffers, then sync
      if (!last) {
        unsigned short* wn = wts[cur ^ 1];
        ((uint4*)wn)[tid] = w0;
        if (tid < 128) ((uint4*)wn)[tid + 256] = w1;
        if (stage_x) {
          unsigned short* xn = xcs[xcur ^ 1];
          ((uint4*)xn)[tid] = x0_;
          ((uint4*)xn)[tid + 256] = x1_;
          if (tid < 32) ((uint4*)xn)[tid + 512] = x2_;
        }
        __syncthreads();
      }
    }
  }

  int co0 = nset * 96;
#pragma unroll
  for (int j = 0; j < 3; ++j) {
    int co = co0 + (nh * 3 + j) * 16 + il;
    float bias = bo[co];
#pragma unroll
    for (int mi = 0; mi < 2; ++mi) {
      int mf = mh * 2 + mi;
      v4f a = acc[mi][j];
      float4 v; v.x = a[0] + bias; v.y = a[1] + bias;
      v.z = a[2] + bias; v.w = a[3] + bias;
      *(float4*)(out + ((size_t)(b * 512 + co)) * 1024 + pos0 + mf * 16 + q * 4) = v;
    }
  }
}

// ---------------------------------------------------------------------------
extern "C" void kernel_launch(void* const* d_in, const int* in_sizes, int n_in,
                              void* d_out, int out_size, void* d_ws, size_t ws_size,
                              hipStream_t stream) {
  const float* x      = (const float*)d_in[0];
  const float* b_out  = (const float*)d_in[2];
  const float* b_kqv  = (const float*)d_in[4];
  const float* b_attn = (const float*)d_in[6];
  const float* krw    = (const float*)d_in[7];
  const float* krh    = (const float*)d_in[8];
  unsigned short* ws = (unsigned short*)d_ws;
  float* out = (float*)d_out;
  unsigned short* dq = (unsigned short*)d_out;

  prep_kernel<<<3912, 256, 0, stream>>>(
      (const float*)d_in[1], (const float*)d_in[3], (const float*)d_in[5],
      krw, krh, ws);
  zero_xc_kernel<<<1156, 256, 0, stream>>>(ws + XC_US);
  xt_kernel<<<dim3(16, 4, 8), 256, 0, stream>>>(x, ws + XC_US);
  kqv_mfma<<<dim3(128, 6), 256, 0, stream>>>(
      ws + XC_US, ws + WK2_US, b_kqv, dq);
  attn_mfma<<<dim3(16, 64), 256, 0, stream>>>(
      dq, ws + KRWB_US, ws + KRHB_US, ws + ART2_US);
  attn_out_mfma<<<dim3(128, 2), 256, 0, stream>>>(
      dq, ws + ART2_US, ws + WA2_US, b_attn, out);
  conv_mfma<<<dim3(128, 4), 256, 0, stream>>>(
      ws + XC_US, ws + WB2_US, b_out, out);
}

// Round 3
// 166.761 us; speedup vs baseline: 1.0982x; 1.0383x over previous
//
#include <hip/hip_runtime.h>
#include <hip/hip_bf16.h>

// ---------------------------------------------------------------------------
// SelfAttention2d, fully-MFMA pipeline, fragment-major memory layouts.
// MFMA 16x16x32 bf16: A[m=il][k=q*8+j], B[col=il][k=q*8+j], C[row=q*4+r][col=il]
//
// R3: conv_mfma v3. R2 evidence: LDS dbuf with per-tap barriers gave only
// 45->39us (72 barriers x 6 MFMA/wave each; weight-LDS staging has no
// multicast value since each frag feeds ONE wave). New structure:
//   - weights: DIRECT global loads per wave (L2/L1-hot), 2-deep rolling
//     register prefetch (3 slots, tap%3 compile-time), zero barriers;
//   - X: LDS (shared across waves), staged per kc via global_load_lds,
//     dbuf, ONE barrier per kc (8 total, 54 MFMA/wave per window);
//   - LDS layout [row][q][x][8ci]: ds_read_b128 is consecutive-16B-per-lane
//     (conflict-free, no swizzle); source permutation folded into the
//     per-lane global_load_lds address (linear dest + permuted src);
//   - block 128 pos x 96 cout, 512 thr = 8 waves (4mh x 2nh, wave 32x48);
//     grid (64,4)=256 blocks, b = bx&7 pins batch to XCD.
//
// Attention computes S TRANSPOSED (A=K, B=Q) so each lane holds
// S[m=m0+il][n=nb+q*4+r]:  pw lookups become ny-invariant registers, ph is one
// read/ny, and P needs only an 8B LDS write + b128 read to become the PV
// A-operand (full K=32).
//
// Layouts:
//   XC   [b][kc 0..7][y 0..33][x 0..33][ci 32]  zero-padded image, bf16
//   WB2  [t9][coG6][nt4][kc8][lane64][8]        w_out frag-major
//   WK2  [coG6][nt4][kc8][lane64][8]            w_kqv frag-major
//   WA2  [coG2][nt4][kc4][lane64][8]            w_attn frag-major
//   VT   [bh][ny32][d16][ci 32]                 V^T frag-major
//   artX [b][kc4][pp1024][ci32]                 attn out, frag-major
//
// ws (ushort units, 7,262,208 B <= proven-safe 8,192,000):
//   WB2 0 / WK2 884736 / WA2 983040 / KRWB 999424 / KRHB 1000448 /
//   XC 1001472 (2,367,488) / ART2 3368960 (b=6,7 slots)
// d_out scratch (ushort): KS 0 / QS 1048576 / VT 2097152 / ART1 7340032 (b0..5)
// Order: prep -> zero_xc -> xt -> kqv -> attn -> attn_out -> conv
// ---------------------------------------------------------------------------

typedef short v8s __attribute__((ext_vector_type(8)));
typedef float v4f __attribute__((ext_vector_type(4)));

#define WB2_US   0u
#define WK2_US   884736u
#define WA2_US   983040u
#define KRWB_US  999424u
#define KRHB_US  1000448u
#define XC_US    1001472u
#define ART2_US  3368960u

#define KS_US    0u
#define QS_US    1048576u
#define VTS_US   2097152u
#define ART1_US  7340032u

#define QSCALE 0.360673760f   // 0.25 * log2(e)
#define SHIFT2 17.3123405f    // 12 * log2(e)

__device__ __forceinline__ unsigned short f2bs(float f) {
  __hip_bfloat16 h = __float2bfloat16(f);
  return *reinterpret_cast<unsigned short*>(&h);
}

// ---------------------------------------------------------------------------
__global__ __launch_bounds__(256) void prep_kernel(
    const float* __restrict__ w_out, const float* __restrict__ w_kqv,
    const float* __restrict__ w_attn, const float* __restrict__ krw,
    const float* __restrict__ krh, unsigned short* __restrict__ ws) {
  int i = blockIdx.x * 256 + threadIdx.x;
  if (i < 884736) {              // WB2[t][coG][nt][kc][lane][8]
    int j = i & 7, l = (i >> 3) & 63, kc = (i >> 9) & 7, nt = (i >> 12) & 3;
    int r = i >> 14; int coG = r % 6, t = r / 6;
    int co = coG * 64 + nt * 16 + (l & 15);
    int ci = kc * 32 + (l >> 4) * 8 + j;
    ws[WB2_US + i] = f2bs(w_out[(size_t)co * 2304 + ci * 9 + t]);
  } else if (i < 983040) {       // WK2[coG][nt][kc][lane][8]
    int o = i - 884736;
    int j = o & 7, l = (o >> 3) & 63, kc = (o >> 9) & 7, nt = (o >> 12) & 3;
    int coG = o >> 14;
    int co = coG * 64 + nt * 16 + (l & 15);
    int ci = kc * 32 + (l >> 4) * 8 + j;
    ws[WK2_US + o] = f2bs(w_kqv[co * 256 + ci]);
  } else if (i < 999424) {       // WA2[coG][nt][kc][lane][8]
    int o = i - 983040;
    int j = o & 7, l = (o >> 3) & 63, kc = (o >> 9) & 3, nt = (o >> 11) & 3;
    int coG = o >> 13;
    int co = coG * 64 + nt * 16 + (l & 15);
    int ci = kc * 32 + (l >> 4) * 8 + j;
    ws[WA2_US + o] = f2bs(w_attn[co * 128 + ci]);
  } else if (i < 1000448) {      // krw bf16 [64][16], row 63 zero
    int j = i - 999424; int c = j >> 4, d = j & 15;
    ws[KRWB_US + j] = (c < 63) ? f2bs(krw[c * 16 + d]) : (unsigned short)0;
  } else if (i < 1001472) {
    int j = i - 1000448; int c = j >> 4, d = j & 15;
    ws[KRHB_US + j] = (c < 63) ? f2bs(krh[c * 16 + d]) : (unsigned short)0;
  }
}

// ---------------------------------------------------------------------------
__global__ __launch_bounds__(256) void zero_xc_kernel(unsigned short* __restrict__ xc) {
  int i = blockIdx.x * 256 + threadIdx.x;   // 295,936 uint4 = 2,367,488 us
  uint4 z = {0u, 0u, 0u, 0u};
  ((uint4*)xc)[i] = z;
}

// ---------------------------------------------------------------------------
// x [b][ci][pos] fp32 -> XC[b][ci>>5][y+1][x+1][ci&31] bf16 via LDS tile.
__global__ __launch_bounds__(256) void xt_kernel(
    const float* __restrict__ x, unsigned short* __restrict__ xc) {
  __shared__ float t[64][65];
  int tid = threadIdx.x; int pl = tid & 63, cg = tid >> 6;
  int pos0 = blockIdx.x * 64, ci0 = blockIdx.y * 64, b = blockIdx.z;
  const float* xb = x + ((size_t)(b * 256 + ci0)) * 1024 + pos0;
#pragma unroll
  for (int i = 0; i < 16; ++i) {
    int ci_l = cg * 16 + i;
    t[ci_l][pl] = xb[(size_t)ci_l * 1024 + pl];
  }
  __syncthreads();
#pragma unroll
  for (int i = 0; i < 16; ++i) {
    int pos_l = cg * 16 + i;
    int pos = pos0 + pos_l;
    int y = (pos >> 5) + 1, xx = (pos & 31) + 1;
    int ci = ci0 + pl;
    xc[((size_t)((b * 8 + (ci >> 5)) * 34 + y) * 34 + xx) * 32 + (ci & 31)] =
        f2bs(t[pl][pos_l]);
  }
}

// ---------------------------------------------------------------------------
// kqv GEMM: A-frags from XC (tap 1,1; contiguous 1KB loads), B from WK2.
// 4 waves/block; wave (mh,nh) owns the 2x2 quadrant (mt=mh*2+mi, nt=nh*2+ni).
__global__ __launch_bounds__(256) void kqv_mfma(
    const unsigned short* __restrict__ xc, const unsigned short* __restrict__ wk2,
    const float* __restrict__ bkqv, unsigned short* __restrict__ dq) {
  int tid = threadIdx.x;
  int lane = tid & 63; int il = lane & 15, q = lane >> 4;
  int wv = tid >> 6; int mh = wv >> 1, nh = wv & 1;
  int m0 = blockIdx.x * 64, coG = blockIdx.y;
  int b = m0 >> 10, pos0 = m0 & 1023;
  int row0 = pos0 >> 5;
  v4f acc[2][2];
#pragma unroll
  for (int mi = 0; mi < 2; ++mi)
#pragma unroll
    for (int ni = 0; ni < 2; ++ni) acc[mi][ni] = (v4f){0.f, 0.f, 0.f, 0.f};

  int pix[2];
#pragma unroll
  for (int mi = 0; mi < 2; ++mi)
    pix[mi] = (row0 + mh + 1) * 34 + (mi * 16 + il + 1);
  const unsigned short* bt = wk2 + (size_t)coG * 16384 + lane * 8;

#pragma unroll 4
  for (int kc = 0; kc < 8; ++kc) {
    v8s af[2], bf[2];
#pragma unroll
    for (int ni = 0; ni < 2; ++ni)
      bf[ni] = *(const v8s*)(bt + ((nh * 2 + ni) * 8 + kc) * 512);
#pragma unroll
    for (int mi = 0; mi < 2; ++mi)
      af[mi] = *(const v8s*)(xc + ((size_t)(b * 8 + kc) * 1156 + pix[mi]) * 32 + q * 8);
#pragma unroll
    for (int mi = 0; mi < 2; ++mi)
#pragma unroll
      for (int ni = 0; ni < 2; ++ni)
        acc[mi][ni] = __builtin_amdgcn_mfma_f32_16x16x32_bf16(
            af[mi], bf[ni], acc[mi][ni], 0, 0, 0);
  }
  int co0 = coG * 64;
#pragma unroll
  for (int ni = 0; ni < 2; ++ni) {
    int nt = nh * 2 + ni;
    int cob = co0 + nt * 16;
    int co = cob + il;
    float bias = bkqv[co];
    int cls = cob >> 7;                  // 0:k 1:q 2:v (uniform per nt)
    int h = (cob >> 4) & 7;
    size_t bh = (size_t)(b * 8 + h);
#pragma unroll
    for (int mi = 0; mi < 2; ++mi) {
      int mt = mh * 2 + mi;
      int pos = pos0 + mt * 16 + q * 4;
      v4f a = acc[mi][ni];
#pragma unroll
      for (int r = 0; r < 4; ++r) {
        float v = a[r] + bias;
        int p = pos + r;
        if (cls == 0)      dq[KS_US + bh * 16384 + p * 16 + il] = f2bs(v);
        else if (cls == 1) dq[QS_US + bh * 16384 + p * 16 + il] = f2bs(v * QSCALE);
        else               dq[VTS_US + bh * 16384 + ((p >> 5) * 16 + il) * 32 + (p & 31)] = f2bs(v);
      }
    }
  }
}

// ---------------------------------------------------------------------------
// MFMA attention, S-transposed formulation. Block 256 = 4 waves; wave owns a
// 16-row m-tile. Lane (q,il) reg r holds S[m0+il][nb+q*4+r].
__global__ __launch_bounds__(256) void attn_mfma(
    unsigned short* __restrict__ dq, const unsigned short* __restrict__ krwb,
    const unsigned short* __restrict__ krhb, unsigned short* __restrict__ wsart) {
  __shared__ float lds[4][2448];
  int tid = threadIdx.x; int w = tid >> 6, lane = tid & 63;
  int il = lane & 15, q = lane >> 4;
  int bh = blockIdx.y; int b = bh >> 3, h = bh & 7;
  int m0 = blockIdx.x * 64 + w * 16;
  int my = m0 >> 5, mxb = m0 & 31;
  float* pw = lds[w];                       // [16 rows][stride 64]
  float* ph = pw + 1024;                    // [16 rows][stride 68], - SHIFT2
  unsigned short* pl = (unsigned short*)(ph + 1088);  // [16 rows][stride 40] bf16

  const v8s z8 = {0, 0, 0, 0, 0, 0, 0, 0};
  const v4f z4 = {0.f, 0.f, 0.f, 0.f};

  // Q frag: A-layout for table build == B-layout for S^T (same registers).
  const unsigned short* qrow = dq + QS_US + (size_t)bh * 16384 + (m0 + il) * 16;
  v8s qa = *(const v8s*)(qrow + (q & 1) * 8);
  qa = (q < 2) ? qa : z8;

  // PW / PH tables via MFMA (C row = m-row in tile, col = table col)
#pragma unroll
  for (int nt = 0; nt < 4; ++nt) {
    int c = nt * 16 + il;
    v8s bw = *(const v8s*)(krwb + c * 16 + (q & 1) * 8);
    v8s bhh = *(const v8s*)(krhb + c * 16 + (q & 1) * 8);
    bw = (q < 2) ? bw : z8;
    bhh = (q < 2) ? bhh : z8;
    v4f pwc = __builtin_amdgcn_mfma_f32_16x16x32_bf16(qa, bw, z4, 0, 0, 0);
    v4f phc = __builtin_amdgcn_mfma_f32_16x16x32_bf16(qa, bhh, z4, 0, 0, 0);
#pragma unroll
    for (int r = 0; r < 4; ++r) {
      pw[(q * 4 + r) * 64 + c] = pwc[r];
      ph[(q * 4 + r) * 68 + c] = phc[r] - SHIFT2;
    }
  }
  __builtin_amdgcn_wave_barrier();

  // pw lookups are ny-invariant per lane in the transposed scheme: hoist.
  float pwv[2][4];
#pragma unroll
  for (int nt2 = 0; nt2 < 2; ++nt2)
#pragma unroll
    for (int r = 0; r < 4; ++r)
      pwv[nt2][r] = pw[il * 64 + (nt2 * 16 + q * 4 + r) - mxb - il + 31];

  v4f oacc = z4;
  float sacc = 0.f;
  const unsigned short* kbase = dq + KS_US + (size_t)bh * 16384;
  const unsigned short* vbase = dq + VTS_US + (size_t)bh * 16384;

  for (int ny = 0; ny < 32; ++ny) {
    float phv = ph[il * 68 + (ny - my + 31)];
    v4f s[2];
#pragma unroll
    for (int nt2 = 0; nt2 < 2; ++nt2) {
      v8s kb = *(const v8s*)(kbase + (ny * 32 + nt2 * 16 + il) * 16 + (q & 1) * 8);
      kb = (q < 2) ? kb : z8;
      s[nt2] = __builtin_amdgcn_mfma_f32_16x16x32_bf16(kb, qa, z4, 0, 0, 0);
    }
#pragma unroll
    for (int nt2 = 0; nt2 < 2; ++nt2) {
      float p[4];
#pragma unroll
      for (int r = 0; r < 4; ++r) {
        float t = s[nt2][r] + pwv[nt2][r] + phv;
        p[r] = exp2f(t);
        sacc += p[r];
      }
      uint2 pk;
      pk.x = (unsigned)f2bs(p[0]) | ((unsigned)f2bs(p[1]) << 16);
      pk.y = (unsigned)f2bs(p[2]) | ((unsigned)f2bs(p[3]) << 16);
      *(uint2*)(pl + il * 40 + nt2 * 16 + q * 4) = pk;
    }
    __builtin_amdgcn_wave_barrier();
    v8s pf = *(const v8s*)(pl + il * 40 + q * 8);
    v8s vb = *(const v8s*)(vbase + (ny * 16 + il) * 32 + q * 8);
    oacc = __builtin_amdgcn_mfma_f32_16x16x32_bf16(pf, vb, oacc, 0, 0, 0);
    __builtin_amdgcn_wave_barrier();
  }

  // row sums: lane holds partial for row il; combine quads, then fetch per-r.
  sacc += __shfl_xor(sacc, 16);
  sacc += __shfl_xor(sacc, 32);

  unsigned short* abase = (b < 6) ? (dq + ART1_US + (size_t)b * 131072)
                                  : (wsart + (size_t)(b - 6) * 131072);
#pragma unroll
  for (int r = 0; r < 4; ++r) {
    float sr = __shfl(sacc, q * 4 + r);       // full sum for row q*4+r
    int m = m0 + q * 4 + r;
    int c = h * 16 + (m >> 6);                // ci of art
    int pp = (m & 63) * 16 + il;              // pos' of art
    abase[((c >> 5) * 1024 + pp) * 32 + (c & 31)] = f2bs(oacc[r] / sr);
  }
}

// ---------------------------------------------------------------------------
// attn_out GEMM: A from artX (contiguous), B from WA2 (frag-major).
// 4 waves/block; wave (mh,nh) owns the 2x2 quadrant.
__global__ __launch_bounds__(256) void attn_out_mfma(
    const unsigned short* __restrict__ dq, const unsigned short* __restrict__ wsart,
    const unsigned short* __restrict__ wa2, const float* __restrict__ ba,
    float* __restrict__ out) {
  int tid = threadIdx.x;
  int lane = tid & 63; int il = lane & 15, q = lane >> 4;
  int wv = tid >> 6; int mh = wv >> 1, nh = wv & 1;
  int m0 = blockIdx.x * 64, coG = blockIdx.y;
  int b = m0 >> 10, pp0 = m0 & 1023;
  const unsigned short* ab = (b < 6) ? (dq + ART1_US + (size_t)b * 131072)
                                     : (wsart + (size_t)(b - 6) * 131072);
  const unsigned short* bt = wa2 + (size_t)coG * 8192 + lane * 8;
  v4f acc[2][2];
#pragma unroll
  for (int mi = 0; mi < 2; ++mi)
#pragma unroll
    for (int ni = 0; ni < 2; ++ni) acc[mi][ni] = (v4f){0.f, 0.f, 0.f, 0.f};
#pragma unroll
  for (int kc = 0; kc < 4; ++kc) {
    v8s af[2], bf[2];
#pragma unroll
    for (int ni = 0; ni < 2; ++ni)
      bf[ni] = *(const v8s*)(bt + ((nh * 2 + ni) * 4 + kc) * 512);
#pragma unroll
    for (int mi = 0; mi < 2; ++mi)
      af[mi] = *(const v8s*)(ab + (kc * 1024 + pp0 + (mh * 2 + mi) * 16 + il) * 32 + q * 8);
#pragma unroll
    for (int mi = 0; mi < 2; ++mi)
#pragma unroll
      for (int ni = 0; ni < 2; ++ni)
        acc[mi][ni] = __builtin_amdgcn_mfma_f32_16x16x32_bf16(
            af[mi], bf[ni], acc[mi][ni], 0, 0, 0);
  }
  int co0 = coG * 64;
#pragma unroll
  for (int ni = 0; ni < 2; ++ni) {
    int co = co0 + (nh * 2 + ni) * 16 + il;
    float bias = ba[co];
#pragma unroll
    for (int mi = 0; mi < 2; ++mi) {
      int mt = mh * 2 + mi;
      v4f a = acc[mi][ni];
      float4 v; v.x = a[0] + bias; v.y = a[1] + bias;
      v.z = a[2] + bias; v.w = a[3] + bias;
      *(float4*)(out + ((size_t)(b * 512 + 384 + co)) * 1024 + pp0 + mt * 16 + q * 4) = v;
    }
  }
}

// ---------------------------------------------------------------------------
// conv3x3 via MFMA (R3). Block 128 pos x 96 cout, 512 thr = 8 waves
// (mh=wv>>1 picks 32-pos row, nh=wv&1 picks 48-cout half; wave tile 2m x 3n).
// X: LDS [row6][q4][x34][8ci] per kc, dbuf, staged via global_load_lds with
// source-permuted per-lane addresses (dest linear); ONE barrier per kc.
// Weights: direct global v8s loads, 3-slot rolling prefetch 2 taps ahead
// (slot = tap%3, compile-time since 9 % 3 == 0). 54 MFMA/wave per barrier.
// Grid (64,4): b = bx&7 pins batch to XCD.
__global__ __launch_bounds__(512) void conv_mfma(
    const unsigned short* __restrict__ xc, const unsigned short* __restrict__ wb2,
    const float* __restrict__ bo, float* __restrict__ out) {
  __shared__ unsigned short xcs[2][6656];   // 6 rows x 4 q x 34 x 8 = 6528 + pad
  int tid = threadIdx.x;
  int lane = tid & 63; int il = lane & 15, q = lane >> 4;
  int wv = tid >> 6; int mh = wv >> 1, nh = wv & 1;
  int bx = blockIdx.x, nset = blockIdx.y;
  int b = bx & 7, pt = bx >> 3;             // b fastest => XCD-pinned
  int pos0 = pt * 128, y0 = pt * 4;
  const unsigned short* xb = xc + ((size_t)(b * 8) * 1156 + y0 * 34) * 32;

  v4f acc[2][3];
#pragma unroll
  for (int mi = 0; mi < 2; ++mi)
#pragma unroll
    for (int j = 0; j < 3; ++j) acc[mi][j] = (v4f){0.f, 0.f, 0.f, 0.f};

  // ---- X staging: lds chunk C=(row*4+q)*34+x holds XC chunk row*136+x*4+q
  auto stageX = [&](int buf, int kc) {
    const unsigned short* src = xb + (size_t)kc * 36992;   // 1156*32
#pragma unroll
    for (int t = 0; t < 2; ++t) {
      int s = wv + t * 8;
      if (s < 13) {
        int C = s * 64 + lane;
        int row = C / 136, rem = C % 136;
        int qv = rem / 34, xx = rem % 34;
        const unsigned short* g = src + ((row * 136 + xx * 4 + qv) << 3);
        __builtin_amdgcn_global_load_lds(
            (const __attribute__((address_space(1))) void*)g,
            (__attribute__((address_space(3))) void*)(&xcs[buf][s * 512]),
            16, 0, 0);
      }
    }
  };

  // ---- weight frag fetch: direct global (L2/L1-hot)
  auto wfrag = [&](int tap, int kc, int j) -> v8s {
    int nfg = nset * 6 + nh * 3 + j;
    int coG = nfg >> 2, nt = nfg & 3;
    return *(const v8s*)(wb2 +
        ((size_t)(((tap * 6 + coG) * 4 + nt) * 8 + kc) * 512 + lane * 8));
  };

  // prologue: stage X[kc=0]; preload weight slots for taps 0,1
  stageX(0, 0);
  v8s bS[3][3];
#pragma unroll
  for (int j = 0; j < 3; ++j) bS[0][j] = wfrag(0, 0, j);
#pragma unroll
  for (int j = 0; j < 3; ++j) bS[1][j] = wfrag(1, 0, j);
  __syncthreads();

  for (int kc = 0; kc < 8; ++kc) {
    int buf = kc & 1;
    if (kc < 7) stageX(buf ^ 1, kc + 1);    // async, drains at the barrier
#pragma unroll
    for (int tap = 0; tap < 9; ++tap) {
      // prefetch tap+2 (rolls into next kc's taps 0,1) into slot (tap+2)%3
      if (tap < 7 || kc < 7) {
        int t2 = tap + 2, k2 = kc;
        if (t2 >= 9) { t2 -= 9; ++k2; }
#pragma unroll
        for (int j = 0; j < 3; ++j) bS[(tap + 2) % 3][j] = wfrag(t2, k2, j);
      }
      int ky = tap / 3, kx = tap % 3;
      v8s af[2];
#pragma unroll
      for (int mi = 0; mi < 2; ++mi)
        af[mi] = *(const v8s*)&xcs[buf][((mh + ky) * 4 + q) * 272 +
                                        (mi * 16 + kx + il) * 8];
#pragma unroll
      for (int mi = 0; mi < 2; ++mi)
#pragma unroll
        for (int j = 0; j < 3; ++j)
          acc[mi][j] = __builtin_amdgcn_mfma_f32_16x16x32_bf16(
              af[mi], bS[tap % 3][j], acc[mi][j], 0, 0, 0);
    }
    __syncthreads();
  }

  int co0 = nset * 96;
#pragma unroll
  for (int j = 0; j < 3; ++j) {
    int co = co0 + (nh * 3 + j) * 16 + il;
    float bias = bo[co];
#pragma unroll
    for (int mi = 0; mi < 2; ++mi) {
      v4f a = acc[mi][j];
      float4 v; v.x = a[0] + bias; v.y = a[1] + bias;
      v.z = a[2] + bias; v.w = a[3] + bias;
      *(float4*)(out + ((size_t)(b * 512 + co)) * 1024 +
                 pos0 + mh * 32 + mi * 16 + q * 4) = v;
    }
  }
}

// ---------------------------------------------------------------------------
extern "C" void kernel_launch(void* const* d_in, const int* in_sizes, int n_in,
                              void* d_out, int out_size, void* d_ws, size_t ws_size,
                              hipStream_t stream) {
  const float* x      = (const float*)d_in[0];
  const float* b_out  = (const float*)d_in[2];
  const float* b_kqv  = (const float*)d_in[4];
  const float* b_attn = (const float*)d_in[6];
  const float* krw    = (const float*)d_in[7];
  const float* krh    = (const float*)d_in[8];
  unsigned short* ws = (unsigned short*)d_ws;
  float* out = (float*)d_out;
  unsigned short* dq = (unsigned short*)d_out;

  prep_kernel<<<3912, 256, 0, stream>>>(
      (const float*)d_in[1], (const float*)d_in[3], (const float*)d_in[5],
      krw, krh, ws);
  zero_xc_kernel<<<1156, 256, 0, stream>>>(ws + XC_US);
  xt_kernel<<<dim3(16, 4, 8), 256, 0, stream>>>(x, ws + XC_US);
  kqv_mfma<<<dim3(128, 6), 256, 0, stream>>>(
      ws + XC_US, ws + WK2_US, b_kqv, dq);
  attn_mfma<<<dim3(16, 64), 256, 0, stream>>>(
      dq, ws + KRWB_US, ws + KRHB_US, ws + ART2_US);
  attn_out_mfma<<<dim3(128, 2), 256, 0, stream>>>(
      dq, ws + ART2_US, ws + WA2_US, b_attn, out);
  conv_mfma<<<dim3(64, 4), 512, 0, stream>>>(
      ws + XC_US, ws + WB2_US, b_out, out);
}

// Round 4
// 160.746 us; speedup vs baseline: 1.1393x; 1.0374x over previous
//
#include <hip/hip_runtime.h>
#include <hip/hip_bf16.h>

// ---------------------------------------------------------------------------
// SelfAttention2d, fully-MFMA pipeline, fragment-major memory layouts.
// MFMA 16x16x32 bf16: A[m=il][k=q*8+j], B[col=il][k=q*8+j], C[row=q*4+r][col=il]
//
// R4: (a) conv_mfma occupancy fix: 256-thr 4-wave blocks (64 pos x 96 cout,
// wave tile 32x48 unchanged), grid (128,4) = 512 blocks = 2 blocks/CU so the
// per-kc barrier drain overlaps with the co-resident block (m114 mechanism;
// R3 at 1 block/CU exposed every stall). (b) weight layout WB3
// [coG][nt][kc][tap][lane][8]: per-wave weight stream is a linear pointer
// walk (+512/iter, monotone over all 72 iters) instead of a 5-term address
// recompute per load. (c) attn_mfma: depth-1 register prefetch of next-ny
// K/V fragments so ~300cy L2 latency hides under softmax VALU + MFMA.
//
// Attention computes S TRANSPOSED (A=K, B=Q) so each lane holds
// S[m=m0+il][n=nb+q*4+r]:  pw lookups become ny-invariant registers, ph is one
// read/ny, and P needs only an 8B LDS write + b128 read to become the PV
// A-operand (full K=32).
//
// Layouts:
//   XC   [b][kc 0..7][y 0..33][x 0..33][ci 32]  zero-padded image, bf16
//   WB3  [coG6][nt4][kc8][tap9][lane64][8]      w_out frag-major, linear walk
//   WK2  [coG6][nt4][kc8][lane64][8]            w_kqv frag-major
//   WA2  [coG2][nt4][kc4][lane64][8]            w_attn frag-major
//   VT   [bh][ny32][d16][ci 32]                 V^T frag-major
//   artX [b][kc4][pp1024][ci32]                 attn out, frag-major
//
// ws (ushort units, 7,262,208 B <= proven-safe 8,192,000):
//   WB3 0 / WK2 884736 / WA2 983040 / KRWB 999424 / KRHB 1000448 /
//   XC 1001472 (2,367,488) / ART2 3368960 (b=6,7 slots)
// d_out scratch (ushort): KS 0 / QS 1048576 / VT 2097152 / ART1 7340032 (b0..5)
// Order: prep -> zero_xc -> xt -> kqv -> attn -> attn_out -> conv
// ---------------------------------------------------------------------------

typedef short v8s __attribute__((ext_vector_type(8)));
typedef float v4f __attribute__((ext_vector_type(4)));

#define WB2_US   0u
#define WK2_US   884736u
#define WA2_US   983040u
#define KRWB_US  999424u
#define KRHB_US  1000448u
#define XC_US    1001472u
#define ART2_US  3368960u

#define KS_US    0u
#define QS_US    1048576u
#define VTS_US   2097152u
#define ART1_US  7340032u

#define QSCALE 0.360673760f   // 0.25 * log2(e)
#define SHIFT2 17.3123405f    // 12 * log2(e)

__device__ __forceinline__ unsigned short f2bs(float f) {
  __hip_bfloat16 h = __float2bfloat16(f);
  return *reinterpret_cast<unsigned short*>(&h);
}

// ---------------------------------------------------------------------------
__global__ __launch_bounds__(256) void prep_kernel(
    const float* __restrict__ w_out, const float* __restrict__ w_kqv,
    const float* __restrict__ w_attn, const float* __restrict__ krw,
    const float* __restrict__ krh, unsigned short* __restrict__ ws) {
  int i = blockIdx.x * 256 + threadIdx.x;
  if (i < 884736) {              // WB3[coG][nt][kc][tap][lane][8]
    int j = i & 7, l = (i >> 3) & 63;
    int r = i >> 9;              // fragment chunk index [coG][nt][kc][tap]
    int tap = r % 9; int r2 = r / 9;
    int kc = r2 & 7, nt = (r2 >> 3) & 3, coG = r2 >> 5;
    int co = coG * 64 + nt * 16 + (l & 15);
    int ci = kc * 32 + (l >> 4) * 8 + j;
    ws[WB2_US + i] = f2bs(w_out[(size_t)co * 2304 + ci * 9 + tap]);
  } else if (i < 983040) {       // WK2[coG][nt][kc][lane][8]
    int o = i - 884736;
    int j = o & 7, l = (o >> 3) & 63, kc = (o >> 9) & 7, nt = (o >> 12) & 3;
    int coG = o >> 14;
    int co = coG * 64 + nt * 16 + (l & 15);
    int ci = kc * 32 + (l >> 4) * 8 + j;
    ws[WK2_US + o] = f2bs(w_kqv[co * 256 + ci]);
  } else if (i < 999424) {       // WA2[coG][nt][kc][lane][8]
    int o = i - 983040;
    int j = o & 7, l = (o >> 3) & 63, kc = (o >> 9) & 3, nt = (o >> 11) & 3;
    int coG = o >> 13;
    int co = coG * 64 + nt * 16 + (l & 15);
    int ci = kc * 32 + (l >> 4) * 8 + j;
    ws[WA2_US + o] = f2bs(w_attn[co * 128 + ci]);
  } else if (i < 1000448) {      // krw bf16 [64][16], row 63 zero
    int j = i - 999424; int c = j >> 4, d = j & 15;
    ws[KRWB_US + j] = (c < 63) ? f2bs(krw[c * 16 + d]) : (unsigned short)0;
  } else if (i < 1001472) {
    int j = i - 1000448; int c = j >> 4, d = j & 15;
    ws[KRHB_US + j] = (c < 63) ? f2bs(krh[c * 16 + d]) : (unsigned short)0;
  }
}

// ---------------------------------------------------------------------------
__global__ __launch_bounds__(256) void zero_xc_kernel(unsigned short* __restrict__ xc) {
  int i = blockIdx.x * 256 + threadIdx.x;   // 295,936 uint4 = 2,367,488 us
  uint4 z = {0u, 0u, 0u, 0u};
  ((uint4*)xc)[i] = z;
}

// ---------------------------------------------------------------------------
// x [b][ci][pos] fp32 -> XC[b][ci>>5][y+1][x+1][ci&31] bf16 via LDS tile.
__global__ __launch_bounds__(256) void xt_kernel(
    const float* __restrict__ x, unsigned short* __restrict__ xc) {
  __shared__ float t[64][65];
  int tid = threadIdx.x; int pl = tid & 63, cg = tid >> 6;
  int pos0 = blockIdx.x * 64, ci0 = blockIdx.y * 64, b = blockIdx.z;
  const float* xb = x + ((size_t)(b * 256 + ci0)) * 1024 + pos0;
#pragma unroll
  for (int i = 0; i < 16; ++i) {
    int ci_l = cg * 16 + i;
    t[ci_l][pl] = xb[(size_t)ci_l * 1024 + pl];
  }
  __syncthreads();
#pragma unroll
  for (int i = 0; i < 16; ++i) {
    int pos_l = cg * 16 + i;
    int pos = pos0 + pos_l;
    int y = (pos >> 5) + 1, xx = (pos & 31) + 1;
    int ci = ci0 + pl;
    xc[((size_t)((b * 8 + (ci >> 5)) * 34 + y) * 34 + xx) * 32 + (ci & 31)] =
        f2bs(t[pl][pos_l]);
  }
}

// ---------------------------------------------------------------------------
// kqv GEMM: A-frags from XC (tap 1,1; contiguous 1KB loads), B from WK2.
// 4 waves/block; wave (mh,nh) owns the 2x2 quadrant (mt=mh*2+mi, nt=nh*2+ni).
__global__ __launch_bounds__(256) void kqv_mfma(
    const unsigned short* __restrict__ xc, const unsigned short* __restrict__ wk2,
    const float* __restrict__ bkqv, unsigned short* __restrict__ dq) {
  int tid = threadIdx.x;
  int lane = tid & 63; int il = lane & 15, q = lane >> 4;
  int wv = tid >> 6; int mh = wv >> 1, nh = wv & 1;
  int m0 = blockIdx.x * 64, coG = blockIdx.y;
  int b = m0 >> 10, pos0 = m0 & 1023;
  int row0 = pos0 >> 5;
  v4f acc[2][2];
#pragma unroll
  for (int mi = 0; mi < 2; ++mi)
#pragma unroll
    for (int ni = 0; ni < 2; ++ni) acc[mi][ni] = (v4f){0.f, 0.f, 0.f, 0.f};

  int pix[2];
#pragma unroll
  for (int mi = 0; mi < 2; ++mi)
    pix[mi] = (row0 + mh + 1) * 34 + (mi * 16 + il + 1);
  const unsigned short* bt = wk2 + (size_t)coG * 16384 + lane * 8;

#pragma unroll 4
  for (int kc = 0; kc < 8; ++kc) {
    v8s af[2], bf[2];
#pragma unroll
    for (int ni = 0; ni < 2; ++ni)
      bf[ni] = *(const v8s*)(bt + ((nh * 2 + ni) * 8 + kc) * 512);
#pragma unroll
    for (int mi = 0; mi < 2; ++mi)
      af[mi] = *(const v8s*)(xc + ((size_t)(b * 8 + kc) * 1156 + pix[mi]) * 32 + q * 8);
#pragma unroll
    for (int mi = 0; mi < 2; ++mi)
#pragma unroll
      for (int ni = 0; ni < 2; ++ni)
        acc[mi][ni] = __builtin_amdgcn_mfma_f32_16x16x32_bf16(
            af[mi], bf[ni], acc[mi][ni], 0, 0, 0);
  }
  int co0 = coG * 64;
#pragma unroll
  for (int ni = 0; ni < 2; ++ni) {
    int nt = nh * 2 + ni;
    int cob = co0 + nt * 16;
    int co = cob + il;
    float bias = bkqv[co];
    int cls = cob >> 7;                  // 0:k 1:q 2:v (uniform per nt)
    int h = (cob >> 4) & 7;
    size_t bh = (size_t)(b * 8 + h);
#pragma unroll
    for (int mi = 0; mi < 2; ++mi) {
      int mt = mh * 2 + mi;
      int pos = pos0 + mt * 16 + q * 4;
      v4f a = acc[mi][ni];
#pragma unroll
      for (int r = 0; r < 4; ++r) {
        float v = a[r] + bias;
        int p = pos + r;
        if (cls == 0)      dq[KS_US + bh * 16384 + p * 16 + il] = f2bs(v);
        else if (cls == 1) dq[QS_US + bh * 16384 + p * 16 + il] = f2bs(v * QSCALE);
        else               dq[VTS_US + bh * 16384 + ((p >> 5) * 16 + il) * 32 + (p & 31)] = f2bs(v);
      }
    }
  }
}

// ---------------------------------------------------------------------------
// MFMA attention, S-transposed formulation. Block 256 = 4 waves; wave owns a
// 16-row m-tile. Lane (q,il) reg r holds S[m0+il][nb+q*4+r].
// R4: depth-1 register prefetch of next-ny K/V (T14: latency under compute).
__global__ __launch_bounds__(256) void attn_mfma(
    unsigned short* __restrict__ dq, const unsigned short* __restrict__ krwb,
    const unsigned short* __restrict__ krhb, unsigned short* __restrict__ wsart) {
  __shared__ float lds[4][2448];
  int tid = threadIdx.x; int w = tid >> 6, lane = tid & 63;
  int il = lane & 15, q = lane >> 4;
  int bh = blockIdx.y; int b = bh >> 3, h = bh & 7;
  int m0 = blockIdx.x * 64 + w * 16;
  int my = m0 >> 5, mxb = m0 & 31;
  float* pw = lds[w];                       // [16 rows][stride 64]
  float* ph = pw + 1024;                    // [16 rows][stride 68], - SHIFT2
  unsigned short* pl = (unsigned short*)(ph + 1088);  // [16 rows][stride 40] bf16

  const v8s z8 = {0, 0, 0, 0, 0, 0, 0, 0};
  const v4f z4 = {0.f, 0.f, 0.f, 0.f};

  // Q frag: A-layout for table build == B-layout for S^T (same registers).
  const unsigned short* qrow = dq + QS_US + (size_t)bh * 16384 + (m0 + il) * 16;
  v8s qa = *(const v8s*)(qrow + (q & 1) * 8);
  qa = (q < 2) ? qa : z8;

  // PW / PH tables via MFMA (C row = m-row in tile, col = table col)
#pragma unroll
  for (int nt = 0; nt < 4; ++nt) {
    int c = nt * 16 + il;
    v8s bw = *(const v8s*)(krwb + c * 16 + (q & 1) * 8);
    v8s bhh = *(const v8s*)(krhb + c * 16 + (q & 1) * 8);
    bw = (q < 2) ? bw : z8;
    bhh = (q < 2) ? bhh : z8;
    v4f pwc = __builtin_amdgcn_mfma_f32_16x16x32_bf16(qa, bw, z4, 0, 0, 0);
    v4f phc = __builtin_amdgcn_mfma_f32_16x16x32_bf16(qa, bhh, z4, 0, 0, 0);
#pragma unroll
    for (int r = 0; r < 4; ++r) {
      pw[(q * 4 + r) * 64 + c] = pwc[r];
      ph[(q * 4 + r) * 68 + c] = phc[r] - SHIFT2;
    }
  }
  __builtin_amdgcn_wave_barrier();

  // pw lookups are ny-invariant per lane in the transposed scheme: hoist.
  float pwv[2][4];
#pragma unroll
  for (int nt2 = 0; nt2 < 2; ++nt2)
#pragma unroll
    for (int r = 0; r < 4; ++r)
      pwv[nt2][r] = pw[il * 64 + (nt2 * 16 + q * 4 + r) - mxb - il + 31];

  v4f oacc = z4;
  float sacc = 0.f;
  const unsigned short* kbase = dq + KS_US + (size_t)bh * 16384;
  const unsigned short* vbase = dq + VTS_US + (size_t)bh * 16384;

  // depth-1 prefetch of ny=0 K/V fragments
  v8s kb0 = *(const v8s*)(kbase + (il) * 16 + (q & 1) * 8);
  v8s kb1 = *(const v8s*)(kbase + (16 + il) * 16 + (q & 1) * 8);
  v8s vb0 = *(const v8s*)(vbase + (il) * 32 + q * 8);

  for (int ny = 0; ny < 32; ++ny) {
    v8s kc0 = (q < 2) ? kb0 : z8;
    v8s kc1 = (q < 2) ? kb1 : z8;
    v8s vcur = vb0;
    if (ny < 31) {   // issue next-ny loads; land under softmax + PV below
      kb0 = *(const v8s*)(kbase + ((ny + 1) * 32 + il) * 16 + (q & 1) * 8);
      kb1 = *(const v8s*)(kbase + ((ny + 1) * 32 + 16 + il) * 16 + (q & 1) * 8);
      vb0 = *(const v8s*)(vbase + ((ny + 1) * 16 + il) * 32 + q * 8);
    }
    float phv = ph[il * 68 + (ny - my + 31)];
    v4f s[2];
    s[0] = __builtin_amdgcn_mfma_f32_16x16x32_bf16(kc0, qa, z4, 0, 0, 0);
    s[1] = __builtin_amdgcn_mfma_f32_16x16x32_bf16(kc1, qa, z4, 0, 0, 0);
#pragma unroll
    for (int nt2 = 0; nt2 < 2; ++nt2) {
      float p[4];
#pragma unroll
      for (int r = 0; r < 4; ++r) {
        float t = s[nt2][r] + pwv[nt2][r] + phv;
        p[r] = exp2f(t);
        sacc += p[r];
      }
      uint2 pk;
      pk.x = (unsigned)f2bs(p[0]) | ((unsigned)f2bs(p[1]) << 16);
      pk.y = (unsigned)f2bs(p[2]) | ((unsigned)f2bs(p[3]) << 16);
      *(uint2*)(pl + il * 40 + nt2 * 16 + q * 4) = pk;
    }
    __builtin_amdgcn_wave_barrier();
    v8s pf = *(const v8s*)(pl + il * 40 + q * 8);
    oacc = __builtin_amdgcn_mfma_f32_16x16x32_bf16(pf, vcur, oacc, 0, 0, 0);
    __builtin_amdgcn_wave_barrier();
  }

  // row sums: lane holds partial for row il; combine quads, then fetch per-r.
  sacc += __shfl_xor(sacc, 16);
  sacc += __shfl_xor(sacc, 32);

  unsigned short* abase = (b < 6) ? (dq + ART1_US + (size_t)b * 131072)
                                  : (wsart + (size_t)(b - 6) * 131072);
#pragma unroll
  for (int r = 0; r < 4; ++r) {
    float sr = __shfl(sacc, q * 4 + r);       // full sum for row q*4+r
    int m = m0 + q * 4 + r;
    int c = h * 16 + (m >> 6);                // ci of art
    int pp = (m & 63) * 16 + il;              // pos' of art
    abase[((c >> 5) * 1024 + pp) * 32 + (c & 31)] = f2bs(oacc[r] / sr);
  }
}

// ---------------------------------------------------------------------------
// attn_out GEMM: A from artX (contiguous), B from WA2 (frag-major).
// 4 waves/block; wave (mh,nh) owns the 2x2 quadrant.
__global__ __launch_bounds__(256) void attn_out_mfma(
    const unsigned short* __restrict__ dq, const unsigned short* __restrict__ wsart,
    const unsigned short* __restrict__ wa2, const float* __restrict__ ba,
    float* __restrict__ out) {
  int tid = threadIdx.x;
  int lane = tid & 63; int il = lane & 15, q = lane >> 4;
  int wv = tid >> 6; int mh = wv >> 1, nh = wv & 1;
  int m0 = blockIdx.x * 64, coG = blockIdx.y;
  int b = m0 >> 10, pp0 = m0 & 1023;
  const unsigned short* ab = (b < 6) ? (dq + ART1_US + (size_t)b * 131072)
                                     : (wsart + (size_t)(b - 6) * 131072);
  const unsigned short* bt = wa2 + (size_t)coG * 8192 + lane * 8;
  v4f acc[2][2];
#pragma unroll
  for (int mi = 0; mi < 2; ++mi)
#pragma unroll
    for (int ni = 0; ni < 2; ++ni) acc[mi][ni] = (v4f){0.f, 0.f, 0.f, 0.f};
#pragma unroll
  for (int kc = 0; kc < 4; ++kc) {
    v8s af[2], bf[2];
#pragma unroll
    for (int ni = 0; ni < 2; ++ni)
      bf[ni] = *(const v8s*)(bt + ((nh * 2 + ni) * 4 + kc) * 512);
#pragma unroll
    for (int mi = 0; mi < 2; ++mi)
      af[mi] = *(const v8s*)(ab + (kc * 1024 + pp0 + (mh * 2 + mi) * 16 + il) * 32 + q * 8);
#pragma unroll
    for (int mi = 0; mi < 2; ++mi)
#pragma unroll
      for (int ni = 0; ni < 2; ++ni)
        acc[mi][ni] = __builtin_amdgcn_mfma_f32_16x16x32_bf16(
            af[mi], bf[ni], acc[mi][ni], 0, 0, 0);
  }
  int co0 = coG * 64;
#pragma unroll
  for (int ni = 0; ni < 2; ++ni) {
    int co = co0 + (nh * 2 + ni) * 16 + il;
    float bias = ba[co];
#pragma unroll
    for (int mi = 0; mi < 2; ++mi) {
      int mt = mh * 2 + mi;
      v4f a = acc[mi][ni];
      float4 v; v.x = a[0] + bias; v.y = a[1] + bias;
      v.z = a[2] + bias; v.w = a[3] + bias;
      *(float4*)(out + ((size_t)(b * 512 + 384 + co)) * 1024 + pp0 + mt * 16 + q * 4) = v;
    }
  }
}

// ---------------------------------------------------------------------------
// conv3x3 via MFMA (R4). Block 64 pos x 96 cout, 256 thr = 4 waves
// (mh=wv>>1 picks 32-pos half, nh=wv&1 picks 48-cout half; wave tile 2m x 3n,
// 6 MFMA/tap — unchanged from R3). Grid (128,4) = 512 blocks = 2 blocks/CU
// so barrier drains overlap across blocks. X: LDS [row4][q4][x34][8ci] per
// kc, dbuf, staged via global_load_lds (linear dest + permuted per-lane src);
// ONE barrier per kc. Weights: WB3 linear pointer walk (+512/iter), 3-slot
// rolling register prefetch 2 taps ahead. b = bx&7 pins batch to XCD.
__global__ __launch_bounds__(256, 2) void conv_mfma(
    const unsigned short* __restrict__ xc, const unsigned short* __restrict__ wb3,
    const float* __restrict__ bo, float* __restrict__ out) {
  __shared__ unsigned short xcs[2][4608];   // 9 slots x 512 (544 chunks used)
  int tid = threadIdx.x;
  int lane = tid & 63; int il = lane & 15, q = lane >> 4;
  int wv = tid >> 6; int mh = wv >> 1, nh = wv & 1;
  int bx = blockIdx.x, nset = blockIdx.y;
  int b = bx & 7, pt = bx >> 3;             // pt 0..15; b fastest => XCD-pinned
  int pos0 = pt * 64, y0 = pt * 2;
  const unsigned short* xb = xc + ((size_t)(b * 8) * 1156 + y0 * 34) * 32;

  v4f acc[2][3];
#pragma unroll
  for (int mi = 0; mi < 2; ++mi)
#pragma unroll
    for (int j = 0; j < 3; ++j) acc[mi][j] = (v4f){0.f, 0.f, 0.f, 0.f};

  // linear weight pointers, one per j; frag(it) = wp[j] + it*512
  const unsigned short* wp[3];
#pragma unroll
  for (int j = 0; j < 3; ++j) {
    int nfg = nset * 6 + nh * 3 + j;
    int coG = nfg >> 2, nt = nfg & 3;
    wp[j] = wb3 + (size_t)(coG * 4 + nt) * 36864 + lane * 8;
  }

  // ---- X staging: lds chunk C=(row*4+q)*34+x holds XC chunk row*136+x*4+q
  auto stageX = [&](int buf, int kc) {
    const unsigned short* src = xb + (size_t)kc * 36992;   // 1156*32
#pragma unroll
    for (int t = 0; t < 3; ++t) {
      int s = wv + t * 4;
      if (s < 9) {
        int C = s * 64 + lane;
        int row = C / 136, rem = C % 136;
        int qv = rem / 34, xx = rem % 34;
        const unsigned short* g = src + ((row * 136 + xx * 4 + qv) << 3);
        __builtin_amdgcn_global_load_lds(
            (const __attribute__((address_space(1))) void*)g,
            (__attribute__((address_space(3))) void*)(&xcs[buf][s * 512]),
            16, 0, 0);
      }
    }
  };

  // prologue: stage X[kc=0]; preload weight slots for it=0,1
  stageX(0, 0);
  v8s bS[3][3];
#pragma unroll
  for (int j = 0; j < 3; ++j) bS[0][j] = *(const v8s*)(wp[j]);
#pragma unroll
  for (int j = 0; j < 3; ++j) bS[1][j] = *(const v8s*)(wp[j] + 512);
  __syncthreads();

  for (int kc = 0; kc < 8; ++kc) {
    int buf = kc & 1;
    if (kc < 7) stageX(buf ^ 1, kc + 1);    // async, drains at the barrier
#pragma unroll
    for (int tap = 0; tap < 9; ++tap) {
      int it = kc * 9 + tap;
      if (it < 70) {                        // prefetch it+2 into slot (tap+2)%3
#pragma unroll
        for (int j = 0; j < 3; ++j)
          bS[(tap + 2) % 3][j] = *(const v8s*)(wp[j] + (size_t)(it + 2) * 512);
      }
      int ky = tap / 3, kx = tap % 3;
      v8s af[2];
#pragma unroll
      for (int mi = 0; mi < 2; ++mi)
        af[mi] = *(const v8s*)&xcs[buf][((mh + ky) * 4 + q) * 272 +
                                        (mi * 16 + kx + il) * 8];
#pragma unroll
      for (int mi = 0; mi < 2; ++mi)
#pragma unroll
        for (int j = 0; j < 3; ++j)
          acc[mi][j] = __builtin_amdgcn_mfma_f32_16x16x32_bf16(
              af[mi], bS[tap % 3][j], acc[mi][j], 0, 0, 0);
    }
    __syncthreads();
  }

  int co0 = nset * 96;
#pragma unroll
  for (int j = 0; j < 3; ++j) {
    int co = co0 + (nh * 3 + j) * 16 + il;
    float bias = bo[co];
#pragma unroll
    for (int mi = 0; mi < 2; ++mi) {
      v4f a = acc[mi][j];
      float4 v; v.x = a[0] + bias; v.y = a[1] + bias;
      v.z = a[2] + bias; v.w = a[3] + bias;
      *(float4*)(out + ((size_t)(b * 512 + co)) * 1024 +
                 pos0 + mh * 32 + mi * 16 + q * 4) = v;
    }
  }
}

// ---------------------------------------------------------------------------
extern "C" void kernel_launch(void* const* d_in, const int* in_sizes, int n_in,
                              void* d_out, int out_size, void* d_ws, size_t ws_size,
                              hipStream_t stream) {
  const float* x      = (const float*)d_in[0];
  const float* b_out  = (const float*)d_in[2];
  const float* b_kqv  = (const float*)d_in[4];
  const float* b_attn = (const float*)d_in[6];
  const float* krw    = (const float*)d_in[7];
  const float* krh    = (const float*)d_in[8];
  unsigned short* ws = (unsigned short*)d_ws;
  float* out = (float*)d_out;
  unsigned short* dq = (unsigned short*)d_out;

  prep_kernel<<<3912, 256, 0, stream>>>(
      (const float*)d_in[1], (const float*)d_in[3], (const float*)d_in[5],
      krw, krh, ws);
  zero_xc_kernel<<<1156, 256, 0, stream>>>(ws + XC_US);
  xt_kernel<<<dim3(16, 4, 8), 256, 0, stream>>>(x, ws + XC_US);
  kqv_mfma<<<dim3(128, 6), 256, 0, stream>>>(
      ws + XC_US, ws + WK2_US, b_kqv, dq);
  attn_mfma<<<dim3(16, 64), 256, 0, stream>>>(
      dq, ws + KRWB_US, ws + KRHB_US, ws + ART2_US);
  attn_out_mfma<<<dim3(128, 2), 256, 0, stream>>>(
      dq, ws + ART2_US, ws + WA2_US, b_attn, out);
  conv_mfma<<<dim3(128, 4), 256, 0, stream>>>(
      ws + XC_US, ws + WB2_US, b_out, out);
}

// Round 6
// 159.339 us; speedup vs baseline: 1.1493x; 1.0088x over previous
//
#include <hip/hip_runtime.h>
#include <hip/hip_bf16.h>

// ---------------------------------------------------------------------------
// SelfAttention2d, fully-MFMA pipeline, fragment-major memory layouts.
// MFMA 16x16x32 bf16: A[m=il][k=q*8+j], B[col=il][k=q*8+j], C[row=q*4+r][col=il]
//
// R6: fix R5's conv slot collision. R5 used depth-4 prefetch into 4 slots:
// (it+4)&3 == it&3, so the prefetch overwrote the slot being consumed ->
// wrong weights (absmax 16.4). Invariant: prefetch depth < slot count.
// Now 5 slots, depth 4 ((it+4)%5 != it%5), all indices compile-time via the
// fully-unrolled kc/tap loops. kqv keeps R5's (sound) 4-slot depth-3 scheme.
//
// Attention computes S TRANSPOSED (A=K, B=Q) so each lane holds
// S[m=m0+il][n=nb+q*4+r]:  pw lookups become ny-invariant registers, ph is one
// read/ny, and P needs only an 8B LDS write + b128 read to become the PV
// A-operand (full K=32).
//
// Layouts:
//   XC   [b][kc 0..7][y 0..33][x 0..33][ci 32]  zero-padded image, bf16
//   WB3  [coG6][nt4][kc8][tap9][lane64][8]      w_out frag-major, linear walk
//   WK2  [coG6][nt4][kc8][lane64][8]            w_kqv frag-major
//   WA2  [coG2][nt4][kc4][lane64][8]            w_attn frag-major
//   VT   [bh][ny32][d16][ci 32]                 V^T frag-major
//   artX [b][kc4][pp1024][ci32]                 attn out, frag-major
//
// ws (ushort units, 7,262,208 B <= proven-safe 8,192,000):
//   WB3 0 / WK2 884736 / WA2 983040 / KRWB 999424 / KRHB 1000448 /
//   XC 1001472 (2,367,488) / ART2 3368960 (b=6,7 slots)
// d_out scratch (ushort): KS 0 / QS 1048576 / VT 2097152 / ART1 7340032 (b0..5)
// Order: prep -> zero_xc -> xt -> kqv -> attn -> attn_out -> conv
// ---------------------------------------------------------------------------

typedef short v8s __attribute__((ext_vector_type(8)));
typedef float v4f __attribute__((ext_vector_type(4)));

#define WB2_US   0u
#define WK2_US   884736u
#define WA2_US   983040u
#define KRWB_US  999424u
#define KRHB_US  1000448u
#define XC_US    1001472u
#define ART2_US  3368960u

#define KS_US    0u
#define QS_US    1048576u
#define VTS_US   2097152u
#define ART1_US  7340032u

#define QSCALE 0.360673760f   // 0.25 * log2(e)
#define SHIFT2 17.3123405f    // 12 * log2(e)

__device__ __forceinline__ unsigned short f2bs(float f) {
  __hip_bfloat16 h = __float2bfloat16(f);
  return *reinterpret_cast<unsigned short*>(&h);
}

// ---------------------------------------------------------------------------
__global__ __launch_bounds__(256) void prep_kernel(
    const float* __restrict__ w_out, const float* __restrict__ w_kqv,
    const float* __restrict__ w_attn, const float* __restrict__ krw,
    const float* __restrict__ krh, unsigned short* __restrict__ ws) {
  int i = blockIdx.x * 256 + threadIdx.x;
  if (i < 884736) {              // WB3[coG][nt][kc][tap][lane][8]
    int j = i & 7, l = (i >> 3) & 63;
    int r = i >> 9;              // fragment chunk index [coG][nt][kc][tap]
    int tap = r % 9; int r2 = r / 9;
    int kc = r2 & 7, nt = (r2 >> 3) & 3, coG = r2 >> 5;
    int co = coG * 64 + nt * 16 + (l & 15);
    int ci = kc * 32 + (l >> 4) * 8 + j;
    ws[WB2_US + i] = f2bs(w_out[(size_t)co * 2304 + ci * 9 + tap]);
  } else if (i < 983040) {       // WK2[coG][nt][kc][lane][8]
    int o = i - 884736;
    int j = o & 7, l = (o >> 3) & 63, kc = (o >> 9) & 7, nt = (o >> 12) & 3;
    int coG = o >> 14;
    int co = coG * 64 + nt * 16 + (l & 15);
    int ci = kc * 32 + (l >> 4) * 8 + j;
    ws[WK2_US + o] = f2bs(w_kqv[co * 256 + ci]);
  } else if (i < 999424) {       // WA2[coG][nt][kc][lane][8]
    int o = i - 983040;
    int j = o & 7, l = (o >> 3) & 63, kc = (o >> 9) & 3, nt = (o >> 11) & 3;
    int coG = o >> 13;
    int co = coG * 64 + nt * 16 + (l & 15);
    int ci = kc * 32 + (l >> 4) * 8 + j;
    ws[WA2_US + o] = f2bs(w_attn[co * 128 + ci]);
  } else if (i < 1000448) {      // krw bf16 [64][16], row 63 zero
    int j = i - 999424; int c = j >> 4, d = j & 15;
    ws[KRWB_US + j] = (c < 63) ? f2bs(krw[c * 16 + d]) : (unsigned short)0;
  } else if (i < 1001472) {
    int j = i - 1000448; int c = j >> 4, d = j & 15;
    ws[KRHB_US + j] = (c < 63) ? f2bs(krh[c * 16 + d]) : (unsigned short)0;
  }
}

// ---------------------------------------------------------------------------
__global__ __launch_bounds__(256) void zero_xc_kernel(unsigned short* __restrict__ xc) {
  int i = blockIdx.x * 256 + threadIdx.x;   // 295,936 uint4 = 2,367,488 us
  uint4 z = {0u, 0u, 0u, 0u};
  ((uint4*)xc)[i] = z;
}

// ---------------------------------------------------------------------------
// x [b][ci][pos] fp32 -> XC[b][ci>>5][y+1][x+1][ci&31] bf16 via LDS tile.
__global__ __launch_bounds__(256) void xt_kernel(
    const float* __restrict__ x, unsigned short* __restrict__ xc) {
  __shared__ float t[64][65];
  int tid = threadIdx.x; int pl = tid & 63, cg = tid >> 6;
  int pos0 = blockIdx.x * 64, ci0 = blockIdx.y * 64, b = blockIdx.z;
  const float* xb = x + ((size_t)(b * 256 + ci0)) * 1024 + pos0;
#pragma unroll
  for (int i = 0; i < 16; ++i) {
    int ci_l = cg * 16 + i;
    t[ci_l][pl] = xb[(size_t)ci_l * 1024 + pl];
  }
  __syncthreads();
#pragma unroll
  for (int i = 0; i < 16; ++i) {
    int pos_l = cg * 16 + i;
    int pos = pos0 + pos_l;
    int y = (pos >> 5) + 1, xx = (pos & 31) + 1;
    int ci = ci0 + pl;
    xc[((size_t)((b * 8 + (ci >> 5)) * 34 + y) * 34 + xx) * 32 + (ci & 31)] =
        f2bs(t[pl][pos_l]);
  }
}

// ---------------------------------------------------------------------------
// kqv GEMM: A-frags from XC (tap 1,1; contiguous 1KB loads), B from WK2.
// 4 waves/block; wave (mh,nh) owns the 2x2 quadrant (mt=mh*2+mi, nt=nh*2+ni).
// R5: full kc unroll + 4-slot depth-3 rolling prefetch of A/B fragments.
__global__ __launch_bounds__(256) void kqv_mfma(
    const unsigned short* __restrict__ xc, const unsigned short* __restrict__ wk2,
    const float* __restrict__ bkqv, unsigned short* __restrict__ dq) {
  int tid = threadIdx.x;
  int lane = tid & 63; int il = lane & 15, q = lane >> 4;
  int wv = tid >> 6; int mh = wv >> 1, nh = wv & 1;
  int m0 = blockIdx.x * 64, coG = blockIdx.y;
  int b = m0 >> 10, pos0 = m0 & 1023;
  int row0 = pos0 >> 5;
  v4f acc[2][2];
#pragma unroll
  for (int mi = 0; mi < 2; ++mi)
#pragma unroll
    for (int ni = 0; ni < 2; ++ni) acc[mi][ni] = (v4f){0.f, 0.f, 0.f, 0.f};

  int pix[2];
#pragma unroll
  for (int mi = 0; mi < 2; ++mi)
    pix[mi] = (row0 + mh + 1) * 34 + (mi * 16 + il + 1);
  const unsigned short* bt = wk2 + (size_t)coG * 16384 + lane * 8;
  const unsigned short* at = xc + (size_t)(b * 8) * 36992 + q * 8;

  v8s afS[4][2], bfS[4][2];
  // prologue: preload kc = 0..2 into slots 0..2
#pragma unroll
  for (int p = 0; p < 3; ++p) {
#pragma unroll
    for (int ni = 0; ni < 2; ++ni)
      bfS[p][ni] = *(const v8s*)(bt + ((nh * 2 + ni) * 8 + p) * 512);
#pragma unroll
    for (int mi = 0; mi < 2; ++mi)
      afS[p][mi] = *(const v8s*)(at + (size_t)p * 36992 + pix[mi] * 32);
  }

#pragma unroll
  for (int kc = 0; kc < 8; ++kc) {
    if (kc + 3 < 8) {
      int kn = kc + 3, s = kn & 3;
#pragma unroll
      for (int ni = 0; ni < 2; ++ni)
        bfS[s][ni] = *(const v8s*)(bt + ((nh * 2 + ni) * 8 + kn) * 512);
#pragma unroll
      for (int mi = 0; mi < 2; ++mi)
        afS[s][mi] = *(const v8s*)(at + (size_t)kn * 36992 + pix[mi] * 32);
    }
    int cs = kc & 3;
#pragma unroll
    for (int mi = 0; mi < 2; ++mi)
#pragma unroll
      for (int ni = 0; ni < 2; ++ni)
        acc[mi][ni] = __builtin_amdgcn_mfma_f32_16x16x32_bf16(
            afS[cs][mi], bfS[cs][ni], acc[mi][ni], 0, 0, 0);
  }
  int co0 = coG * 64;
#pragma unroll
  for (int ni = 0; ni < 2; ++ni) {
    int nt = nh * 2 + ni;
    int cob = co0 + nt * 16;
    int co = cob + il;
    float bias = bkqv[co];
    int cls = cob >> 7;                  // 0:k 1:q 2:v (uniform per nt)
    int h = (cob >> 4) & 7;
    size_t bh = (size_t)(b * 8 + h);
#pragma unroll
    for (int mi = 0; mi < 2; ++mi) {
      int mt = mh * 2 + mi;
      int pos = pos0 + mt * 16 + q * 4;
      v4f a = acc[mi][ni];
#pragma unroll
      for (int r = 0; r < 4; ++r) {
        float v = a[r] + bias;
        int p = pos + r;
        if (cls == 0)      dq[KS_US + bh * 16384 + p * 16 + il] = f2bs(v);
        else if (cls == 1) dq[QS_US + bh * 16384 + p * 16 + il] = f2bs(v * QSCALE);
        else               dq[VTS_US + bh * 16384 + ((p >> 5) * 16 + il) * 32 + (p & 31)] = f2bs(v);
      }
    }
  }
}

// ---------------------------------------------------------------------------
// MFMA attention, S-transposed formulation. Block 256 = 4 waves; wave owns a
// 16-row m-tile. Lane (q,il) reg r holds S[m0+il][nb+q*4+r].
// R4: depth-1 register prefetch of next-ny K/V (T14: latency under compute).
__global__ __launch_bounds__(256) void attn_mfma(
    unsigned short* __restrict__ dq, const unsigned short* __restrict__ krwb,
    const unsigned short* __restrict__ krhb, unsigned short* __restrict__ wsart) {
  __shared__ float lds[4][2448];
  int tid = threadIdx.x; int w = tid >> 6, lane = tid & 63;
  int il = lane & 15, q = lane >> 4;
  int bh = blockIdx.y; int b = bh >> 3, h = bh & 7;
  int m0 = blockIdx.x * 64 + w * 16;
  int my = m0 >> 5, mxb = m0 & 31;
  float* pw = lds[w];                       // [16 rows][stride 64]
  float* ph = pw + 1024;                    // [16 rows][stride 68], - SHIFT2
  unsigned short* pl = (unsigned short*)(ph + 1088);  // [16 rows][stride 40] bf16

  const v8s z8 = {0, 0, 0, 0, 0, 0, 0, 0};
  const v4f z4 = {0.f, 0.f, 0.f, 0.f};

  // Q frag: A-layout for table build == B-layout for S^T (same registers).
  const unsigned short* qrow = dq + QS_US + (size_t)bh * 16384 + (m0 + il) * 16;
  v8s qa = *(const v8s*)(qrow + (q & 1) * 8);
  qa = (q < 2) ? qa : z8;

  // PW / PH tables via MFMA (C row = m-row in tile, col = table col)
#pragma unroll
  for (int nt = 0; nt < 4; ++nt) {
    int c = nt * 16 + il;
    v8s bw = *(const v8s*)(krwb + c * 16 + (q & 1) * 8);
    v8s bhh = *(const v8s*)(krhb + c * 16 + (q & 1) * 8);
    bw = (q < 2) ? bw : z8;
    bhh = (q < 2) ? bhh : z8;
    v4f pwc = __builtin_amdgcn_mfma_f32_16x16x32_bf16(qa, bw, z4, 0, 0, 0);
    v4f phc = __builtin_amdgcn_mfma_f32_16x16x32_bf16(qa, bhh, z4, 0, 0, 0);
#pragma unroll
    for (int r = 0; r < 4; ++r) {
      pw[(q * 4 + r) * 64 + c] = pwc[r];
      ph[(q * 4 + r) * 68 + c] = phc[r] - SHIFT2;
    }
  }
  __builtin_amdgcn_wave_barrier();

  // pw lookups are ny-invariant per lane in the transposed scheme: hoist.
  float pwv[2][4];
#pragma unroll
  for (int nt2 = 0; nt2 < 2; ++nt2)
#pragma unroll
    for (int r = 0; r < 4; ++r)
      pwv[nt2][r] = pw[il * 64 + (nt2 * 16 + q * 4 + r) - mxb - il + 31];

  v4f oacc = z4;
  float sacc = 0.f;
  const unsigned short* kbase = dq + KS_US + (size_t)bh * 16384;
  const unsigned short* vbase = dq + VTS_US + (size_t)bh * 16384;

  // depth-1 prefetch of ny=0 K/V fragments
  v8s kb0 = *(const v8s*)(kbase + (il) * 16 + (q & 1) * 8);
  v8s kb1 = *(const v8s*)(kbase + (16 + il) * 16 + (q & 1) * 8);
  v8s vb0 = *(const v8s*)(vbase + (il) * 32 + q * 8);

  for (int ny = 0; ny < 32; ++ny) {
    v8s kc0 = (q < 2) ? kb0 : z8;
    v8s kc1 = (q < 2) ? kb1 : z8;
    v8s vcur = vb0;
    if (ny < 31) {   // issue next-ny loads; land under softmax + PV below
      kb0 = *(const v8s*)(kbase + ((ny + 1) * 32 + il) * 16 + (q & 1) * 8);
      kb1 = *(const v8s*)(kbase + ((ny + 1) * 32 + 16 + il) * 16 + (q & 1) * 8);
      vb0 = *(const v8s*)(vbase + ((ny + 1) * 16 + il) * 32 + q * 8);
    }
    float phv = ph[il * 68 + (ny - my + 31)];
    v4f s[2];
    s[0] = __builtin_amdgcn_mfma_f32_16x16x32_bf16(kc0, qa, z4, 0, 0, 0);
    s[1] = __builtin_amdgcn_mfma_f32_16x16x32_bf16(kc1, qa, z4, 0, 0, 0);
#pragma unroll
    for (int nt2 = 0; nt2 < 2; ++nt2) {
      float p[4];
#pragma unroll
      for (int r = 0; r < 4; ++r) {
        float t = s[nt2][r] + pwv[nt2][r] + phv;
        p[r] = exp2f(t);
        sacc += p[r];
      }
      uint2 pk;
      pk.x = (unsigned)f2bs(p[0]) | ((unsigned)f2bs(p[1]) << 16);
      pk.y = (unsigned)f2bs(p[2]) | ((unsigned)f2bs(p[3]) << 16);
      *(uint2*)(pl + il * 40 + nt2 * 16 + q * 4) = pk;
    }
    __builtin_amdgcn_wave_barrier();
    v8s pf = *(const v8s*)(pl + il * 40 + q * 8);
    oacc = __builtin_amdgcn_mfma_f32_16x16x32_bf16(pf, vcur, oacc, 0, 0, 0);
    __builtin_amdgcn_wave_barrier();
  }

  // row sums: lane holds partial for row il; combine quads, then fetch per-r.
  sacc += __shfl_xor(sacc, 16);
  sacc += __shfl_xor(sacc, 32);

  unsigned short* abase = (b < 6) ? (dq + ART1_US + (size_t)b * 131072)
                                  : (wsart + (size_t)(b - 6) * 131072);
#pragma unroll
  for (int r = 0; r < 4; ++r) {
    float sr = __shfl(sacc, q * 4 + r);       // full sum for row q*4+r
    int m = m0 + q * 4 + r;
    int c = h * 16 + (m >> 6);                // ci of art
    int pp = (m & 63) * 16 + il;              // pos' of art
    abase[((c >> 5) * 1024 + pp) * 32 + (c & 31)] = f2bs(oacc[r] / sr);
  }
}

// ---------------------------------------------------------------------------
// attn_out GEMM: A from artX (contiguous), B from WA2 (frag-major).
// 4 waves/block; wave (mh,nh) owns the 2x2 quadrant.
__global__ __launch_bounds__(256) void attn_out_mfma(
    const unsigned short* __restrict__ dq, const unsigned short* __restrict__ wsart,
    const unsigned short* __restrict__ wa2, const float* __restrict__ ba,
    float* __restrict__ out) {
  int tid = threadIdx.x;
  int lane = tid & 63; int il = lane & 15, q = lane >> 4;
  int wv = tid >> 6; int mh = wv >> 1, nh = wv & 1;
  int m0 = blockIdx.x * 64, coG = blockIdx.y;
  int b = m0 >> 10, pp0 = m0 & 1023;
  const unsigned short* ab = (b < 6) ? (dq + ART1_US + (size_t)b * 131072)
                                     : (wsart + (size_t)(b - 6) * 131072);
  const unsigned short* bt = wa2 + (size_t)coG * 8192 + lane * 8;
  v4f acc[2][2];
#pragma unroll
  for (int mi = 0; mi < 2; ++mi)
#pragma unroll
    for (int ni = 0; ni < 2; ++ni) acc[mi][ni] = (v4f){0.f, 0.f, 0.f, 0.f};
#pragma unroll
  for (int kc = 0; kc < 4; ++kc) {
    v8s af[2], bf[2];
#pragma unroll
    for (int ni = 0; ni < 2; ++ni)
      bf[ni] = *(const v8s*)(bt + ((nh * 2 + ni) * 4 + kc) * 512);
#pragma unroll
    for (int mi = 0; mi < 2; ++mi)
      af[mi] = *(const v8s*)(ab + (kc * 1024 + pp0 + (mh * 2 + mi) * 16 + il) * 32 + q * 8);
#pragma unroll
    for (int mi = 0; mi < 2; ++mi)
#pragma unroll
      for (int ni = 0; ni < 2; ++ni)
        acc[mi][ni] = __builtin_amdgcn_mfma_f32_16x16x32_bf16(
            af[mi], bf[ni], acc[mi][ni], 0, 0, 0);
  }
  int co0 = coG * 64;
#pragma unroll
  for (int ni = 0; ni < 2; ++ni) {
    int co = co0 + (nh * 2 + ni) * 16 + il;
    float bias = ba[co];
#pragma unroll
    for (int mi = 0; mi < 2; ++mi) {
      int mt = mh * 2 + mi;
      v4f a = acc[mi][ni];
      float4 v; v.x = a[0] + bias; v.y = a[1] + bias;
      v.z = a[2] + bias; v.w = a[3] + bias;
      *(float4*)(out + ((size_t)(b * 512 + 384 + co)) * 1024 + pp0 + mt * 16 + q * 4) = v;
    }
  }
}

// ---------------------------------------------------------------------------
// conv3x3 via MFMA (R6). Block 64 pos x 96 cout, 256 thr = 4 waves
// (wave tile 32pos x 48cout, 6 MFMA/tap). Grid (128,4) = 512 blocks =
// 2 blocks/CU. X: LDS [row4+1][q4][x34][8ci] per kc, dbuf, global_load_lds
// (linear dest + permuted src); ONE barrier per kc. Weights: WB3 linear walk,
// FULL kc unroll -> 5-slot depth-4 rolling register prefetch (slot = it%5,
// static; depth < nslots so no consume/overwrite collision).
// b = bx&7 pins batch to XCD.
__global__ __launch_bounds__(256, 2) void conv_mfma(
    const unsigned short* __restrict__ xc, const unsigned short* __restrict__ wb3,
    const float* __restrict__ bo, float* __restrict__ out) {
  __shared__ unsigned short xcs[2][4608];   // 9 slots x 512 (544 chunks used)
  int tid = threadIdx.x;
  int lane = tid & 63; int il = lane & 15, q = lane >> 4;
  int wv = tid >> 6; int mh = wv >> 1, nh = wv & 1;
  int bx = blockIdx.x, nset = blockIdx.y;
  int b = bx & 7, pt = bx >> 3;             // pt 0..15; b fastest => XCD-pinned
  int pos0 = pt * 64, y0 = pt * 2;
  const unsigned short* xb = xc + ((size_t)(b * 8) * 1156 + y0 * 34) * 32;

  v4f acc[2][3];
#pragma unroll
  for (int mi = 0; mi < 2; ++mi)
#pragma unroll
    for (int j = 0; j < 3; ++j) acc[mi][j] = (v4f){0.f, 0.f, 0.f, 0.f};

  // linear weight pointers, one per j; frag(it) = wp[j] + it*512
  const unsigned short* wp[3];
#pragma unroll
  for (int j = 0; j < 3; ++j) {
    int nfg = nset * 6 + nh * 3 + j;
    int coG = nfg >> 2, nt = nfg & 3;
    wp[j] = wb3 + (size_t)(coG * 4 + nt) * 36864 + lane * 8;
  }

  // ---- X staging: lds chunk C=(row*4+q)*34+x holds XC chunk row*136+x*4+q
  auto stageX = [&](int buf, int kc) {
    const unsigned short* src = xb + (size_t)kc * 36992;   // 1156*32
#pragma unroll
    for (int t = 0; t < 3; ++t) {
      int s = wv + t * 4;
      if (s < 9) {
        int C = s * 64 + lane;
        int row = C / 136, rem = C % 136;
        int qv = rem / 34, xx = rem % 34;
        const unsigned short* g = src + ((row * 136 + xx * 4 + qv) << 3);
        __builtin_amdgcn_global_load_lds(
            (const __attribute__((address_space(1))) void*)g,
            (__attribute__((address_space(3))) void*)(&xcs[buf][s * 512]),
            16, 0, 0);
      }
    }
  };

  // prologue: stage X[kc=0]; preload weight slots for it = 0..3
  stageX(0, 0);
  v8s bS[5][3];
#pragma unroll
  for (int p = 0; p < 4; ++p)
#pragma unroll
    for (int j = 0; j < 3; ++j)
      bS[p][j] = *(const v8s*)(wp[j] + (size_t)p * 512);
  __syncthreads();

#pragma unroll
  for (int kc = 0; kc < 8; ++kc) {
    int buf = kc & 1;
    if (kc < 7) stageX(buf ^ 1, kc + 1);    // async, drains at the barrier
#pragma unroll
    for (int tap = 0; tap < 9; ++tap) {
      int it = kc * 9 + tap;                // compile-time (kc unrolled)
      if (it + 4 < 72) {                    // depth-4 prefetch into slot (it+4)%5
#pragma unroll
        for (int j = 0; j < 3; ++j)
          bS[(it + 4) % 5][j] = *(const v8s*)(wp[j] + (size_t)(it + 4) * 512);
      }
      int ky = tap / 3, kx = tap % 3;
      v8s af[2];
#pragma unroll
      for (int mi = 0; mi < 2; ++mi)
        af[mi] = *(const v8s*)&xcs[buf][((mh + ky) * 4 + q) * 272 +
                                        (mi * 16 + kx + il) * 8];
#pragma unroll
      for (int mi = 0; mi < 2; ++mi)
#pragma unroll
        for (int j = 0; j < 3; ++j)
          acc[mi][j] = __builtin_amdgcn_mfma_f32_16x16x32_bf16(
              af[mi], bS[it % 5][j], acc[mi][j], 0, 0, 0);
    }
    __syncthreads();
  }

  int co0 = nset * 96;
#pragma unroll
  for (int j = 0; j < 3; ++j) {
    int co = co0 + (nh * 3 + j) * 16 + il;
    float bias = bo[co];
#pragma unroll
    for (int mi = 0; mi < 2; ++mi) {
      v4f a = acc[mi][j];
      float4 v; v.x = a[0] + bias; v.y = a[1] + bias;
      v.z = a[2] + bias; v.w = a[3] + bias;
      *(float4*)(out + ((size_t)(b * 512 + co)) * 1024 +
                 pos0 + mh * 32 + mi * 16 + q * 4) = v;
    }
  }
}

// ---------------------------------------------------------------------------
extern "C" void kernel_launch(void* const* d_in, const int* in_sizes, int n_in,
                              void* d_out, int out_size, void* d_ws, size_t ws_size,
                              hipStream_t stream) {
  const float* x      = (const float*)d_in[0];
  const float* b_out  = (const float*)d_in[2];
  const float* b_kqv  = (const float*)d_in[4];
  const float* b_attn = (const float*)d_in[6];
  const float* krw    = (const float*)d_in[7];
  const float* krh    = (const float*)d_in[8];
  unsigned short* ws = (unsigned short*)d_ws;
  float* out = (float*)d_out;
  unsigned short* dq = (unsigned short*)d_out;

  prep_kernel<<<3912, 256, 0, stream>>>(
      (const float*)d_in[1], (const float*)d_in[3], (const float*)d_in[5],
      krw, krh, ws);
  zero_xc_kernel<<<1156, 256, 0, stream>>>(ws + XC_US);
  xt_kernel<<<dim3(16, 4, 8), 256, 0, stream>>>(x, ws + XC_US);
  kqv_mfma<<<dim3(128, 6), 256, 0, stream>>>(
      ws + XC_US, ws + WK2_US, b_kqv, dq);
  attn_mfma<<<dim3(16, 64), 256, 0, stream>>>(
      dq, ws + KRWB_US, ws + KRHB_US, ws + ART2_US);
  attn_out_mfma<<<dim3(128, 2), 256, 0, stream>>>(
      dq, ws + ART2_US, ws + WA2_US, b_attn, out);
  conv_mfma<<<dim3(128, 4), 256, 0, stream>>>(
      ws + XC_US, ws + WB2_US, b_out, out);
}

// Round 7
// 154.646 us; speedup vs baseline: 1.1842x; 1.0303x over previous
//
#include <hip/hip_runtime.h>
#include <hip/hip_bf16.h>

// ---------------------------------------------------------------------------
// SelfAttention2d, fully-MFMA pipeline, fragment-major memory layouts.
// MFMA 16x16x32 bf16: A[m=il][k=q*8+j], B[col=il][k=q*8+j], C[row=q*4+r][col=il]
//
// R7: conv v5 — weight reads through LDS. R6 falsified the latency theory
// (deep prefetch ~= 0); arithmetic says conv is L2-BW bound: 4 waves x 512
// blocks x 216KB private weight streams = 442MB L2 traffic for a 1.77MB
// weight set (12.9us/XCD floor). v5 stages W[kc] (54KB) + X[kc] (13KB) in
// LDS once per block per kc -> 110MB total; all 8 waves share. 512thr
// blocks (128pos x 96cout), single-buffered tiles, 2 barriers/kc, staging
// covered by the co-resident block (2 blocks/CU, LDS 68.6KB).
//
// Attention computes S TRANSPOSED (A=K, B=Q) so each lane holds
// S[m=m0+il][n=nb+q*4+r]:  pw lookups become ny-invariant registers, ph is one
// read/ny, and P needs only an 8B LDS write + b128 read to become the PV
// A-operand (full K=32).
//
// Layouts:
//   XC   [b][kc 0..7][y 0..33][x 0..33][ci 32]  zero-padded image, bf16
//   WB3  [coG6][nt4][kc8][tap9][lane64][8]      w_out frag-major
//   WK2  [coG6][nt4][kc8][lane64][8]            w_kqv frag-major
//   WA2  [coG2][nt4][kc4][lane64][8]            w_attn frag-major
//   VT   [bh][ny32][d16][ci 32]                 V^T frag-major
//   artX [b][kc4][pp1024][ci32]                 attn out, frag-major
//
// ws (ushort units, 7,262,208 B <= proven-safe 8,192,000):
//   WB3 0 / WK2 884736 / WA2 983040 / KRWB 999424 / KRHB 1000448 /
//   XC 1001472 (2,367,488) / ART2 3368960 (b=6,7 slots)
// d_out scratch (ushort): KS 0 / QS 1048576 / VT 2097152 / ART1 7340032 (b0..5)
// Order: prep -> zero_xc -> xt -> kqv -> attn -> attn_out -> conv
// ---------------------------------------------------------------------------

typedef short v8s __attribute__((ext_vector_type(8)));
typedef float v4f __attribute__((ext_vector_type(4)));

#define WB2_US   0u
#define WK2_US   884736u
#define WA2_US   983040u
#define KRWB_US  999424u
#define KRHB_US  1000448u
#define XC_US    1001472u
#define ART2_US  3368960u

#define KS_US    0u
#define QS_US    1048576u
#define VTS_US   2097152u
#define ART1_US  7340032u

#define QSCALE 0.360673760f   // 0.25 * log2(e)
#define SHIFT2 17.3123405f    // 12 * log2(e)

__device__ __forceinline__ unsigned short f2bs(float f) {
  __hip_bfloat16 h = __float2bfloat16(f);
  return *reinterpret_cast<unsigned short*>(&h);
}

// ---------------------------------------------------------------------------
__global__ __launch_bounds__(256) void prep_kernel(
    const float* __restrict__ w_out, const float* __restrict__ w_kqv,
    const float* __restrict__ w_attn, const float* __restrict__ krw,
    const float* __restrict__ krh, unsigned short* __restrict__ ws) {
  int i = blockIdx.x * 256 + threadIdx.x;
  if (i < 884736) {              // WB3[coG][nt][kc][tap][lane][8]
    int j = i & 7, l = (i >> 3) & 63;
    int r = i >> 9;              // fragment chunk index [coG][nt][kc][tap]
    int tap = r % 9; int r2 = r / 9;
    int kc = r2 & 7, nt = (r2 >> 3) & 3, coG = r2 >> 5;
    int co = coG * 64 + nt * 16 + (l & 15);
    int ci = kc * 32 + (l >> 4) * 8 + j;
    ws[WB2_US + i] = f2bs(w_out[(size_t)co * 2304 + ci * 9 + tap]);
  } else if (i < 983040) {       // WK2[coG][nt][kc][lane][8]
    int o = i - 884736;
    int j = o & 7, l = (o >> 3) & 63, kc = (o >> 9) & 7, nt = (o >> 12) & 3;
    int coG = o >> 14;
    int co = coG * 64 + nt * 16 + (l & 15);
    int ci = kc * 32 + (l >> 4) * 8 + j;
    ws[WK2_US + o] = f2bs(w_kqv[co * 256 + ci]);
  } else if (i < 999424) {       // WA2[coG][nt][kc][lane][8]
    int o = i - 983040;
    int j = o & 7, l = (o >> 3) & 63, kc = (o >> 9) & 3, nt = (o >> 11) & 3;
    int coG = o >> 13;
    int co = coG * 64 + nt * 16 + (l & 15);
    int ci = kc * 32 + (l >> 4) * 8 + j;
    ws[WA2_US + o] = f2bs(w_attn[co * 128 + ci]);
  } else if (i < 1000448) {      // krw bf16 [64][16], row 63 zero
    int j = i - 999424; int c = j >> 4, d = j & 15;
    ws[KRWB_US + j] = (c < 63) ? f2bs(krw[c * 16 + d]) : (unsigned short)0;
  } else if (i < 1001472) {
    int j = i - 1000448; int c = j >> 4, d = j & 15;
    ws[KRHB_US + j] = (c < 63) ? f2bs(krh[c * 16 + d]) : (unsigned short)0;
  }
}

// ---------------------------------------------------------------------------
__global__ __launch_bounds__(256) void zero_xc_kernel(unsigned short* __restrict__ xc) {
  int i = blockIdx.x * 256 + threadIdx.x;   // 295,936 uint4 = 2,367,488 us
  uint4 z = {0u, 0u, 0u, 0u};
  ((uint4*)xc)[i] = z;
}

// ---------------------------------------------------------------------------
// x [b][ci][pos] fp32 -> XC[b][ci>>5][y+1][x+1][ci&31] bf16 via LDS tile.
__global__ __launch_bounds__(256) void xt_kernel(
    const float* __restrict__ x, unsigned short* __restrict__ xc) {
  __shared__ float t[64][65];
  int tid = threadIdx.x; int pl = tid & 63, cg = tid >> 6;
  int pos0 = blockIdx.x * 64, ci0 = blockIdx.y * 64, b = blockIdx.z;
  const float* xb = x + ((size_t)(b * 256 + ci0)) * 1024 + pos0;
#pragma unroll
  for (int i = 0; i < 16; ++i) {
    int ci_l = cg * 16 + i;
    t[ci_l][pl] = xb[(size_t)ci_l * 1024 + pl];
  }
  __syncthreads();
#pragma unroll
  for (int i = 0; i < 16; ++i) {
    int pos_l = cg * 16 + i;
    int pos = pos0 + pos_l;
    int y = (pos >> 5) + 1, xx = (pos & 31) + 1;
    int ci = ci0 + pl;
    xc[((size_t)((b * 8 + (ci >> 5)) * 34 + y) * 34 + xx) * 32 + (ci & 31)] =
        f2bs(t[pl][pos_l]);
  }
}

// ---------------------------------------------------------------------------
// kqv GEMM: A-frags from XC (tap 1,1; contiguous 1KB loads), B from WK2.
// 4 waves/block; wave (mh,nh) owns the 2x2 quadrant (mt=mh*2+mi, nt=nh*2+ni).
// R5: full kc unroll + 4-slot depth-3 rolling prefetch of A/B fragments.
__global__ __launch_bounds__(256) void kqv_mfma(
    const unsigned short* __restrict__ xc, const unsigned short* __restrict__ wk2,
    const float* __restrict__ bkqv, unsigned short* __restrict__ dq) {
  int tid = threadIdx.x;
  int lane = tid & 63; int il = lane & 15, q = lane >> 4;
  int wv = tid >> 6; int mh = wv >> 1, nh = wv & 1;
  int m0 = blockIdx.x * 64, coG = blockIdx.y;
  int b = m0 >> 10, pos0 = m0 & 1023;
  int row0 = pos0 >> 5;
  v4f acc[2][2];
#pragma unroll
  for (int mi = 0; mi < 2; ++mi)
#pragma unroll
    for (int ni = 0; ni < 2; ++ni) acc[mi][ni] = (v4f){0.f, 0.f, 0.f, 0.f};

  int pix[2];
#pragma unroll
  for (int mi = 0; mi < 2; ++mi)
    pix[mi] = (row0 + mh + 1) * 34 + (mi * 16 + il + 1);
  const unsigned short* bt = wk2 + (size_t)coG * 16384 + lane * 8;
  const unsigned short* at = xc + (size_t)(b * 8) * 36992 + q * 8;

  v8s afS[4][2], bfS[4][2];
  // prologue: preload kc = 0..2 into slots 0..2
#pragma unroll
  for (int p = 0; p < 3; ++p) {
#pragma unroll
    for (int ni = 0; ni < 2; ++ni)
      bfS[p][ni] = *(const v8s*)(bt + ((nh * 2 + ni) * 8 + p) * 512);
#pragma unroll
    for (int mi = 0; mi < 2; ++mi)
      afS[p][mi] = *(const v8s*)(at + (size_t)p * 36992 + pix[mi] * 32);
  }

#pragma unroll
  for (int kc = 0; kc < 8; ++kc) {
    if (kc + 3 < 8) {
      int kn = kc + 3, s = kn & 3;
#pragma unroll
      for (int ni = 0; ni < 2; ++ni)
        bfS[s][ni] = *(const v8s*)(bt + ((nh * 2 + ni) * 8 + kn) * 512);
#pragma unroll
      for (int mi = 0; mi < 2; ++mi)
        afS[s][mi] = *(const v8s*)(at + (size_t)kn * 36992 + pix[mi] * 32);
    }
    int cs = kc & 3;
#pragma unroll
    for (int mi = 0; mi < 2; ++mi)
#pragma unroll
      for (int ni = 0; ni < 2; ++ni)
        acc[mi][ni] = __builtin_amdgcn_mfma_f32_16x16x32_bf16(
            afS[cs][mi], bfS[cs][ni], acc[mi][ni], 0, 0, 0);
  }
  int co0 = coG * 64;
#pragma unroll
  for (int ni = 0; ni < 2; ++ni) {
    int nt = nh * 2 + ni;
    int cob = co0 + nt * 16;
    int co = cob + il;
    float bias = bkqv[co];
    int cls = cob >> 7;                  // 0:k 1:q 2:v (uniform per nt)
    int h = (cob >> 4) & 7;
    size_t bh = (size_t)(b * 8 + h);
#pragma unroll
    for (int mi = 0; mi < 2; ++mi) {
      int mt = mh * 2 + mi;
      int pos = pos0 + mt * 16 + q * 4;
      v4f a = acc[mi][ni];
#pragma unroll
      for (int r = 0; r < 4; ++r) {
        float v = a[r] + bias;
        int p = pos + r;
        if (cls == 0)      dq[KS_US + bh * 16384 + p * 16 + il] = f2bs(v);
        else if (cls == 1) dq[QS_US + bh * 16384 + p * 16 + il] = f2bs(v * QSCALE);
        else               dq[VTS_US + bh * 16384 + ((p >> 5) * 16 + il) * 32 + (p & 31)] = f2bs(v);
      }
    }
  }
}

// ---------------------------------------------------------------------------
// MFMA attention, S-transposed formulation. Block 256 = 4 waves; wave owns a
// 16-row m-tile. Lane (q,il) reg r holds S[m0+il][nb+q*4+r].
// R4: depth-1 register prefetch of next-ny K/V (T14: latency under compute).
__global__ __launch_bounds__(256) void attn_mfma(
    unsigned short* __restrict__ dq, const unsigned short* __restrict__ krwb,
    const unsigned short* __restrict__ krhb, unsigned short* __restrict__ wsart) {
  __shared__ float lds[4][2448];
  int tid = threadIdx.x; int w = tid >> 6, lane = tid & 63;
  int il = lane & 15, q = lane >> 4;
  int bh = blockIdx.y; int b = bh >> 3, h = bh & 7;
  int m0 = blockIdx.x * 64 + w * 16;
  int my = m0 >> 5, mxb = m0 & 31;
  float* pw = lds[w];                       // [16 rows][stride 64]
  float* ph = pw + 1024;                    // [16 rows][stride 68], - SHIFT2
  unsigned short* pl = (unsigned short*)(ph + 1088);  // [16 rows][stride 40] bf16

  const v8s z8 = {0, 0, 0, 0, 0, 0, 0, 0};
  const v4f z4 = {0.f, 0.f, 0.f, 0.f};

  // Q frag: A-layout for table build == B-layout for S^T (same registers).
  const unsigned short* qrow = dq + QS_US + (size_t)bh * 16384 + (m0 + il) * 16;
  v8s qa = *(const v8s*)(qrow + (q & 1) * 8);
  qa = (q < 2) ? qa : z8;

  // PW / PH tables via MFMA (C row = m-row in tile, col = table col)
#pragma unroll
  for (int nt = 0; nt < 4; ++nt) {
    int c = nt * 16 + il;
    v8s bw = *(const v8s*)(krwb + c * 16 + (q & 1) * 8);
    v8s bhh = *(const v8s*)(krhb + c * 16 + (q & 1) * 8);
    bw = (q < 2) ? bw : z8;
    bhh = (q < 2) ? bhh : z8;
    v4f pwc = __builtin_amdgcn_mfma_f32_16x16x32_bf16(qa, bw, z4, 0, 0, 0);
    v4f phc = __builtin_amdgcn_mfma_f32_16x16x32_bf16(qa, bhh, z4, 0, 0, 0);
#pragma unroll
    for (int r = 0; r < 4; ++r) {
      pw[(q * 4 + r) * 64 + c] = pwc[r];
      ph[(q * 4 + r) * 68 + c] = phc[r] - SHIFT2;
    }
  }
  __builtin_amdgcn_wave_barrier();

  // pw lookups are ny-invariant per lane in the transposed scheme: hoist.
  float pwv[2][4];
#pragma unroll
  for (int nt2 = 0; nt2 < 2; ++nt2)
#pragma unroll
    for (int r = 0; r < 4; ++r)
      pwv[nt2][r] = pw[il * 64 + (nt2 * 16 + q * 4 + r) - mxb - il + 31];

  v4f oacc = z4;
  float sacc = 0.f;
  const unsigned short* kbase = dq + KS_US + (size_t)bh * 16384;
  const unsigned short* vbase = dq + VTS_US + (size_t)bh * 16384;

  // depth-1 prefetch of ny=0 K/V fragments
  v8s kb0 = *(const v8s*)(kbase + (il) * 16 + (q & 1) * 8);
  v8s kb1 = *(const v8s*)(kbase + (16 + il) * 16 + (q & 1) * 8);
  v8s vb0 = *(const v8s*)(vbase + (il) * 32 + q * 8);

  for (int ny = 0; ny < 32; ++ny) {
    v8s kc0 = (q < 2) ? kb0 : z8;
    v8s kc1 = (q < 2) ? kb1 : z8;
    v8s vcur = vb0;
    if (ny < 31) {   // issue next-ny loads; land under softmax + PV below
      kb0 = *(const v8s*)(kbase + ((ny + 1) * 32 + il) * 16 + (q & 1) * 8);
      kb1 = *(const v8s*)(kbase + ((ny + 1) * 32 + 16 + il) * 16 + (q & 1) * 8);
      vb0 = *(const v8s*)(vbase + ((ny + 1) * 16 + il) * 32 + q * 8);
    }
    float phv = ph[il * 68 + (ny - my + 31)];
    v4f s[2];
    s[0] = __builtin_amdgcn_mfma_f32_16x16x32_bf16(kc0, qa, z4, 0, 0, 0);
    s[1] = __builtin_amdgcn_mfma_f32_16x16x32_bf16(kc1, qa, z4, 0, 0, 0);
#pragma unroll
    for (int nt2 = 0; nt2 < 2; ++nt2) {
      float p[4];
#pragma unroll
      for (int r = 0; r < 4; ++r) {
        float t = s[nt2][r] + pwv[nt2][r] + phv;
        p[r] = exp2f(t);
        sacc += p[r];
      }
      uint2 pk;
      pk.x = (unsigned)f2bs(p[0]) | ((unsigned)f2bs(p[1]) << 16);
      pk.y = (unsigned)f2bs(p[2]) | ((unsigned)f2bs(p[3]) << 16);
      *(uint2*)(pl + il * 40 + nt2 * 16 + q * 4) = pk;
    }
    __builtin_amdgcn_wave_barrier();
    v8s pf = *(const v8s*)(pl + il * 40 + q * 8);
    oacc = __builtin_amdgcn_mfma_f32_16x16x32_bf16(pf, vcur, oacc, 0, 0, 0);
    __builtin_amdgcn_wave_barrier();
  }

  // row sums: lane holds partial for row il; combine quads, then fetch per-r.
  sacc += __shfl_xor(sacc, 16);
  sacc += __shfl_xor(sacc, 32);

  unsigned short* abase = (b < 6) ? (dq + ART1_US + (size_t)b * 131072)
                                  : (wsart + (size_t)(b - 6) * 131072);
#pragma unroll
  for (int r = 0; r < 4; ++r) {
    float sr = __shfl(sacc, q * 4 + r);       // full sum for row q*4+r
    int m = m0 + q * 4 + r;
    int c = h * 16 + (m >> 6);                // ci of art
    int pp = (m & 63) * 16 + il;              // pos' of art
    abase[((c >> 5) * 1024 + pp) * 32 + (c & 31)] = f2bs(oacc[r] / sr);
  }
}

// ---------------------------------------------------------------------------
// attn_out GEMM: A from artX (contiguous), B from WA2 (frag-major).
// 4 waves/block; wave (mh,nh) owns the 2x2 quadrant.
__global__ __launch_bounds__(256) void attn_out_mfma(
    const unsigned short* __restrict__ dq, const unsigned short* __restrict__ wsart,
    const unsigned short* __restrict__ wa2, const float* __restrict__ ba,
    float* __restrict__ out) {
  int tid = threadIdx.x;
  int lane = tid & 63; int il = lane & 15, q = lane >> 4;
  int wv = tid >> 6; int mh = wv >> 1, nh = wv & 1;
  int m0 = blockIdx.x * 64, coG = blockIdx.y;
  int b = m0 >> 10, pp0 = m0 & 1023;
  const unsigned short* ab = (b < 6) ? (dq + ART1_US + (size_t)b * 131072)
                                     : (wsart + (size_t)(b - 6) * 131072);
  const unsigned short* bt = wa2 + (size_t)coG * 8192 + lane * 8;
  v4f acc[2][2];
#pragma unroll
  for (int mi = 0; mi < 2; ++mi)
#pragma unroll
    for (int ni = 0; ni < 2; ++ni) acc[mi][ni] = (v4f){0.f, 0.f, 0.f, 0.f};
#pragma unroll
  for (int kc = 0; kc < 4; ++kc) {
    v8s af[2], bf[2];
#pragma unroll
    for (int ni = 0; ni < 2; ++ni)
      bf[ni] = *(const v8s*)(bt + ((nh * 2 + ni) * 4 + kc) * 512);
#pragma unroll
    for (int mi = 0; mi < 2; ++mi)
      af[mi] = *(const v8s*)(ab + (kc * 1024 + pp0 + (mh * 2 + mi) * 16 + il) * 32 + q * 8);
#pragma unroll
    for (int mi = 0; mi < 2; ++mi)
#pragma unroll
      for (int ni = 0; ni < 2; ++ni)
        acc[mi][ni] = __builtin_amdgcn_mfma_f32_16x16x32_bf16(
            af[mi], bf[ni], acc[mi][ni], 0, 0, 0);
  }
  int co0 = coG * 64;
#pragma unroll
  for (int ni = 0; ni < 2; ++ni) {
    int co = co0 + (nh * 2 + ni) * 16 + il;
    float bias = ba[co];
#pragma unroll
    for (int mi = 0; mi < 2; ++mi) {
      int mt = mh * 2 + mi;
      v4f a = acc[mi][ni];
      float4 v; v.x = a[0] + bias; v.y = a[1] + bias;
      v.z = a[2] + bias; v.w = a[3] + bias;
      *(float4*)(out + ((size_t)(b * 512 + 384 + co)) * 1024 + pp0 + mt * 16 + q * 4) = v;
    }
  }
}

// ---------------------------------------------------------------------------
// conv3x3 via MFMA (R7/v5). Block 512 thr = 8 waves, 128 pos x 96 cout
// (wave = mh(0..3) x nh(0..1), tile 32pos x 48cout, 6 MFMA/tap).
// Per kc: W tile [6 nfg][9 tap][512us] (54KB) + X tile [6 row][4 q][34 x][8ci]
// (13KB) staged to LDS via global_load_lds (wave-uniform slot base, lane x16B
// auto-offset; permuted global source). Single-buffered; 2 barriers/kc;
// staging stall covered by co-resident block (LDS 68.6KB -> 2 blocks/CU).
// All 8 waves share the W tile: L2 weight traffic 442MB -> 110MB.
// Grid (64,4): b = bx&7 pins batch to XCD.
__global__ __launch_bounds__(512, 4) void conv_mfma(
    const unsigned short* __restrict__ xc, const unsigned short* __restrict__ wb3,
    const float* __restrict__ bo, float* __restrict__ out) {
  __shared__ unsigned short xlds[6656];     // 13 slots x 512 (816 chunks + pad)
  __shared__ unsigned short wlds[27648];    // 54 slots x 512
  int tid = threadIdx.x;
  int lane = tid & 63; int il = lane & 15, q = lane >> 4;
  int wv = tid >> 6; int mh = wv >> 1, nh = wv & 1;
  int bx = blockIdx.x, nset = blockIdx.y;
  int b = bx & 7, pt = bx >> 3;             // pt 0..7; b fastest => XCD-pinned
  int pos0 = pt * 128, y0 = pt * 4;
  const unsigned short* xb = xc + ((size_t)(b * 8) * 1156 + y0 * 34) * 32;

  v4f acc[2][3];
#pragma unroll
  for (int mi = 0; mi < 2; ++mi)
#pragma unroll
    for (int j = 0; j < 3; ++j) acc[mi][j] = (v4f){0.f, 0.f, 0.f, 0.f};

  // X: lds chunk c=(row*4+q)*34+x <- global chunk row*136+x*4+q of slice kc.
  auto stageX = [&](int kc) {
    const unsigned short* src = xb + (size_t)kc * 36992;   // 1156*32
#pragma unroll
    for (int t = 0; t < 2; ++t) {
      int s = wv + t * 8;                   // wave-uniform slot
      if (s < 13) {
        int c = s * 64 + lane;
        int row = c / 136, rem = c % 136;
        int qv = rem / 34, xx = rem % 34;
        const unsigned short* g = src + ((row * 136 + xx * 4 + qv) << 3);
        __builtin_amdgcn_global_load_lds(
            (const __attribute__((address_space(1))) void*)g,
            (__attribute__((address_space(3))) void*)(&xlds[s * 512]),
            16, 0, 0);
      }
    }
  };

  // W: lds [nfg][tap][512] <- WB3[(nset*6+nfg)][kc][tap]; slot s: nfg=s/9,tap=s%9.
  auto stageW = [&](int kc) {
#pragma unroll
    for (int t = 0; t < 7; ++t) {
      int s = wv + t * 8;                   // wave-uniform slot
      if (s < 54) {
        int nfg = s / 9, tp = s % 9;
        const unsigned short* g = wb3 +
            ((size_t)(((nset * 6 + nfg) * 8 + kc) * 9 + tp) * 512 + lane * 8);
        __builtin_amdgcn_global_load_lds(
            (const __attribute__((address_space(1))) void*)g,
            (__attribute__((address_space(3))) void*)(&wlds[s * 512]),
            16, 0, 0);
      }
    }
  };

  stageX(0);
  stageW(0);
  __syncthreads();

  for (int kc = 0; kc < 8; ++kc) {
#pragma unroll
    for (int tap = 0; tap < 9; ++tap) {
      int ky = tap / 3, kx = tap % 3;
      v8s af[2], bf[3];
#pragma unroll
      for (int j = 0; j < 3; ++j)
        bf[j] = *(const v8s*)&wlds[((nh * 3 + j) * 9 + tap) * 512 + lane * 8];
#pragma unroll
      for (int mi = 0; mi < 2; ++mi) {
        int mf = mh * 2 + mi;
        af[mi] = *(const v8s*)&xlds[((((mf >> 1) + ky) * 4 + q) * 34 +
                                     ((mf & 1) * 16 + kx + il)) * 8];
      }
#pragma unroll
      for (int mi = 0; mi < 2; ++mi)
#pragma unroll
        for (int j = 0; j < 3; ++j)
          acc[mi][j] = __builtin_amdgcn_mfma_f32_16x16x32_bf16(
              af[mi], bf[j], acc[mi][j], 0, 0, 0);
    }
    if (kc < 7) {
      __syncthreads();                      // all reads of W/X done
      stageX(kc + 1);
      stageW(kc + 1);
      __syncthreads();                      // staging drained (vmcnt 0)
    }
  }

  int co0 = nset * 96;
#pragma unroll
  for (int j = 0; j < 3; ++j) {
    int co = co0 + (nh * 3 + j) * 16 + il;
    float bias = bo[co];
#pragma unroll
    for (int mi = 0; mi < 2; ++mi) {
      int mf = mh * 2 + mi;
      v4f a = acc[mi][j];
      float4 v; v.x = a[0] + bias; v.y = a[1] + bias;
      v.z = a[2] + bias; v.w = a[3] + bias;
      *(float4*)(out + ((size_t)(b * 512 + co)) * 1024 +
                 pos0 + mf * 16 + q * 4) = v;
    }
  }
}

// ---------------------------------------------------------------------------
extern "C" void kernel_launch(void* const* d_in, const int* in_sizes, int n_in,
                              void* d_out, int out_size, void* d_ws, size_t ws_size,
                              hipStream_t stream) {
  const float* x      = (const float*)d_in[0];
  const float* b_out  = (const float*)d_in[2];
  const float* b_kqv  = (const float*)d_in[4];
  const float* b_attn = (const float*)d_in[6];
  const float* krw    = (const float*)d_in[7];
  const float* krh    = (const float*)d_in[8];
  unsigned short* ws = (unsigned short*)d_ws;
  float* out = (float*)d_out;
  unsigned short* dq = (unsigned short*)d_out;

  prep_kernel<<<3912, 256, 0, stream>>>(
      (const float*)d_in[1], (const float*)d_in[3], (const float*)d_in[5],
      krw, krh, ws);
  zero_xc_kernel<<<1156, 256, 0, stream>>>(ws + XC_US);
  xt_kernel<<<dim3(16, 4, 8), 256, 0, stream>>>(x, ws + XC_US);
  kqv_mfma<<<dim3(128, 6), 256, 0, stream>>>(
      ws + XC_US, ws + WK2_US, b_kqv, dq);
  attn_mfma<<<dim3(16, 64), 256, 0, stream>>>(
      dq, ws + KRWB_US, ws + KRHB_US, ws + ART2_US);
  attn_out_mfma<<<dim3(128, 2), 256, 0, stream>>>(
      dq, ws + ART2_US, ws + WA2_US, b_attn, out);
  conv_mfma<<<dim3(64, 4), 512, 0, stream>>>(
      ws + XC_US, ws + WB2_US, b_out, out);
}

// Round 8
// 148.966 us; speedup vs baseline: 1.2294x; 1.0381x over previous
//
#include <hip/hip_runtime.h>
#include <hip/hip_bf16.h>

// ---------------------------------------------------------------------------
// SelfAttention2d, fully-MFMA pipeline, fragment-major memory layouts.
// MFMA 16x16x32 bf16: A[m=il][k=q*8+j], B[col=il][k=q*8+j], C[row=q*4+r][col=il]
//
// R8: structural. (a) prep + XC-ring-zero + xt fused into ONE launch (they
// write disjoint ws regions); zero_xc dropped entirely — xt covers the whole
// interior, only the 132-pixel pad ring per [b][kc] slice needs zeroing.
// 7 -> 5 launches. (b) attn: removed the (q<2)?frag:z8 masks on QK/table
// A-operands — the B operand (qa) is already zeroed for k>=16, so finite
// A values there contribute A*0=0; saves ~8 v_cndmask per hot-loop iter.
// (attn_out+conv fusion was evaluated and REJECTED: conv's b=7 output bytes
// alias the ART1 scratch attn_out reads concurrently.)
//
// Attention computes S TRANSPOSED (A=K, B=Q) so each lane holds
// S[m=m0+il][n=nb+q*4+r]:  pw lookups become ny-invariant registers, ph is one
// read/ny, and P needs only an 8B LDS write + b128 read to become the PV
// A-operand (full K=32).
//
// Layouts:
//   XC   [b][kc 0..7][y 0..33][x 0..33][ci 32]  zero-padded image, bf16
//   WB3  [coG6][nt4][kc8][tap9][lane64][8]      w_out frag-major
//   WK2  [coG6][nt4][kc8][lane64][8]            w_kqv frag-major
//   WA2  [coG2][nt4][kc4][lane64][8]            w_attn frag-major
//   VT   [bh][ny32][d16][ci 32]                 V^T frag-major
//   artX [b][kc4][pp1024][ci32]                 attn out, frag-major
//
// ws (ushort units, 7,262,208 B <= proven-safe 8,192,000):
//   WB3 0 / WK2 884736 / WA2 983040 / KRWB 999424 / KRHB 1000448 /
//   XC 1001472 (2,367,488) / ART2 3368960 (b=6,7 slots)
// d_out scratch (ushort): KS 0 / QS 1048576 / VT 2097152 / ART1 7340032 (b0..5)
// Order: prep(+ring+xt) -> kqv -> attn -> attn_out -> conv
// ---------------------------------------------------------------------------

typedef short v8s __attribute__((ext_vector_type(8)));
typedef float v4f __attribute__((ext_vector_type(4)));

#define WB2_US   0u
#define WK2_US   884736u
#define WA2_US   983040u
#define KRWB_US  999424u
#define KRHB_US  1000448u
#define XC_US    1001472u
#define ART2_US  3368960u

#define KS_US    0u
#define QS_US    1048576u
#define VTS_US   2097152u
#define ART1_US  7340032u

#define QSCALE 0.360673760f   // 0.25 * log2(e)
#define SHIFT2 17.3123405f    // 12 * log2(e)

__device__ __forceinline__ unsigned short f2bs(float f) {
  __hip_bfloat16 h = __float2bfloat16(f);
  return *reinterpret_cast<unsigned short*>(&h);
}

// ---------------------------------------------------------------------------
// Fused: [0,3912) weight/KR transform; [3912,4044) XC pad-ring zero;
// [4044,4556) xt (x fp32 -> XC interior bf16).
__global__ __launch_bounds__(256) void prep_kernel(
    const float* __restrict__ w_out, const float* __restrict__ w_kqv,
    const float* __restrict__ w_attn, const float* __restrict__ krw,
    const float* __restrict__ krh, const float* __restrict__ x,
    unsigned short* __restrict__ ws) {
  __shared__ float t[64][65];
  int bx = blockIdx.x;
  if (bx < 3912) {
    int i = bx * 256 + threadIdx.x;
    if (i < 884736) {              // WB3[coG][nt][kc][tap][lane][8]
      int j = i & 7, l = (i >> 3) & 63;
      int r = i >> 9;              // fragment chunk index [coG][nt][kc][tap]
      int tap = r % 9; int r2 = r / 9;
      int kc = r2 & 7, nt = (r2 >> 3) & 3, coG = r2 >> 5;
      int co = coG * 64 + nt * 16 + (l & 15);
      int ci = kc * 32 + (l >> 4) * 8 + j;
      ws[WB2_US + i] = f2bs(w_out[(size_t)co * 2304 + ci * 9 + tap]);
    } else if (i < 983040) {       // WK2[coG][nt][kc][lane][8]
      int o = i - 884736;
      int j = o & 7, l = (o >> 3) & 63, kc = (o >> 9) & 7, nt = (o >> 12) & 3;
      int coG = o >> 14;
      int co = coG * 64 + nt * 16 + (l & 15);
      int ci = kc * 32 + (l >> 4) * 8 + j;
      ws[WK2_US + o] = f2bs(w_kqv[co * 256 + ci]);
    } else if (i < 999424) {       // WA2[coG][nt][kc][lane][8]
      int o = i - 983040;
      int j = o & 7, l = (o >> 3) & 63, kc = (o >> 9) & 3, nt = (o >> 11) & 3;
      int coG = o >> 13;
      int co = coG * 64 + nt * 16 + (l & 15);
      int ci = kc * 32 + (l >> 4) * 8 + j;
      ws[WA2_US + o] = f2bs(w_attn[co * 128 + ci]);
    } else if (i < 1000448) {      // krw bf16 [64][16], row 63 zero
      int j = i - 999424; int c = j >> 4, d = j & 15;
      ws[KRWB_US + j] = (c < 63) ? f2bs(krw[c * 16 + d]) : (unsigned short)0;
    } else if (i < 1001472) {
      int j = i - 1000448; int c = j >> 4, d = j & 15;
      ws[KRHB_US + j] = (c < 63) ? f2bs(krh[c * 16 + d]) : (unsigned short)0;
    }
  } else if (bx < 4044) {
    // XC pad ring: 64 slices x 132 pixels x 4 uint4. 33792 uint4 total.
    int g = (bx - 3912) * 256 + threadIdx.x;
    int slice = g / 528, rem = g % 528;
    int pix = rem >> 2, d = rem & 3;
    int y, xx;
    if (pix < 34)       { y = 0;        xx = pix; }
    else if (pix < 68)  { y = 33;       xx = pix - 34; }
    else if (pix < 100) { y = pix - 67; xx = 0; }
    else                { y = pix - 99; xx = 33; }
    uint4 z = {0u, 0u, 0u, 0u};
    ((uint4*)(ws + XC_US))[(slice * 1156 + y * 34 + xx) * 4 + d] = z;
  } else {
    // xt: x [b][ci][pos] fp32 -> XC[b][ci>>5][y+1][x+1][ci&31] bf16.
    int blk = bx - 4044;
    int tid = threadIdx.x; int pl = tid & 63, cg = tid >> 6;
    int pos0 = (blk & 15) * 64, ci0 = ((blk >> 4) & 3) * 64, b = blk >> 6;
    unsigned short* xc = ws + XC_US;
    const float* xb = x + ((size_t)(b * 256 + ci0)) * 1024 + pos0;
#pragma unroll
    for (int i = 0; i < 16; ++i) {
      int ci_l = cg * 16 + i;
      t[ci_l][pl] = xb[(size_t)ci_l * 1024 + pl];
    }
    __syncthreads();
#pragma unroll
    for (int i = 0; i < 16; ++i) {
      int pos_l = cg * 16 + i;
      int pos = pos0 + pos_l;
      int y = (pos >> 5) + 1, xx = (pos & 31) + 1;
      int ci = ci0 + pl;
      xc[((size_t)((b * 8 + (ci >> 5)) * 34 + y) * 34 + xx) * 32 + (ci & 31)] =
          f2bs(t[pl][pos_l]);
    }
  }
}

// ---------------------------------------------------------------------------
// kqv GEMM: A-frags from XC (tap 1,1; contiguous 1KB loads), B from WK2.
// 4 waves/block; wave (mh,nh) owns the 2x2 quadrant (mt=mh*2+mi, nt=nh*2+ni).
// Full kc unroll + 4-slot depth-3 rolling prefetch of A/B fragments.
__global__ __launch_bounds__(256) void kqv_mfma(
    const unsigned short* __restrict__ xc, const unsigned short* __restrict__ wk2,
    const float* __restrict__ bkqv, unsigned short* __restrict__ dq) {
  int tid = threadIdx.x;
  int lane = tid & 63; int il = lane & 15, q = lane >> 4;
  int wv = tid >> 6; int mh = wv >> 1, nh = wv & 1;
  int m0 = blockIdx.x * 64, coG = blockIdx.y;
  int b = m0 >> 10, pos0 = m0 & 1023;
  int row0 = pos0 >> 5;
  v4f acc[2][2];
#pragma unroll
  for (int mi = 0; mi < 2; ++mi)
#pragma unroll
    for (int ni = 0; ni < 2; ++ni) acc[mi][ni] = (v4f){0.f, 0.f, 0.f, 0.f};

  int pix[2];
#pragma unroll
  for (int mi = 0; mi < 2; ++mi)
    pix[mi] = (row0 + mh + 1) * 34 + (mi * 16 + il + 1);
  const unsigned short* bt = wk2 + (size_t)coG * 16384 + lane * 8;
  const unsigned short* at = xc + (size_t)(b * 8) * 36992 + q * 8;

  v8s afS[4][2], bfS[4][2];
  // prologue: preload kc = 0..2 into slots 0..2
#pragma unroll
  for (int p = 0; p < 3; ++p) {
#pragma unroll
    for (int ni = 0; ni < 2; ++ni)
      bfS[p][ni] = *(const v8s*)(bt + ((nh * 2 + ni) * 8 + p) * 512);
#pragma unroll
    for (int mi = 0; mi < 2; ++mi)
      afS[p][mi] = *(const v8s*)(at + (size_t)p * 36992 + pix[mi] * 32);
  }

#pragma unroll
  for (int kc = 0; kc < 8; ++kc) {
    if (kc + 3 < 8) {
      int kn = kc + 3, s = kn & 3;
#pragma unroll
      for (int ni = 0; ni < 2; ++ni)
        bfS[s][ni] = *(const v8s*)(bt + ((nh * 2 + ni) * 8 + kn) * 512);
#pragma unroll
      for (int mi = 0; mi < 2; ++mi)
        afS[s][mi] = *(const v8s*)(at + (size_t)kn * 36992 + pix[mi] * 32);
    }
    int cs = kc & 3;
#pragma unroll
    for (int mi = 0; mi < 2; ++mi)
#pragma unroll
      for (int ni = 0; ni < 2; ++ni)
        acc[mi][ni] = __builtin_amdgcn_mfma_f32_16x16x32_bf16(
            afS[cs][mi], bfS[cs][ni], acc[mi][ni], 0, 0, 0);
  }
  int co0 = coG * 64;
#pragma unroll
  for (int ni = 0; ni < 2; ++ni) {
    int nt = nh * 2 + ni;
    int cob = co0 + nt * 16;
    int co = cob + il;
    float bias = bkqv[co];
    int cls = cob >> 7;                  // 0:k 1:q 2:v (uniform per nt)
    int h = (cob >> 4) & 7;
    size_t bh = (size_t)(b * 8 + h);
#pragma unroll
    for (int mi = 0; mi < 2; ++mi) {
      int mt = mh * 2 + mi;
      int pos = pos0 + mt * 16 + q * 4;
      v4f a = acc[mi][ni];
#pragma unroll
      for (int r = 0; r < 4; ++r) {
        float v = a[r] + bias;
        int p = pos + r;
        if (cls == 0)      dq[KS_US + bh * 16384 + p * 16 + il] = f2bs(v);
        else if (cls == 1) dq[QS_US + bh * 16384 + p * 16 + il] = f2bs(v * QSCALE);
        else               dq[VTS_US + bh * 16384 + ((p >> 5) * 16 + il) * 32 + (p & 31)] = f2bs(v);
      }
    }
  }
}

// ---------------------------------------------------------------------------
// MFMA attention, S-transposed formulation. Block 256 = 4 waves; wave owns a
// 16-row m-tile. Lane (q,il) reg r holds S[m0+il][nb+q*4+r].
// Depth-1 register prefetch of next-ny K/V. R8: A-side masks removed (B=qa
// is zeroed for k>=16, so finite A garbage contributes 0).
__global__ __launch_bounds__(256) void attn_mfma(
    unsigned short* __restrict__ dq, const unsigned short* __restrict__ krwb,
    const unsigned short* __restrict__ krhb, unsigned short* __restrict__ wsart) {
  __shared__ float lds[4][2448];
  int tid = threadIdx.x; int w = tid >> 6, lane = tid & 63;
  int il = lane & 15, q = lane >> 4;
  int bh = blockIdx.y; int b = bh >> 3, h = bh & 7;
  int m0 = blockIdx.x * 64 + w * 16;
  int my = m0 >> 5, mxb = m0 & 31;
  float* pw = lds[w];                       // [16 rows][stride 64]
  float* ph = pw + 1024;                    // [16 rows][stride 68], - SHIFT2
  unsigned short* pl = (unsigned short*)(ph + 1088);  // [16 rows][stride 40] bf16

  const v8s z8 = {0, 0, 0, 0, 0, 0, 0, 0};
  const v4f z4 = {0.f, 0.f, 0.f, 0.f};

  // Q frag: A-layout for table build == B-layout for S^T (same registers).
  // Zeroed for q>=2 (k>=16): this zero makes all A-side masks unnecessary.
  const unsigned short* qrow = dq + QS_US + (size_t)bh * 16384 + (m0 + il) * 16;
  v8s qa = *(const v8s*)(qrow + (q & 1) * 8);
  qa = (q < 2) ? qa : z8;

  // PW / PH tables via MFMA (A=qa zeroed at k>=16; B-side garbage is harmless)
#pragma unroll
  for (int nt = 0; nt < 4; ++nt) {
    int c = nt * 16 + il;
    v8s bw = *(const v8s*)(krwb + c * 16 + (q & 1) * 8);
    v8s bhh = *(const v8s*)(krhb + c * 16 + (q & 1) * 8);
    v4f pwc = __builtin_amdgcn_mfma_f32_16x16x32_bf16(qa, bw, z4, 0, 0, 0);
    v4f phc = __builtin_amdgcn_mfma_f32_16x16x32_bf16(qa, bhh, z4, 0, 0, 0);
#pragma unroll
    for (int r = 0; r < 4; ++r) {
      pw[(q * 4 + r) * 64 + c] = pwc[r];
      ph[(q * 4 + r) * 68 + c] = phc[r] - SHIFT2;
    }
  }
  __builtin_amdgcn_wave_barrier();

  // pw lookups are ny-invariant per lane in the transposed scheme: hoist.
  float pwv[2][4];
#pragma unroll
  for (int nt2 = 0; nt2 < 2; ++nt2)
#pragma unroll
    for (int r = 0; r < 4; ++r)
      pwv[nt2][r] = pw[il * 64 + (nt2 * 16 + q * 4 + r) - mxb - il + 31];

  v4f oacc = z4;
  float sacc = 0.f;
  const unsigned short* kbase = dq + KS_US + (size_t)bh * 16384;
  const unsigned short* vbase = dq + VTS_US + (size_t)bh * 16384;

  // depth-1 prefetch of ny=0 K/V fragments
  v8s kb0 = *(const v8s*)(kbase + (il) * 16 + (q & 1) * 8);
  v8s kb1 = *(const v8s*)(kbase + (16 + il) * 16 + (q & 1) * 8);
  v8s vb0 = *(const v8s*)(vbase + (il) * 32 + q * 8);

  for (int ny = 0; ny < 32; ++ny) {
    v8s kc0 = kb0;          // no mask needed: B=qa zero at k>=16
    v8s kc1 = kb1;
    v8s vcur = vb0;
    if (ny < 31) {   // issue next-ny loads; land under softmax + PV below
      kb0 = *(const v8s*)(kbase + ((ny + 1) * 32 + il) * 16 + (q & 1) * 8);
      kb1 = *(const v8s*)(kbase + ((ny + 1) * 32 + 16 + il) * 16 + (q & 1) * 8);
      vb0 = *(const v8s*)(vbase + ((ny + 1) * 16 + il) * 32 + q * 8);
    }
    float phv = ph[il * 68 + (ny - my + 31)];
    v4f s[2];
    s[0] = __builtin_amdgcn_mfma_f32_16x16x32_bf16(kc0, qa, z4, 0, 0, 0);
    s[1] = __builtin_amdgcn_mfma_f32_16x16x32_bf16(kc1, qa, z4, 0, 0, 0);
#pragma unroll
    for (int nt2 = 0; nt2 < 2; ++nt2) {
      float p[4];
#pragma unroll
      for (int r = 0; r < 4; ++r) {
        float t = s[nt2][r] + pwv[nt2][r] + phv;
        p[r] = exp2f(t);
        sacc += p[r];
      }
      uint2 pk;
      pk.x = (unsigned)f2bs(p[0]) | ((unsigned)f2bs(p[1]) << 16);
      pk.y = (unsigned)f2bs(p[2]) | ((unsigned)f2bs(p[3]) << 16);
      *(uint2*)(pl + il * 40 + nt2 * 16 + q * 4) = pk;
    }
    __builtin_amdgcn_wave_barrier();
    v8s pf = *(const v8s*)(pl + il * 40 + q * 8);
    oacc = __builtin_amdgcn_mfma_f32_16x16x32_bf16(pf, vcur, oacc, 0, 0, 0);
    __builtin_amdgcn_wave_barrier();
  }

  // row sums: lane holds partial for row il; combine quads, then fetch per-r.
  sacc += __shfl_xor(sacc, 16);
  sacc += __shfl_xor(sacc, 32);

  unsigned short* abase = (b < 6) ? (dq + ART1_US + (size_t)b * 131072)
                                  : (wsart + (size_t)(b - 6) * 131072);
#pragma unroll
  for (int r = 0; r < 4; ++r) {
    float sr = __shfl(sacc, q * 4 + r);       // full sum for row q*4+r
    int m = m0 + q * 4 + r;
    int c = h * 16 + (m >> 6);                // ci of art
    int pp = (m & 63) * 16 + il;              // pos' of art
    abase[((c >> 5) * 1024 + pp) * 32 + (c & 31)] = f2bs(oacc[r] / sr);
  }
}

// ---------------------------------------------------------------------------
// attn_out GEMM: A from artX (contiguous), B from WA2 (frag-major).
// 4 waves/block; wave (mh,nh) owns the 2x2 quadrant.
__global__ __launch_bounds__(256) void attn_out_mfma(
    const unsigned short* __restrict__ dq, const unsigned short* __restrict__ wsart,
    const unsigned short* __restrict__ wa2, const float* __restrict__ ba,
    float* __restrict__ out) {
  int tid = threadIdx.x;
  int lane = tid & 63; int il = lane & 15, q = lane >> 4;
  int wv = tid >> 6; int mh = wv >> 1, nh = wv & 1;
  int m0 = blockIdx.x * 64, coG = blockIdx.y;
  int b = m0 >> 10, pp0 = m0 & 1023;
  const unsigned short* ab = (b < 6) ? (dq + ART1_US + (size_t)b * 131072)
                                     : (wsart + (size_t)(b - 6) * 131072);
  const unsigned short* bt = wa2 + (size_t)coG * 8192 + lane * 8;
  v4f acc[2][2];
#pragma unroll
  for (int mi = 0; mi < 2; ++mi)
#pragma unroll
    for (int ni = 0; ni < 2; ++ni) acc[mi][ni] = (v4f){0.f, 0.f, 0.f, 0.f};
#pragma unroll
  for (int kc = 0; kc < 4; ++kc) {
    v8s af[2], bf[2];
#pragma unroll
    for (int ni = 0; ni < 2; ++ni)
      bf[ni] = *(const v8s*)(bt + ((nh * 2 + ni) * 4 + kc) * 512);
#pragma unroll
    for (int mi = 0; mi < 2; ++mi)
      af[mi] = *(const v8s*)(ab + (kc * 1024 + pp0 + (mh * 2 + mi) * 16 + il) * 32 + q * 8);
#pragma unroll
    for (int mi = 0; mi < 2; ++mi)
#pragma unroll
      for (int ni = 0; ni < 2; ++ni)
        acc[mi][ni] = __builtin_amdgcn_mfma_f32_16x16x32_bf16(
            af[mi], bf[ni], acc[mi][ni], 0, 0, 0);
  }
  int co0 = coG * 64;
#pragma unroll
  for (int ni = 0; ni < 2; ++ni) {
    int co = co0 + (nh * 2 + ni) * 16 + il;
    float bias = ba[co];
#pragma unroll
    for (int mi = 0; mi < 2; ++mi) {
      int mt = mh * 2 + mi;
      v4f a = acc[mi][ni];
      float4 v; v.x = a[0] + bias; v.y = a[1] + bias;
      v.z = a[2] + bias; v.w = a[3] + bias;
      *(float4*)(out + ((size_t)(b * 512 + 384 + co)) * 1024 + pp0 + mt * 16 + q * 4) = v;
    }
  }
}

// ---------------------------------------------------------------------------
// conv3x3 via MFMA (R7/v5). Block 512 thr = 8 waves, 128 pos x 96 cout
// (wave = mh(0..3) x nh(0..1), tile 32pos x 48cout, 6 MFMA/tap).
// Per kc: W tile [6 nfg][9 tap][512us] (54KB) + X tile [6 row][4 q][34 x][8ci]
// (13KB) staged to LDS via global_load_lds (wave-uniform slot base, lane x16B
// auto-offset; permuted global source). Single-buffered; 2 barriers/kc;
// staging stall covered by co-resident block (LDS 68.6KB -> 2 blocks/CU).
// All 8 waves share the W tile: L2 weight traffic 442MB -> 110MB.
// Grid (64,4): b = bx&7 pins batch to XCD.
__global__ __launch_bounds__(512, 4) void conv_mfma(
    const unsigned short* __restrict__ xc, const unsigned short* __restrict__ wb3,
    const float* __restrict__ bo, float* __restrict__ out) {
  __shared__ unsigned short xlds[6656];     // 13 slots x 512 (816 chunks + pad)
  __shared__ unsigned short wlds[27648];    // 54 slots x 512
  int tid = threadIdx.x;
  int lane = tid & 63; int il = lane & 15, q = lane >> 4;
  int wv = tid >> 6; int mh = wv >> 1, nh = wv & 1;
  int bx = blockIdx.x, nset = blockIdx.y;
  int b = bx & 7, pt = bx >> 3;             // pt 0..7; b fastest => XCD-pinned
  int pos0 = pt * 128, y0 = pt * 4;
  const unsigned short* xb = xc + ((size_t)(b * 8) * 1156 + y0 * 34) * 32;

  v4f acc[2][3];
#pragma unroll
  for (int mi = 0; mi < 2; ++mi)
#pragma unroll
    for (int j = 0; j < 3; ++j) acc[mi][j] = (v4f){0.f, 0.f, 0.f, 0.f};

  // X: lds chunk c=(row*4+q)*34+x <- global chunk row*136+x*4+q of slice kc.
  auto stageX = [&](int kc) {
    const unsigned short* src = xb + (size_t)kc * 36992;   // 1156*32
#pragma unroll
    for (int t = 0; t < 2; ++t) {
      int s = wv + t * 8;                   // wave-uniform slot
      if (s < 13) {
        int c = s * 64 + lane;
        int row = c / 136, rem = c % 136;
        int qv = rem / 34, xx = rem % 34;
        const unsigned short* g = src + ((row * 136 + xx * 4 + qv) << 3);
        __builtin_amdgcn_global_load_lds(
            (const __attribute__((address_space(1))) void*)g,
            (__attribute__((address_space(3))) void*)(&xlds[s * 512]),
            16, 0, 0);
      }
    }
  };

  // W: lds [nfg][tap][512] <- WB3[(nset*6+nfg)][kc][tap]; slot s: nfg=s/9,tap=s%9.
  auto stageW = [&](int kc) {
#pragma unroll
    for (int t = 0; t < 7; ++t) {
      int s = wv + t * 8;                   // wave-uniform slot
      if (s < 54) {
        int nfg = s / 9, tp = s % 9;
        const unsigned short* g = wb3 +
            ((size_t)(((nset * 6 + nfg) * 8 + kc) * 9 + tp) * 512 + lane * 8);
        __builtin_amdgcn_global_load_lds(
            (const __attribute__((address_space(1))) void*)g,
            (__attribute__((address_space(3))) void*)(&wlds[s * 512]),
            16, 0, 0);
      }
    }
  };

  stageX(0);
  stageW(0);
  __syncthreads();

  for (int kc = 0; kc < 8; ++kc) {
#pragma unroll
    for (int tap = 0; tap < 9; ++tap) {
      int ky = tap / 3, kx = tap % 3;
      v8s af[2], bf[3];
#pragma unroll
      for (int j = 0; j < 3; ++j)
        bf[j] = *(const v8s*)&wlds[((nh * 3 + j) * 9 + tap) * 512 + lane * 8];
#pragma unroll
      for (int mi = 0; mi < 2; ++mi) {
        int mf = mh * 2 + mi;
        af[mi] = *(const v8s*)&xlds[((((mf >> 1) + ky) * 4 + q) * 34 +
                                     ((mf & 1) * 16 + kx + il)) * 8];
      }
#pragma unroll
      for (int mi = 0; mi < 2; ++mi)
#pragma unroll
        for (int j = 0; j < 3; ++j)
          acc[mi][j] = __builtin_amdgcn_mfma_f32_16x16x32_bf16(
              af[mi], bf[j], acc[mi][j], 0, 0, 0);
    }
    if (kc < 7) {
      __syncthreads();                      // all reads of W/X done
      stageX(kc + 1);
      stageW(kc + 1);
      __syncthreads();                      // staging drained (vmcnt 0)
    }
  }

  int co0 = nset * 96;
#pragma unroll
  for (int j = 0; j < 3; ++j) {
    int co = co0 + (nh * 3 + j) * 16 + il;
    float bias = bo[co];
#pragma unroll
    for (int mi = 0; mi < 2; ++mi) {
      int mf = mh * 2 + mi;
      v4f a = acc[mi][j];
      float4 v; v.x = a[0] + bias; v.y = a[1] + bias;
      v.z = a[2] + bias; v.w = a[3] + bias;
      *(float4*)(out + ((size_t)(b * 512 + co)) * 1024 +
                 pos0 + mf * 16 + q * 4) = v;
    }
  }
}

// ---------------------------------------------------------------------------
extern "C" void kernel_launch(void* const* d_in, const int* in_sizes, int n_in,
                              void* d_out, int out_size, void* d_ws, size_t ws_size,
                              hipStream_t stream) {
  const float* x      = (const float*)d_in[0];
  const float* b_out  = (const float*)d_in[2];
  const float* b_kqv  = (const float*)d_in[4];
  const float* b_attn = (const float*)d_in[6];
  const float* krw    = (const float*)d_in[7];
  const float* krh    = (const float*)d_in[8];
  unsigned short* ws = (unsigned short*)d_ws;
  float* out = (float*)d_out;
  unsigned short* dq = (unsigned short*)d_out;

  prep_kernel<<<4556, 256, 0, stream>>>(
      (const float*)d_in[1], (const float*)d_in[3], (const float*)d_in[5],
      krw, krh, x, ws);
  kqv_mfma<<<dim3(128, 6), 256, 0, stream>>>(
      ws + XC_US, ws + WK2_US, b_kqv, dq);
  attn_mfma<<<dim3(16, 64), 256, 0, stream>>>(
      dq, ws + KRWB_US, ws + KRHB_US, ws + ART2_US);
  attn_out_mfma<<<dim3(128, 2), 256, 0, stream>>>(
      dq, ws + ART2_US, ws + WA2_US, b_attn, out);
  conv_mfma<<<dim3(64, 4), 512, 0, stream>>>(
      ws + XC_US, ws + WB2_US, b_out, out);
}

// Round 9
// 144.618 us; speedup vs baseline: 1.2663x; 1.0301x over previous
//
#include <hip/hip_runtime.h>
#include <hip/hip_bf16.h>

// ---------------------------------------------------------------------------
// SelfAttention2d, fully-MFMA pipeline, fragment-major memory layouts.
// MFMA 16x16x32 bf16: A[m=il][k=q*8+j], B[col=il][k=q*8+j], C[row=q*4+r][col=il]
//
// R9: XCD-locality + scheduling. (a) attn grid (16,64)->(64,16): bh on
// blockIdx.x so linear-id%8 = h -> each XCD's K/V working set 4MB -> 512KB
// (L2-resident). (b) kqv/attn_out remapped to 1D grids with b = bx&7 (same
// pin conv uses). (c) attn wave_barriers removed: they only ordered a wave
// against its OWN LDS ops, which lgkmcnt dependency tracking already does —
// they pinned the schedule and blocked cross-ny pipelining.
// (attn_out+conv fusion rejected: art scratch can't be relocated out of the
// fused kernel's write range within the proven-safe ws budget.)
//
// Attention computes S TRANSPOSED (A=K, B=Q) so each lane holds
// S[m=m0+il][n=nb+q*4+r]:  pw lookups become ny-invariant registers, ph is one
// read/ny, and P needs only an 8B LDS write + b128 read to become the PV
// A-operand (full K=32).
//
// Layouts:
//   XC   [b][kc 0..7][y 0..33][x 0..33][ci 32]  zero-padded image, bf16
//   WB3  [coG6][nt4][kc8][tap9][lane64][8]      w_out frag-major
//   WK2  [coG6][nt4][kc8][lane64][8]            w_kqv frag-major
//   WA2  [coG2][nt4][kc4][lane64][8]            w_attn frag-major
//   VT   [bh][ny32][d16][ci 32]                 V^T frag-major
//   artX [b][kc4][pp1024][ci32]                 attn out, frag-major
//
// ws (ushort units, 7,262,208 B <= proven-safe 8,192,000):
//   WB3 0 / WK2 884736 / WA2 983040 / KRWB 999424 / KRHB 1000448 /
//   XC 1001472 (2,367,488) / ART2 3368960 (b=6,7 slots)
// d_out scratch (ushort): KS 0 / QS 1048576 / VT 2097152 / ART1 7340032 (b0..5)
// Order: prep(+ring+xt) -> kqv -> attn -> attn_out -> conv
// ---------------------------------------------------------------------------

typedef short v8s __attribute__((ext_vector_type(8)));
typedef float v4f __attribute__((ext_vector_type(4)));

#define WB2_US   0u
#define WK2_US   884736u
#define WA2_US   983040u
#define KRWB_US  999424u
#define KRHB_US  1000448u
#define XC_US    1001472u
#define ART2_US  3368960u

#define KS_US    0u
#define QS_US    1048576u
#define VTS_US   2097152u
#define ART1_US  7340032u

#define QSCALE 0.360673760f   // 0.25 * log2(e)
#define SHIFT2 17.3123405f    // 12 * log2(e)

__device__ __forceinline__ unsigned short f2bs(float f) {
  __hip_bfloat16 h = __float2bfloat16(f);
  return *reinterpret_cast<unsigned short*>(&h);
}

// ---------------------------------------------------------------------------
// Fused: [0,3912) weight/KR transform; [3912,4044) XC pad-ring zero;
// [4044,4556) xt (x fp32 -> XC interior bf16).
__global__ __launch_bounds__(256) void prep_kernel(
    const float* __restrict__ w_out, const float* __restrict__ w_kqv,
    const float* __restrict__ w_attn, const float* __restrict__ krw,
    const float* __restrict__ krh, const float* __restrict__ x,
    unsigned short* __restrict__ ws) {
  __shared__ float t[64][65];
  int bx = blockIdx.x;
  if (bx < 3912) {
    int i = bx * 256 + threadIdx.x;
    if (i < 884736) {              // WB3[coG][nt][kc][tap][lane][8]
      int j = i & 7, l = (i >> 3) & 63;
      int r = i >> 9;              // fragment chunk index [coG][nt][kc][tap]
      int tap = r % 9; int r2 = r / 9;
      int kc = r2 & 7, nt = (r2 >> 3) & 3, coG = r2 >> 5;
      int co = coG * 64 + nt * 16 + (l & 15);
      int ci = kc * 32 + (l >> 4) * 8 + j;
      ws[WB2_US + i] = f2bs(w_out[(size_t)co * 2304 + ci * 9 + tap]);
    } else if (i < 983040) {       // WK2[coG][nt][kc][lane][8]
      int o = i - 884736;
      int j = o & 7, l = (o >> 3) & 63, kc = (o >> 9) & 7, nt = (o >> 12) & 3;
      int coG = o >> 14;
      int co = coG * 64 + nt * 16 + (l & 15);
      int ci = kc * 32 + (l >> 4) * 8 + j;
      ws[WK2_US + o] = f2bs(w_kqv[co * 256 + ci]);
    } else if (i < 999424) {       // WA2[coG][nt][kc][lane][8]
      int o = i - 983040;
      int j = o & 7, l = (o >> 3) & 63, kc = (o >> 9) & 3, nt = (o >> 11) & 3;
      int coG = o >> 13;
      int co = coG * 64 + nt * 16 + (l & 15);
      int ci = kc * 32 + (l >> 4) * 8 + j;
      ws[WA2_US + o] = f2bs(w_attn[co * 128 + ci]);
    } else if (i < 1000448) {      // krw bf16 [64][16], row 63 zero
      int j = i - 999424; int c = j >> 4, d = j & 15;
      ws[KRWB_US + j] = (c < 63) ? f2bs(krw[c * 16 + d]) : (unsigned short)0;
    } else if (i < 1001472) {
      int j = i - 1000448; int c = j >> 4, d = j & 15;
      ws[KRHB_US + j] = (c < 63) ? f2bs(krh[c * 16 + d]) : (unsigned short)0;
    }
  } else if (bx < 4044) {
    // XC pad ring: 64 slices x 132 pixels x 4 uint4. 33792 uint4 total.
    int g = (bx - 3912) * 256 + threadIdx.x;
    int slice = g / 528, rem = g % 528;
    int pix = rem >> 2, d = rem & 3;
    int y, xx;
    if (pix < 34)       { y = 0;        xx = pix; }
    else if (pix < 68)  { y = 33;       xx = pix - 34; }
    else if (pix < 100) { y = pix - 67; xx = 0; }
    else                { y = pix - 99; xx = 33; }
    uint4 z = {0u, 0u, 0u, 0u};
    ((uint4*)(ws + XC_US))[(slice * 1156 + y * 34 + xx) * 4 + d] = z;
  } else {
    // xt: x [b][ci][pos] fp32 -> XC[b][ci>>5][y+1][x+1][ci&31] bf16.
    int blk = bx - 4044;
    int tid = threadIdx.x; int pl = tid & 63, cg = tid >> 6;
    int pos0 = (blk & 15) * 64, ci0 = ((blk >> 4) & 3) * 64, b = blk >> 6;
    unsigned short* xc = ws + XC_US;
    const float* xb = x + ((size_t)(b * 256 + ci0)) * 1024 + pos0;
#pragma unroll
    for (int i = 0; i < 16; ++i) {
      int ci_l = cg * 16 + i;
      t[ci_l][pl] = xb[(size_t)ci_l * 1024 + pl];
    }
    __syncthreads();
#pragma unroll
    for (int i = 0; i < 16; ++i) {
      int pos_l = cg * 16 + i;
      int pos = pos0 + pos_l;
      int y = (pos >> 5) + 1, xx = (pos & 31) + 1;
      int ci = ci0 + pl;
      xc[((size_t)((b * 8 + (ci >> 5)) * 34 + y) * 34 + xx) * 32 + (ci & 31)] =
          f2bs(t[pl][pos_l]);
    }
  }
}

// ---------------------------------------------------------------------------
// kqv GEMM: A-frags from XC (tap 1,1; contiguous 1KB loads), B from WK2.
// 4 waves/block; wave (mh,nh) owns the 2x2 quadrant (mt=mh*2+mi, nt=nh*2+ni).
// Full kc unroll + 4-slot depth-3 rolling prefetch of A/B fragments.
// R9: 1D grid 768, b = bx&7 pins batch to XCD (XC slice + WK2 L2-resident).
__global__ __launch_bounds__(256) void kqv_mfma(
    const unsigned short* __restrict__ xc, const unsigned short* __restrict__ wk2,
    const float* __restrict__ bkqv, unsigned short* __restrict__ dq) {
  int tid = threadIdx.x;
  int lane = tid & 63; int il = lane & 15, q = lane >> 4;
  int wv = tid >> 6; int mh = wv >> 1, nh = wv & 1;
  int bx = blockIdx.x;
  int b = bx & 7, pt = (bx >> 3) & 15, coG = bx >> 7;
  int pos0 = pt * 64;
  int row0 = pos0 >> 5;
  v4f acc[2][2];
#pragma unroll
  for (int mi = 0; mi < 2; ++mi)
#pragma unroll
    for (int ni = 0; ni < 2; ++ni) acc[mi][ni] = (v4f){0.f, 0.f, 0.f, 0.f};

  int pix[2];
#pragma unroll
  for (int mi = 0; mi < 2; ++mi)
    pix[mi] = (row0 + mh + 1) * 34 + (mi * 16 + il + 1);
  const unsigned short* bt = wk2 + (size_t)coG * 16384 + lane * 8;
  const unsigned short* at = xc + (size_t)(b * 8) * 36992 + q * 8;

  v8s afS[4][2], bfS[4][2];
  // prologue: preload kc = 0..2 into slots 0..2
#pragma unroll
  for (int p = 0; p < 3; ++p) {
#pragma unroll
    for (int ni = 0; ni < 2; ++ni)
      bfS[p][ni] = *(const v8s*)(bt + ((nh * 2 + ni) * 8 + p) * 512);
#pragma unroll
    for (int mi = 0; mi < 2; ++mi)
      afS[p][mi] = *(const v8s*)(at + (size_t)p * 36992 + pix[mi] * 32);
  }

#pragma unroll
  for (int kc = 0; kc < 8; ++kc) {
    if (kc + 3 < 8) {
      int kn = kc + 3, s = kn & 3;
#pragma unroll
      for (int ni = 0; ni < 2; ++ni)
        bfS[s][ni] = *(const v8s*)(bt + ((nh * 2 + ni) * 8 + kn) * 512);
#pragma unroll
      for (int mi = 0; mi < 2; ++mi)
        afS[s][mi] = *(const v8s*)(at + (size_t)kn * 36992 + pix[mi] * 32);
    }
    int cs = kc & 3;
#pragma unroll
    for (int mi = 0; mi < 2; ++mi)
#pragma unroll
      for (int ni = 0; ni < 2; ++ni)
        acc[mi][ni] = __builtin_amdgcn_mfma_f32_16x16x32_bf16(
            afS[cs][mi], bfS[cs][ni], acc[mi][ni], 0, 0, 0);
  }
  int co0 = coG * 64;
#pragma unroll
  for (int ni = 0; ni < 2; ++ni) {
    int nt = nh * 2 + ni;
    int cob = co0 + nt * 16;
    int co = cob + il;
    float bias = bkqv[co];
    int cls = cob >> 7;                  // 0:k 1:q 2:v (uniform per nt)
    int h = (cob >> 4) & 7;
    size_t bh = (size_t)(b * 8 + h);
#pragma unroll
    for (int mi = 0; mi < 2; ++mi) {
      int mt = mh * 2 + mi;
      int pos = pos0 + mt * 16 + q * 4;
      v4f a = acc[mi][ni];
#pragma unroll
      for (int r = 0; r < 4; ++r) {
        float v = a[r] + bias;
        int p = pos + r;
        if (cls == 0)      dq[KS_US + bh * 16384 + p * 16 + il] = f2bs(v);
        else if (cls == 1) dq[QS_US + bh * 16384 + p * 16 + il] = f2bs(v * QSCALE);
        else               dq[VTS_US + bh * 16384 + ((p >> 5) * 16 + il) * 32 + (p & 31)] = f2bs(v);
      }
    }
  }
}

// ---------------------------------------------------------------------------
// MFMA attention, S-transposed formulation. Block 256 = 4 waves; wave owns a
// 16-row m-tile. Lane (q,il) reg r holds S[m0+il][nb+q*4+r].
// Depth-1 register prefetch of next-ny K/V. R9: bh on blockIdx.x (XCD = h,
// K/V L2-resident per XCD); wave_barriers removed (own-wave LDS ordering is
// already guaranteed by lgkmcnt dependency tracking).
__global__ __launch_bounds__(256) void attn_mfma(
    unsigned short* __restrict__ dq, const unsigned short* __restrict__ krwb,
    const unsigned short* __restrict__ krhb, unsigned short* __restrict__ wsart) {
  __shared__ float lds[4][2448];
  int tid = threadIdx.x; int w = tid >> 6, lane = tid & 63;
  int il = lane & 15, q = lane >> 4;
  int bh = blockIdx.x; int b = bh >> 3, h = bh & 7;
  int m0 = blockIdx.y * 64 + w * 16;
  int my = m0 >> 5, mxb = m0 & 31;
  float* pw = lds[w];                       // [16 rows][stride 64]
  float* ph = pw + 1024;                    // [16 rows][stride 68], - SHIFT2
  unsigned short* pl = (unsigned short*)(ph + 1088);  // [16 rows][stride 40] bf16

  const v8s z8 = {0, 0, 0, 0, 0, 0, 0, 0};
  const v4f z4 = {0.f, 0.f, 0.f, 0.f};

  // Q frag: A-layout for table build == B-layout for S^T (same registers).
  // Zeroed for q>=2 (k>=16): this zero makes all A-side masks unnecessary.
  const unsigned short* qrow = dq + QS_US + (size_t)bh * 16384 + (m0 + il) * 16;
  v8s qa = *(const v8s*)(qrow + (q & 1) * 8);
  qa = (q < 2) ? qa : z8;

  // PW / PH tables via MFMA (A=qa zeroed at k>=16; B-side garbage is harmless)
#pragma unroll
  for (int nt = 0; nt < 4; ++nt) {
    int c = nt * 16 + il;
    v8s bw = *(const v8s*)(krwb + c * 16 + (q & 1) * 8);
    v8s bhh = *(const v8s*)(krhb + c * 16 + (q & 1) * 8);
    v4f pwc = __builtin_amdgcn_mfma_f32_16x16x32_bf16(qa, bw, z4, 0, 0, 0);
    v4f phc = __builtin_amdgcn_mfma_f32_16x16x32_bf16(qa, bhh, z4, 0, 0, 0);
#pragma unroll
    for (int r = 0; r < 4; ++r) {
      pw[(q * 4 + r) * 64 + c] = pwc[r];
      ph[(q * 4 + r) * 68 + c] = phc[r] - SHIFT2;
    }
  }

  // pw lookups are ny-invariant per lane in the transposed scheme: hoist.
  float pwv[2][4];
#pragma unroll
  for (int nt2 = 0; nt2 < 2; ++nt2)
#pragma unroll
    for (int r = 0; r < 4; ++r)
      pwv[nt2][r] = pw[il * 64 + (nt2 * 16 + q * 4 + r) - mxb - il + 31];

  v4f oacc = z4;
  float sacc = 0.f;
  const unsigned short* kbase = dq + KS_US + (size_t)bh * 16384;
  const unsigned short* vbase = dq + VTS_US + (size_t)bh * 16384;

  // depth-1 prefetch of ny=0 K/V fragments
  v8s kb0 = *(const v8s*)(kbase + (il) * 16 + (q & 1) * 8);
  v8s kb1 = *(const v8s*)(kbase + (16 + il) * 16 + (q & 1) * 8);
  v8s vb0 = *(const v8s*)(vbase + (il) * 32 + q * 8);

  for (int ny = 0; ny < 32; ++ny) {
    v8s kc0 = kb0;          // no mask needed: B=qa zero at k>=16
    v8s kc1 = kb1;
    v8s vcur = vb0;
    if (ny < 31) {   // issue next-ny loads; land under softmax + PV below
      kb0 = *(const v8s*)(kbase + ((ny + 1) * 32 + il) * 16 + (q & 1) * 8);
      kb1 = *(const v8s*)(kbase + ((ny + 1) * 32 + 16 + il) * 16 + (q & 1) * 8);
      vb0 = *(const v8s*)(vbase + ((ny + 1) * 16 + il) * 32 + q * 8);
    }
    float phv = ph[il * 68 + (ny - my + 31)];
    v4f s[2];
    s[0] = __builtin_amdgcn_mfma_f32_16x16x32_bf16(kc0, qa, z4, 0, 0, 0);
    s[1] = __builtin_amdgcn_mfma_f32_16x16x32_bf16(kc1, qa, z4, 0, 0, 0);
#pragma unroll
    for (int nt2 = 0; nt2 < 2; ++nt2) {
      float p[4];
#pragma unroll
      for (int r = 0; r < 4; ++r) {
        float t = s[nt2][r] + pwv[nt2][r] + phv;
        p[r] = exp2f(t);
        sacc += p[r];
      }
      uint2 pk;
      pk.x = (unsigned)f2bs(p[0]) | ((unsigned)f2bs(p[1]) << 16);
      pk.y = (unsigned)f2bs(p[2]) | ((unsigned)f2bs(p[3]) << 16);
      *(uint2*)(pl + il * 40 + nt2 * 16 + q * 4) = pk;
    }
    v8s pf = *(const v8s*)(pl + il * 40 + q * 8);
    oacc = __builtin_amdgcn_mfma_f32_16x16x32_bf16(pf, vcur, oacc, 0, 0, 0);
  }

  // row sums: lane holds partial for row il; combine quads, then fetch per-r.
  sacc += __shfl_xor(sacc, 16);
  sacc += __shfl_xor(sacc, 32);

  unsigned short* abase = (b < 6) ? (dq + ART1_US + (size_t)b * 131072)
                                  : (wsart + (size_t)(b - 6) * 131072);
#pragma unroll
  for (int r = 0; r < 4; ++r) {
    float sr = __shfl(sacc, q * 4 + r);       // full sum for row q*4+r
    int m = m0 + q * 4 + r;
    int c = h * 16 + (m >> 6);                // ci of art
    int pp = (m & 63) * 16 + il;              // pos' of art
    abase[((c >> 5) * 1024 + pp) * 32 + (c & 31)] = f2bs(oacc[r] / sr);
  }
}

// ---------------------------------------------------------------------------
// attn_out GEMM: A from artX (contiguous), B from WA2 (frag-major).
// 4 waves/block; wave (mh,nh) owns the 2x2 quadrant.
// R9: 1D grid 256, b = bx&7 pins batch to XCD (art slice L2-resident).
__global__ __launch_bounds__(256) void attn_out_mfma(
    const unsigned short* __restrict__ dq, const unsigned short* __restrict__ wsart,
    const unsigned short* __restrict__ wa2, const float* __restrict__ ba,
    float* __restrict__ out) {
  int tid = threadIdx.x;
  int lane = tid & 63; int il = lane & 15, q = lane >> 4;
  int wv = tid >> 6; int mh = wv >> 1, nh = wv & 1;
  int bx = blockIdx.x;
  int b = bx & 7, pt = (bx >> 3) & 15, coG = bx >> 7;
  int pp0 = pt * 64;
  const unsigned short* ab = (b < 6) ? (dq + ART1_US + (size_t)b * 131072)
                                     : (wsart + (size_t)(b - 6) * 131072);
  const unsigned short* bt = wa2 + (size_t)coG * 8192 + lane * 8;
  v4f acc[2][2];
#pragma unroll
  for (int mi = 0; mi < 2; ++mi)
#pragma unroll
    for (int ni = 0; ni < 2; ++ni) acc[mi][ni] = (v4f){0.f, 0.f, 0.f, 0.f};
#pragma unroll
  for (int kc = 0; kc < 4; ++kc) {
    v8s af[2], bf[2];
#pragma unroll
    for (int ni = 0; ni < 2; ++ni)
      bf[ni] = *(const v8s*)(bt + ((nh * 2 + ni) * 4 + kc) * 512);
#pragma unroll
    for (int mi = 0; mi < 2; ++mi)
      af[mi] = *(const v8s*)(ab + (kc * 1024 + pp0 + (mh * 2 + mi) * 16 + il) * 32 + q * 8);
#pragma unroll
    for (int mi = 0; mi < 2; ++mi)
#pragma unroll
      for (int ni = 0; ni < 2; ++ni)
        acc[mi][ni] = __builtin_amdgcn_mfma_f32_16x16x32_bf16(
            af[mi], bf[ni], acc[mi][ni], 0, 0, 0);
  }
  int co0 = coG * 64;
#pragma unroll
  for (int ni = 0; ni < 2; ++ni) {
    int co = co0 + (nh * 2 + ni) * 16 + il;
    float bias = ba[co];
#pragma unroll
    for (int mi = 0; mi < 2; ++mi) {
      int mt = mh * 2 + mi;
      v4f a = acc[mi][ni];
      float4 v; v.x = a[0] + bias; v.y = a[1] + bias;
      v.z = a[2] + bias; v.w = a[3] + bias;
      *(float4*)(out + ((size_t)(b * 512 + 384 + co)) * 1024 + pp0 + mt * 16 + q * 4) = v;
    }
  }
}

// ---------------------------------------------------------------------------
// conv3x3 via MFMA (R7/v5). Block 512 thr = 8 waves, 128 pos x 96 cout
// (wave = mh(0..3) x nh(0..1), tile 32pos x 48cout, 6 MFMA/tap).
// Per kc: W tile [6 nfg][9 tap][512us] (54KB) + X tile [6 row][4 q][34 x][8ci]
// (13KB) staged to LDS via global_load_lds (wave-uniform slot base, lane x16B
// auto-offset; permuted global source). Single-buffered; 2 barriers/kc;
// staging stall covered by co-resident block (LDS 68.6KB -> 2 blocks/CU).
// All 8 waves share the W tile: L2 weight traffic 442MB -> 110MB.
// Grid (64,4): b = bx&7 pins batch to XCD.
__global__ __launch_bounds__(512, 4) void conv_mfma(
    const unsigned short* __restrict__ xc, const unsigned short* __restrict__ wb3,
    const float* __restrict__ bo, float* __restrict__ out) {
  __shared__ unsigned short xlds[6656];     // 13 slots x 512 (816 chunks + pad)
  __shared__ unsigned short wlds[27648];    // 54 slots x 512
  int tid = threadIdx.x;
  int lane = tid & 63; int il = lane & 15, q = lane >> 4;
  int wv = tid >> 6; int mh = wv >> 1, nh = wv & 1;
  int bx = blockIdx.x, nset = blockIdx.y;
  int b = bx & 7, pt = bx >> 3;             // pt 0..7; b fastest => XCD-pinned
  int pos0 = pt * 128, y0 = pt * 4;
  const unsigned short* xb = xc + ((size_t)(b * 8) * 1156 + y0 * 34) * 32;

  v4f acc[2][3];
#pragma unroll
  for (int mi = 0; mi < 2; ++mi)
#pragma unroll
    for (int j = 0; j < 3; ++j) acc[mi][j] = (v4f){0.f, 0.f, 0.f, 0.f};

  // X: lds chunk c=(row*4+q)*34+x <- global chunk row*136+x*4+q of slice kc.
  auto stageX = [&](int kc) {
    const unsigned short* src = xb + (size_t)kc * 36992;   // 1156*32
#pragma unroll
    for (int t = 0; t < 2; ++t) {
      int s = wv + t * 8;                   // wave-uniform slot
      if (s < 13) {
        int c = s * 64 + lane;
        int row = c / 136, rem = c % 136;
        int qv = rem / 34, xx = rem % 34;
        const unsigned short* g = src + ((row * 136 + xx * 4 + qv) << 3);
        __builtin_amdgcn_global_load_lds(
            (const __attribute__((address_space(1))) void*)g,
            (__attribute__((address_space(3))) void*)(&xlds[s * 512]),
            16, 0, 0);
      }
    }
  };

  // W: lds [nfg][tap][512] <- WB3[(nset*6+nfg)][kc][tap]; slot s: nfg=s/9,tap=s%9.
  auto stageW = [&](int kc) {
#pragma unroll
    for (int t = 0; t < 7; ++t) {
      int s = wv + t * 8;                   // wave-uniform slot
      if (s < 54) {
        int nfg = s / 9, tp = s % 9;
        const unsigned short* g = wb3 +
            ((size_t)(((nset * 6 + nfg) * 8 + kc) * 9 + tp) * 512 + lane * 8);
        __builtin_amdgcn_global_load_lds(
            (const __attribute__((address_space(1))) void*)g,
            (__attribute__((address_space(3))) void*)(&wlds[s * 512]),
            16, 0, 0);
      }
    }
  };

  stageX(0);
  stageW(0);
  __syncthreads();

  for (int kc = 0; kc < 8; ++kc) {
#pragma unroll
    for (int tap = 0; tap < 9; ++tap) {
      int ky = tap / 3, kx = tap % 3;
      v8s af[2], bf[3];
#pragma unroll
      for (int j = 0; j < 3; ++j)
        bf[j] = *(const v8s*)&wlds[((nh * 3 + j) * 9 + tap) * 512 + lane * 8];
#pragma unroll
      for (int mi = 0; mi < 2; ++mi) {
        int mf = mh * 2 + mi;
        af[mi] = *(const v8s*)&xlds[((((mf >> 1) + ky) * 4 + q) * 34 +
                                     ((mf & 1) * 16 + kx + il)) * 8];
      }
#pragma unroll
      for (int mi = 0; mi < 2; ++mi)
#pragma unroll
        for (int j = 0; j < 3; ++j)
          acc[mi][j] = __builtin_amdgcn_mfma_f32_16x16x32_bf16(
              af[mi], bf[j], acc[mi][j], 0, 0, 0);
    }
    if (kc < 7) {
      __syncthreads();                      // all reads of W/X done
      stageX(kc + 1);
      stageW(kc + 1);
      __syncthreads();                      // staging drained (vmcnt 0)
    }
  }

  int co0 = nset * 96;
#pragma unroll
  for (int j = 0; j < 3; ++j) {
    int co = co0 + (nh * 3 + j) * 16 + il;
    float bias = bo[co];
#pragma unroll
    for (int mi = 0; mi < 2; ++mi) {
      int mf = mh * 2 + mi;
      v4f a = acc[mi][j];
      float4 v; v.x = a[0] + bias; v.y = a[1] + bias;
      v.z = a[2] + bias; v.w = a[3] + bias;
      *(float4*)(out + ((size_t)(b * 512 + co)) * 1024 +
                 pos0 + mf * 16 + q * 4) = v;
    }
  }
}

// ---------------------------------------------------------------------------
extern "C" void kernel_launch(void* const* d_in, const int* in_sizes, int n_in,
                              void* d_out, int out_size, void* d_ws, size_t ws_size,
                              hipStream_t stream) {
  const float* x      = (const float*)d_in[0];
  const float* b_out  = (const float*)d_in[2];
  const float* b_kqv  = (const float*)d_in[4];
  const float* b_attn = (const float*)d_in[6];
  const float* krw    = (const float*)d_in[7];
  const float* krh    = (const float*)d_in[8];
  unsigned short* ws = (unsigned short*)d_ws;
  float* out = (float*)d_out;
  unsigned short* dq = (unsigned short*)d_out;

  prep_kernel<<<4556, 256, 0, stream>>>(
      (const float*)d_in[1], (const float*)d_in[3], (const float*)d_in[5],
      krw, krh, x, ws);
  kqv_mfma<<<768, 256, 0, stream>>>(
      ws + XC_US, ws + WK2_US, b_kqv, dq);
  attn_mfma<<<dim3(64, 16), 256, 0, stream>>>(
      dq, ws + KRWB_US, ws + KRHB_US, ws + ART2_US);
  attn_out_mfma<<<256, 256, 0, stream>>>(
      dq, ws + ART2_US, ws + WA2_US, b_attn, out);
  conv_mfma<<<dim3(64, 4), 512, 0, stream>>>(
      ws + XC_US, ws + WB2_US, b_out, out);
}